// Round 7
// baseline (12398.958 us; speedup 1.0000x reference)
//
#include <hip/hip_runtime.h>
#include <hip/hip_bf16.h>
#include <math.h>

// ---- problem constants ----
constexpr int NN   = 131072;   // total nodes (B*NPG)
constexpr int NE   = 262144;   // edges
constexpr int BG   = 256;      // graphs

typedef __bf16 bf16x8 __attribute__((ext_vector_type(8)));
typedef float  f32x4  __attribute__((ext_vector_type(4)));

__device__ inline float sigm(float x){ return 1.f/(1.f+__expf(-x)); }
__device__ inline float blo(unsigned u){ union{unsigned a;float f;}v; v.a=u<<16; return v.f; }
__device__ inline float bhi(unsigned u){ union{unsigned a;float f;}v; v.a=u&0xffff0000u; return v.f; }
__device__ inline unsigned short f2bu(float f){
  union{float f;unsigned u;}v; v.f=f;
  unsigned u = v.u + 0x7fffu + ((v.u>>16)&1u);
  return (unsigned short)(u>>16);
}
__device__ inline bf16x8 cvt8(float4 a, float4 b){
  union { ushort u[8]; bf16x8 v; } r;
  r.u[0]=f2bu(a.x); r.u[1]=f2bu(a.y); r.u[2]=f2bu(a.z); r.u[3]=f2bu(a.w);
  r.u[4]=f2bu(b.x); r.u[5]=f2bu(b.y); r.u[6]=f2bu(b.z); r.u[7]=f2bu(b.w);
  return r.v;
}

__global__ void k_zero(int* __restrict__ p, int n){
  int i = blockIdx.x*256 + threadIdx.x;
  if (i < n) p[i] = 0;
}

// ---------------- node encoder ----------------
__global__ void k_node_enc(const int* __restrict__ x, const float* __restrict__ emb,
                           float* __restrict__ h0){
  int n = blockIdx.x*256 + threadIdx.x;
  if (n >= NN) return;
  int nt = x[2*n], ninv = x[2*n+1];
  float4 v; v.x = emb[nt*3+0]; v.y = emb[nt*3+1]; v.z = emb[nt*3+2]; v.w = (float)ninv;
  reinterpret_cast<float4*>(h0)[n] = v;
}

// ---------------- CSR build (by dst) ----------------
__global__ void k_count(const int* __restrict__ ei, int* __restrict__ deg){
  int e = blockIdx.x*256 + threadIdx.x;
  if (e >= NE) return;
  atomicAdd(&deg[ei[NE + e]], 1);
}
__global__ void k_blocksum(const int* __restrict__ deg, int* __restrict__ bsum){
  __shared__ int sd[256];
  int t = threadIdx.x;
  const int* p = deg + blockIdx.x*1024;
  int s = p[t*4] + p[t*4+1] + p[t*4+2] + p[t*4+3];
  sd[t]=s; __syncthreads();
  for (int d=128; d>0; d>>=1){ if (t<d) sd[t]+=sd[t+d]; __syncthreads(); }
  if (!t) bsum[blockIdx.x] = sd[0];
}
__global__ void k_scanbsum(const int* __restrict__ bsum, int* __restrict__ boff, int* __restrict__ offN){
  __shared__ int s[128];
  int t = threadIdx.x;
  int mine = bsum[t];
  s[t]=mine; __syncthreads();
  for (int d=1; d<128; d<<=1){ int v = (t>=d)? s[t-d]:0; __syncthreads(); s[t]+=v; __syncthreads(); }
  boff[t] = s[t]-mine;
  if (t==127) offN[0] = s[127];
}
__global__ void k_scanchunk(const int* __restrict__ deg, const int* __restrict__ boff, int* __restrict__ offs){
  __shared__ int ts[256];
  int t = threadIdx.x, b = blockIdx.x;
  const int* p = deg + b*1024;
  int v0=p[t*4],v1=p[t*4+1],v2=p[t*4+2],v3=p[t*4+3];
  int mysum=v0+v1+v2+v3;
  ts[t]=mysum; __syncthreads();
  for (int d=1; d<256; d<<=1){ int v=(t>=d)?ts[t-d]:0; __syncthreads(); ts[t]+=v; __syncthreads(); }
  int ex = ts[t]-mysum + boff[b];
  int* o = offs + b*1024 + t*4;
  o[0]=ex; o[1]=ex+v0; o[2]=ex+v0+v1; o[3]=ex+v0+v1+v2;
}
__global__ void k_fill(const int* __restrict__ ei, const int* __restrict__ offs,
                       int* __restrict__ cur, int* __restrict__ esrc){
  int e = blockIdx.x*256 + threadIdx.x;
  if (e >= NE) return;
  int dst = ei[NE+e];
  int pos = offs[dst] + atomicAdd(&cur[dst],1);
  esrc[pos] = ei[e];
}

// ---------------- softmax aggregation, 4-channel (conv1), no-max (exact) ----------------
__global__ void k_aggr4(const float* __restrict__ h, const int* __restrict__ offs,
                        const int* __restrict__ esrc, const float* __restrict__ tptr,
                        float* __restrict__ ag){
  int n = blockIdx.x*256 + threadIdx.x;
  if (n >= NN) return;
  int s = offs[n], e = offs[n+1];
  float4 z = {0,0,0,0};
  if (s == e){ reinterpret_cast<float4*>(ag)[n] = z; return; }
  float t = *tptr;
  float4 num=z, den=z;
  for (int i=s;i<e;++i){
    float4 v = reinterpret_cast<const float4*>(h)[esrc[i]];
    float ex;
    ex=__expf(v.x*t); num.x+=v.x*ex; den.x+=ex;
    ex=__expf(v.y*t); num.y+=v.y*ex; den.y+=ex;
    ex=__expf(v.z*t); num.z+=v.z*ex; den.z+=ex;
    ex=__expf(v.w*t); num.w+=v.w*ex; den.w+=ex;
  }
  float4 r = {num.x/den.x, num.y/den.y, num.z/den.z, num.w/den.w};
  reinterpret_cast<float4*>(ag)[n] = r;
}

// ---------------- softmax aggregation (no-max, 1 pass), fused [h1|ag] layout ----------------
// buf rows are 512-wide: cols 0..255 = h1, cols 256..511 = ag (written here)
__global__ __launch_bounds__(256) void k_aggr256(float* __restrict__ buf, const int* __restrict__ offs,
                          const int* __restrict__ esrc, const float* __restrict__ tptr, int base){
  int n = base + blockIdx.x, c = threadIdx.x;
  int s = offs[n], e = offs[n+1];
  float* outp = buf + (size_t)blockIdx.x*512 + 256 + c;
  if (s == e){ *outp = 0.f; return; }
  float t = *tptr;
  float num=0.f, den=0.f;
  for (int i=s;i<e;++i){
    float v = buf[(size_t)(esrc[i]-base)*512 + c];
    float ex = __expf(v*t);
    num += v*ex; den += ex;
  }
  *outp = num/den;
}

// ---------------- conv1 linear (K=4, fused), writes [n][512] col 0..255 ----------------
__global__ __launch_bounds__(256) void k_conv1_lin(const float* __restrict__ ag, const float* __restrict__ h0,
                            const float* __restrict__ lW, const float* __restrict__ lb,
                            const float* __restrict__ rW, float* __restrict__ out, int base){
  int n = base + blockIdx.x, c = threadIdx.x;
  float4 a  = reinterpret_cast<const float4*>(ag)[n];
  float4 xv = reinterpret_cast<const float4*>(h0)[n];
  float acc = lb[c];
  acc += a.x*lW[c]  + a.y*lW[256+c]  + a.z*lW[512+c]  + a.w*lW[768+c];
  acc += xv.x*rW[c] + xv.y*rW[256+c] + xv.z*rW[512+c] + xv.w*rW[768+c];
  out[(size_t)blockIdx.x*512 + c] = fmaxf(acc, 0.f);
}

// ---------------- flags ----------------
#define GF_BIAS    1
#define GF_RELU    2
#define GF_RESID   4
#define GF_RESID_B 8
#define GF_ADDC    32
#define GF_ATOMIC  64
#define GF_BF16    128

// ---------------- old f32 GEMM (kept for MLP-pool split-K atomic) ----------------
template<int FLAGS>
__global__ __launch_bounds__(256) void k_gemm(const float* __restrict__ A, const float* __restrict__ Bm,
                       const float* __restrict__ bias, const float* __restrict__ resid,
                       float* __restrict__ C, int M, int Nn, int K){
  __shared__ float As[16][128];
  __shared__ float Bs[16][128];
  const int m0 = blockIdx.x*128, n0 = blockIdx.y*128;
  const int kChunk = K / gridDim.z;
  const int kBeg = blockIdx.z * kChunk;
  const int tid = threadIdx.x;
  const int tm = tid>>4, tn = tid&15;
  const int mA = tid>>2, kA = (tid&3)*4;
  const int kB = tid>>4, nB = (tid&15)*8;
  float acc[8][8] = {};
  for (int k0=kBeg; k0<kBeg+kChunk; k0+=16){
    float4 a0 = *reinterpret_cast<const float4*>(A + (size_t)(m0+mA)*K + k0 + kA);
    float4 a1 = *reinterpret_cast<const float4*>(A + (size_t)(m0+mA+64)*K + k0 + kA);
    float4 b0 = *reinterpret_cast<const float4*>(Bm + (size_t)(k0+kB)*Nn + n0 + nB);
    float4 b1 = *reinterpret_cast<const float4*>(Bm + (size_t)(k0+kB)*Nn + n0 + nB + 4);
    __syncthreads();
    As[kA+0][mA]=a0.x; As[kA+1][mA]=a0.y; As[kA+2][mA]=a0.z; As[kA+3][mA]=a0.w;
    As[kA+0][mA+64]=a1.x; As[kA+1][mA+64]=a1.y; As[kA+2][mA+64]=a1.z; As[kA+3][mA+64]=a1.w;
    *reinterpret_cast<float4*>(&Bs[kB][nB])   = b0;
    *reinterpret_cast<float4*>(&Bs[kB][nB+4]) = b1;
    __syncthreads();
    #pragma unroll
    for (int kk=0;kk<16;++kk){
      float4 x0 = *reinterpret_cast<const float4*>(&As[kk][tm*8]);
      float4 x1 = *reinterpret_cast<const float4*>(&As[kk][tm*8+4]);
      float4 y0 = *reinterpret_cast<const float4*>(&Bs[kk][tn*8]);
      float4 y1 = *reinterpret_cast<const float4*>(&Bs[kk][tn*8+4]);
      float av[8]={x0.x,x0.y,x0.z,x0.w,x1.x,x1.y,x1.z,x1.w};
      float bv[8]={y0.x,y0.y,y0.z,y0.w,y1.x,y1.y,y1.z,y1.w};
      #pragma unroll
      for (int i=0;i<8;++i){
        #pragma unroll
        for (int j=0;j<8;++j) acc[i][j] += av[i]*bv[j];
      }
    }
  }
  #pragma unroll
  for (int i=0;i<8;++i){
    const size_t m = (size_t)m0 + tm*8 + i;
    #pragma unroll
    for (int j=0;j<8;++j){
      const int n = n0 + tn*8 + j;
      size_t idx = m*(size_t)Nn + n;
      float v = acc[i][j];
      if (FLAGS & GF_ATOMIC){ atomicAdd(&C[idx], v); }
      else {
        if (FLAGS & GF_BIAS)    v += bias[n];
        if (FLAGS & GF_ADDC)    v += C[idx];
        if (FLAGS & GF_RELU)    v = fmaxf(v, 0.f);
        if (FLAGS & GF_RESID)   v += resid[idx];
        if (FLAGS & GF_RESID_B) v += resid[n];
        if (FLAGS & GF_BF16) reinterpret_cast<__hip_bfloat16*>(C)[idx] = __float2bfloat16(v);
        else C[idx] = v;
      }
    }
  }
}

// ---------------- weight pack: f32 W[K][N] -> MFMA-B bf16 Bp[((k>>3)*N + j)*8 + (k&7)] ----
__global__ void k_packb(const float* __restrict__ W, ushort* __restrict__ Bp, int K, int N){
  int idx = blockIdx.x*256 + threadIdx.x;
  if (idx >= K*N) return;
  int k = idx / N, j = idx - k*N;
  Bp[((size_t)(k>>3)*N + j)*8 + (k&7)] = f2bu(W[idx]);
}
// transposed source: W is [N][K] row-major; B[k][j] = W[j][k]
__global__ void k_packbT(const float* __restrict__ W, ushort* __restrict__ Bp, int K, int N){
  int idx = blockIdx.x*256 + threadIdx.x;
  if (idx >= K*N) return;
  int j = idx / K, k = idx - j*K;
  Bp[((size_t)(k>>3)*N + j)*8 + (k&7)] = f2bu(W[idx]);
}
// combined GRU biases: [0..255]=bir+bhr, [256..511]=biz+bhz, [512..767]=bin, [768..1023]=bhn
__global__ void k_packbias(const float* __restrict__ gbih, const float* __restrict__ gbhh,
                           float* __restrict__ bc){
  int i = blockIdx.x*256 + threadIdx.x;
  if (i >= 1024) return;
  int c = i & 255;
  float v;
  if (i < 256)      v = gbih[c] + gbhh[c];
  else if (i < 512) v = gbih[256+c] + gbhh[256+c];
  else if (i < 768) v = gbih[512+c];
  else              v = gbhh[512+c];
  bc[i] = v;
}

// ---------------- MFMA GEMM: LDS-free, A f32 (cvt in-reg), B pre-packed bf16 ----------------
template<int FLAGS>
__global__ __launch_bounds__(256) void k_bgemm(const float* __restrict__ A, const ushort* __restrict__ Bp,
                       const float* __restrict__ bias, const float* __restrict__ resid,
                       float* __restrict__ C, int M, int Nn, int K, int lda){
  const int tid = threadIdx.x;
  const int wv = tid>>6, lane = tid&63;
  const int mw = wv>>1, nw = wv&1;
  const int arow = lane&15, ks = lane>>4;
  const int m0 = blockIdx.x*128 + mw*64, n0 = blockIdx.y*128 + nw*64;
  const int kChunk = K / gridDim.z, kBeg = blockIdx.z * kChunk;
  f32x4 acc[4][4] = {};
  const float* Arow0 = A + (size_t)(m0 + 0*16 + arow)*lda;
  const float* Arow1 = A + (size_t)(m0 + 1*16 + arow)*lda;
  const float* Arow2 = A + (size_t)(m0 + 2*16 + arow)*lda;
  const float* Arow3 = A + (size_t)(m0 + 3*16 + arow)*lda;
  #pragma unroll 2
  for (int k0 = kBeg; k0 < kBeg+kChunk; k0 += 32){
    const int kb = (k0>>3) + ks;
    bf16x8 af[4];
    {
      const float4* p0 = reinterpret_cast<const float4*>(Arow0 + k0 + ks*8);
      const float4* p1 = reinterpret_cast<const float4*>(Arow1 + k0 + ks*8);
      const float4* p2 = reinterpret_cast<const float4*>(Arow2 + k0 + ks*8);
      const float4* p3 = reinterpret_cast<const float4*>(Arow3 + k0 + ks*8);
      af[0] = cvt8(p0[0], p0[1]);
      af[1] = cvt8(p1[0], p1[1]);
      af[2] = cvt8(p2[0], p2[1]);
      af[3] = cvt8(p3[0], p3[1]);
    }
    #pragma unroll
    for (int nf=0; nf<4; ++nf){
      const int col = n0 + nf*16 + arow;
      bf16x8 bfr = *reinterpret_cast<const bf16x8*>(Bp + ((size_t)kb*Nn + col)*8);
      #pragma unroll
      for (int mf=0; mf<4; ++mf)
        acc[mf][nf] = __builtin_amdgcn_mfma_f32_16x16x32_bf16(af[mf], bfr, acc[mf][nf], 0, 0, 0);
    }
  }
  #pragma unroll
  for (int nf=0; nf<4; ++nf){
    const int n = n0 + nf*16 + arow;
    float bv  = (FLAGS & GF_BIAS)    ? bias[n]  : 0.f;
    float rbv = (FLAGS & GF_RESID_B) ? resid[n] : 0.f;
    #pragma unroll
    for (int mf=0; mf<4; ++mf){
      #pragma unroll
      for (int r=0; r<4; ++r){
        const size_t m = (size_t)m0 + mf*16 + ks*4 + r;
        size_t idx = m*(size_t)Nn + n;
        float v = acc[mf][nf][r];
        if (FLAGS & GF_ATOMIC){ atomicAdd(&C[idx], v); }
        else {
          v += bv;
          if (FLAGS & GF_ADDC)  v += C[idx];
          if (FLAGS & GF_RELU)  v = fmaxf(v, 0.f);
          if (FLAGS & GF_RESID) v += resid[idx];
          v += rbv;
          if (FLAGS & GF_BF16) reinterpret_cast<__hip_bfloat16*>(C)[idx] = __float2bfloat16(v);
          else C[idx] = v;
        }
      }
    }
  }
}

// ---------------- small utilities ----------------
__global__ void k_rowbias(const float* __restrict__ bias, float* __restrict__ C, int Nn, int total){
  int i = blockIdx.x*256 + threadIdx.x;
  if (i < total) C[i] = bias[i % Nn];
}
__global__ void k_qvec(const float* __restrict__ seed, const float* __restrict__ Wq,
                       const float* __restrict__ bq, float* __restrict__ qv){
  __shared__ float s[256];
  int t = threadIdx.x;
  s[t] = seed[t]; __syncthreads();
  float acc = bq[t];
  for (int c = 0; c < 256; ++c) acc += s[c] * Wq[c*256 + t];
  qv[t] = acc;
}
__global__ void k_concat(const float* __restrict__ p1, const float* __restrict__ p2,
                         const float* __restrict__ p3, float* __restrict__ pooled){
  int idx = blockIdx.x*256 + threadIdx.x;
  int b = idx / 768, j = idx % 768;
  float v = (j < 256) ? p1[b*256+j] : (j < 512) ? p2[b*256+j-256] : p3[b*256+j-512];
  pooled[idx] = v;
}

// ---------------- GRU v7b: Whh register-resident. 8 graphs/block, 32 blocks, 512 thr ----
// Per wave: 48 B-fragments of Whh (192 VGPR) held for the whole kernel.
// gi precomputed per 32-step window via in-kernel MFMA GEMM into a global slab.
// FIX vs v7: each wave iterates ALL 16 row-tiles of the window GEMM for its own
// 96-column stripe (v7 covered only 2 row-tiles per wave -> 7/8 of gi unwritten).
__global__ __launch_bounds__(512,1) void k_gru7(const float* __restrict__ X,
                      const ushort* __restrict__ pIh, const ushort* __restrict__ pHh,
                      const float* __restrict__ bc, float* __restrict__ gi,
                      float* __restrict__ p2){
  __shared__ ushort hbf[16*256];     // 8KB, row=graph(0..7 live), kslot xor-swizzled
  __shared__ float  ghl[8][776];     // 24.8KB
  __shared__ float  bcl[1024];       // 4KB
  const int tid = threadIdx.x;
  const int wv = tid>>6, lane = tid&63;
  const int arow = lane&15, ks = lane>>4;
  const int g0 = blockIdx.x*8;
  float* gis = gi + (size_t)blockIdx.x*196608;   // 256 rows x 768
  // Whh fragments: wave wv owns cols [wv*96, wv*96+96)
  bf16x8 whh[8][6];
  #pragma unroll
  for (int kt=0;kt<8;++kt)
    #pragma unroll
    for (int nt=0;nt<6;++nt)
      whh[kt][nt] = *reinterpret_cast<const bf16x8*>(pHh + ((size_t)(kt*4+ks)*768 + wv*96+nt*16+arow)*8);
  for (int i=tid;i<1024;i+=512) bcl[i] = bc[i];
  for (int i=tid;i<2048;i+=512) reinterpret_cast<unsigned*>(hbf)[i] = 0;
  const int gm = tid>>5, c8 = tid&31;            // gate ownership (tid<256)
  float h_reg[8] = {};
  __syncthreads();
  for (int w=0; w<16; ++w){
    const int t0 = w*32;
    // ---- window GEMM: gi[256][768] = Xw[256][256] @ Wih ----
    // wave wv: ALL 16 row-tiles x its 6 col-tiles (full coverage across 8 waves)
    for (int mt=0; mt<16; ++mt){
      const int rl = mt*16 + arow;
      const int dt = rl>>3, gmr = rl&7;
      const float* xr = X + ((size_t)(g0+gmr)*512 + t0+dt)*256;
      f32x4 acc[6] = {};
      #pragma unroll
      for (int kt=0; kt<8; ++kt){
        const float4* xp = reinterpret_cast<const float4*>(xr + kt*32 + ks*8);
        bf16x8 af = cvt8(xp[0], xp[1]);
        #pragma unroll
        for (int nt=0; nt<6; ++nt){
          bf16x8 bfr = *reinterpret_cast<const bf16x8*>(pIh + ((size_t)(kt*4+ks)*768 + wv*96+nt*16+arow)*8);
          acc[nt] = __builtin_amdgcn_mfma_f32_16x16x32_bf16(af, bfr, acc[nt], 0,0,0);
        }
      }
      #pragma unroll
      for (int nt=0; nt<6; ++nt){
        const int col = wv*96 + nt*16 + arow;
        #pragma unroll
        for (int r=0;r<4;++r)
          gis[(size_t)(mt*16 + ks*4 + r)*768 + col] = acc[nt][r];
      }
    }
    __syncthreads();   // gi slab stores drained (vmcnt(0)) + barrier: visible block-wide
    for (int dt=0; dt<32; ++dt){
      // gh = h @ Whh  (A rows 0..7 live, 8..15 zero)
      f32x4 sacc[6] = {};
      #pragma unroll
      for (int kt=0; kt<8; ++kt){
        const int slot = (kt*4+ks) ^ (arow&7);
        bf16x8 af = *reinterpret_cast<const bf16x8*>(&hbf[arow*256 + slot*8]);
        #pragma unroll
        for (int nt=0; nt<6; ++nt)
          sacc[nt] = __builtin_amdgcn_mfma_f32_16x16x32_bf16(af, whh[kt][nt], sacc[nt], 0,0,0);
      }
      if (ks < 2){   // D rows ks*4+r in 0..7
        #pragma unroll
        for (int nt=0; nt<6; ++nt){
          const int col = wv*96 + nt*16 + arow;
          #pragma unroll
          for (int r=0;r<4;++r) ghl[ks*4+r][col] = sacc[nt][r];
        }
      }
      __syncthreads();   // ghl ready; hbf reads done
      if (tid < 256){
        const float* gir = gis + ((size_t)(dt*8+gm))*768 + c8*8;
        float4 i0 = *reinterpret_cast<const float4*>(gir);
        float4 i1 = *reinterpret_cast<const float4*>(gir+4);
        float4 z0 = *reinterpret_cast<const float4*>(gir+256);
        float4 z1 = *reinterpret_cast<const float4*>(gir+260);
        float4 n0 = *reinterpret_cast<const float4*>(gir+512);
        float4 n1 = *reinterpret_cast<const float4*>(gir+516);
        float gir8[8]={i0.x,i0.y,i0.z,i0.w,i1.x,i1.y,i1.z,i1.w};
        float giz8[8]={z0.x,z0.y,z0.z,z0.w,z1.x,z1.y,z1.z,z1.w};
        float gin8[8]={n0.x,n0.y,n0.z,n0.w,n1.x,n1.y,n1.z,n1.w};
        union {ushort u[8]; uint4 q;} hu;
        #pragma unroll
        for (int r=0;r<8;++r){
          const int c = c8*8 + r;
          float rr = sigm(gir8[r] + ghl[gm][c]     + bcl[c]);
          float zz = sigm(giz8[r] + ghl[gm][256+c] + bcl[256+c]);
          float nn = tanhf(gin8[r] + bcl[512+c] + rr*(ghl[gm][512+c] + bcl[768+c]));
          float hv = (1.f-zz)*nn + zz*h_reg[r];
          h_reg[r] = hv;
          hu.u[r] = f2bu(hv);
        }
        *reinterpret_cast<uint4*>(&hbf[gm*256 + ((c8 ^ (gm&7))*8)]) = hu.q;
      }
      __syncthreads();   // hbf ready
    }
  }
  if (tid < 256){
    #pragma unroll
    for (int r=0;r<8;++r) p2[(size_t)(g0+gm)*256 + c8*8 + r] = h_reg[r];
  }
}

// ---------------- fused SAB attention, bf16 K/V: per (graph-in-chunk, 8 q-rows) ----
__global__ __launch_bounds__(256) void k_attn(float* __restrict__ Q, const __hip_bfloat16* __restrict__ K,
                       const __hip_bfloat16* __restrict__ V){
  __shared__ float Qs[8*256];
  __shared__ float S [8*512];
  __shared__ uint4 Ks[32*32];
  const int g = blockIdx.y, q0 = blockIdx.x*8, tid = threadIdx.x;
  const size_t gb = (size_t)g*512*256;
  for (int i=tid;i<2048;i+=256) Qs[i] = Q[gb + (size_t)q0*256 + i];
  const int q = tid>>5, kl = tid&31;
  const float* qp = Qs + q*256;
  float* Sq = S + q*512;
  for (int kt=0; kt<512; kt+=32){
    __syncthreads();
    for (int i=tid;i<1024;i+=256){
      int row = i>>5, c8 = i&31;
      Ks[row*32 + (c8^row)] =
        reinterpret_cast<const uint4*>(K + gb + (size_t)(kt+row)*256)[c8];
    }
    __syncthreads();
    float d = 0.f;
    #pragma unroll
    for (int c8=0;c8<32;++c8){
      uint4 kv = Ks[kl*32 + (c8^kl)];
      const float* qq = qp + c8*8;
      d += qq[0]*blo(kv.x) + qq[1]*bhi(kv.x) + qq[2]*blo(kv.y) + qq[3]*bhi(kv.y)
         + qq[4]*blo(kv.z) + qq[5]*bhi(kv.z) + qq[6]*blo(kv.w) + qq[7]*bhi(kv.w);
    }
    Sq[kt+kl] = d;
  }
  __syncthreads();
  float m = -3e38f;
  for (int j=kl;j<512;j+=32) m = fmaxf(m, Sq[j]);
  #pragma unroll
  for (int o=1;o<32;o<<=1) m = fmaxf(m, __shfl_xor(m,o));
  float sum = 0.f;
  for (int j=kl;j<512;j+=32){ float e = __expf((Sq[j]-m)*0.0625f); Sq[j]=e; sum+=e; }
  #pragma unroll
  for (int o=1;o<32;o<<=1) sum += __shfl_xor(sum,o);
  const float inv = 1.f/sum;
  __syncthreads();
  const int c0 = kl*8;
  float a0=0,a1=0,a2=0,a3=0,a4=0,a5=0,a6=0,a7=0;
  for (int k=0;k<512;++k){
    float a = Sq[k];
    uint4 vv = *reinterpret_cast<const uint4*>(V + gb + (size_t)k*256 + c0);
    a0+=a*blo(vv.x); a1+=a*bhi(vv.x); a2+=a*blo(vv.y); a3+=a*bhi(vv.y);
    a4+=a*blo(vv.z); a5+=a*bhi(vv.z); a6+=a*blo(vv.w); a7+=a*bhi(vv.w);
  }
  float* op = Q + gb + (size_t)(q0+q)*256 + c0;
  float4 o0 = {a0*inv,a1*inv,a2*inv,a3*inv};
  float4 o1 = {a4*inv,a5*inv,a6*inv,a7*inv};
  *reinterpret_cast<float4*>(op)   = o0;
  *reinterpret_cast<float4*>(op+4) = o1;
}

// ---------------- PMA attention (1 query per graph), chunked ----------------
__global__ __launch_bounds__(256) void k_attn2(const float* __restrict__ K2, const float* __restrict__ V2,
                        const float* __restrict__ qv, float* __restrict__ av2){
  int g = blockIdx.x, tid = threadIdx.x;
  __shared__ float qs[256];
  __shared__ float sc[512];
  __shared__ float red[4];
  qs[tid] = qv[tid];
  __syncthreads();
  const size_t gb = (size_t)g*512*256;
  float l0=0.f, l1=0.f;
  for (int j0=0;j0<2;++j0){
    int j = tid + j0*256;
    const float* kr = K2 + gb + (size_t)j*256;
    float a = 0.f;
    for (int c=0;c<256;c+=4){
      float4 k4 = *reinterpret_cast<const float4*>(kr + c);
      a += k4.x*qs[c] + k4.y*qs[c+1] + k4.z*qs[c+2] + k4.w*qs[c+3];
    }
    a *= 0.0625f;
    if (j0) l1=a; else l0=a;
  }
  float m = fmaxf(l0,l1);
  #pragma unroll
  for (int o=1;o<64;o<<=1) m = fmaxf(m, __shfl_xor(m,o));
  if ((tid&63)==0) red[tid>>6] = m;
  __syncthreads();
  m = fmaxf(fmaxf(red[0],red[1]), fmaxf(red[2],red[3]));
  __syncthreads();
  float e0 = __expf(l0-m), e1 = __expf(l1-m);
  sc[tid]=e0; sc[tid+256]=e1;
  float s = e0+e1;
  #pragma unroll
  for (int o=1;o<64;o<<=1) s += __shfl_xor(s,o);
  if ((tid&63)==0) red[tid>>6] = s;
  __syncthreads();
  s = red[0]+red[1]+red[2]+red[3];
  float invs = 1.f/s;
  float acc = 0.f;
  for (int j=0;j<512;++j) acc += sc[j] * V2[gb + (size_t)j*256 + tid];
  av2[(size_t)g*256+tid] = acc*invs;
}

// =====================================================================
extern "C" void kernel_launch(void* const* d_in, const int* in_sizes, int n_in,
                              void* d_out, int out_size, void* d_ws, size_t ws_size,
                              hipStream_t stream){
  const int*   x      = (const int*)  d_in[0];
  const int*   ei     = (const int*)  d_in[1];
  const float* emb_w  = (const float*)d_in[3];
  const float* c1_lW  = (const float*)d_in[4];
  const float* c1_lb  = (const float*)d_in[5];
  const float* c1_rW  = (const float*)d_in[6];
  const float* t1     = (const float*)d_in[7];
  const float* c2_lW  = (const float*)d_in[8];
  const float* c2_lb  = (const float*)d_in[9];
  const float* c2_rW  = (const float*)d_in[10];
  const float* t2     = (const float*)d_in[11];
  const float* mlp_W  = (const float*)d_in[12];
  const float* mlp_b  = (const float*)d_in[13];
  const float* gWih   = (const float*)d_in[14];
  const float* gWhh   = (const float*)d_in[15];
  const float* gbih   = (const float*)d_in[16];
  const float* gbhh   = (const float*)d_in[17];
  const float* stWq   = (const float*)d_in[18];
  const float* stbq   = (const float*)d_in[19];
  const float* stWk   = (const float*)d_in[20];
  const float* stbk   = (const float*)d_in[21];
  const float* stWv   = (const float*)d_in[22];
  const float* stbv   = (const float*)d_in[23];
  const float* stWo   = (const float*)d_in[24];
  const float* stbo   = (const float*)d_in[25];
  const float* stlW   = (const float*)d_in[26];
  const float* stlb   = (const float*)d_in[27];
  const float* pma_lW = (const float*)d_in[28];
  const float* pma_lb = (const float*)d_in[29];
  const float* seed   = (const float*)d_in[30];
  const float* fin_W  = (const float*)d_in[31];
  const float* fin_b  = (const float*)d_in[32];
  float* out = (float*)d_out;

  // ---- choose chunk size by available workspace ----
  auto needFor = [](int CHe)->size_t{
    size_t bufN = (size_t)CHe*512*512;
    size_t floats = (size_t)33554432 + 3*bufN + 2*524288 + 2*196608 + 8*65536 + 196608 + 320;
    size_t ints   = 131072 + 131200 + 131072 + 262144 + 128 + 128;
    return floats*4 + ints*4 + 4096;
  };
  const int CHe = (ws_size >= needFor(64)) ? 64 : 32;
  if (ws_size < needFor(32)) return;
  const int NCHUNKe = BG / CHe;
  const int NCNe = CHe * 512;
  const size_t bufN = (size_t)CHe*512*512;

  // ---- workspace carve ----
  float* H2   = (float*)d_ws;                    // NN*256 f32 (persists)
  float* bufA = H2   + (size_t)33554432;         // CHe*512*512 (conv fused staging / ST bufs / GI slab)
  float* bufB = bufA + bufN;
  float* bufC = bufB + bufN;
  float* h0   = bufC + bufN;                     // NN*4
  float* ag1  = h0   + (size_t)524288;           // NN*4
  float* wT1  = ag1  + (size_t)524288;           // GRU packs (pIh/pHh)
  float* wT2  = wT1  + (size_t)196608;           // pC2 + bcomb
  float* p1   = wT2  + (size_t)196608;
  float* p2   = p1   + (size_t)65536;
  float* p3   = p2   + (size_t)65536;
  float* av2  = p3   + (size_t)65536;
  float* s1   = av2  + (size_t)65536;
  float* s2v  = s1   + (size_t)65536;
  float* v3   = s2v  + (size_t)65536;
  float* h3   = v3   + (size_t)65536;
  float* pooled = h3 + (size_t)65536;
  float* qv   = pooled + (size_t)196608;
  int*   deg  = (int*)(qv + 320);
  int*   offs = deg  + 131072;
  int*   cur  = offs + 131200;
  int*   esrc = cur  + 131072;
  int*   bsum = esrc + 262144;
  int*   boff = bsum + 128;

  ushort* pIh  = (ushort*)wT1;                   // 196608 ush
  ushort* pHh  = (ushort*)(wT1 + 98304);         // 196608 ush
  ushort* pC2  = (ushort*)wT2;                   // 131072 ush (k 0..255=rW, 256..511=lW)
  float*  bcomb= wT2 + 65536;                    // 1024 f32
  float*  pa   = h0;                             // dead after conv phase -> ST packs
  ushort* pQ0  = (ushort*)(pa);
  ushort* pK0  = (ushort*)(pa + 32768);
  ushort* pV0  = (ushort*)(pa + 65536);
  ushort* pO0  = (ushort*)(pa + 98304);
  ushort* pL0  = (ushort*)(pa + 131072);
  ushort* pPma = (ushort*)(pa + 163840);
  ushort* pK1  = (ushort*)(pa + 196608);
  ushort* pV1  = (ushort*)(pa + 229376);
  ushort* pO1  = (ushort*)(pa + 262144);
  ushort* pL1  = (ushort*)(pa + 294912);
  ushort* pV2  = (ushort*)(pa + 327680);
  ushort* pO2  = (ushort*)(pa + 360448);
  ushort* pL2  = (ushort*)(pa + 393216);
  ushort* pFin = (ushort*)(pa + 425984);

  const int ls0 = 65536, ls1 = 256;

  // ---- 1. node encoder ----
  k_node_enc<<<NN/256, 256, 0, stream>>>(x, emb_w, h0);

  // ---- 2. CSR ----
  k_zero<<<NN/256, 256, 0, stream>>>(deg, NN);
  k_count<<<NE/256, 256, 0, stream>>>(ei, deg);
  k_blocksum<<<128, 256, 0, stream>>>(deg, bsum);
  k_scanbsum<<<1, 128, 0, stream>>>(bsum, boff, offs + NN);
  k_scanchunk<<<128, 256, 0, stream>>>(deg, boff, offs);
  k_zero<<<NN/256, 256, 0, stream>>>(cur, NN);
  k_fill<<<NE/256, 256, 0, stream>>>(ei, offs, cur, esrc);

  // ---- 3. conv1 aggregation + early packs ----
  k_aggr4<<<NN/256, 256, 0, stream>>>(h0, offs, esrc, t1, ag1);
  k_packb <<<256, 256, 0, stream>>>(c2_rW, pC2, 256, 256);            // A cols 0..255 = h1
  k_packb <<<256, 256, 0, stream>>>(c2_lW, pC2 + 65536, 256, 256);    // A cols 256..511 = ag
  k_packbT<<<768, 256, 0, stream>>>(gWih, pIh, 256, 768);
  k_packbT<<<768, 256, 0, stream>>>(gWhh, pHh, 256, 768);
  k_packbias<<<4, 256, 0, stream>>>(gbih, gbhh, bcomb);

  // ---- 4. conv1 + conv2 (fused K=512), chunked ----
  for (int cg = 0; cg < NCHUNKe; ++cg){
    const int base = cg * NCNe;
    float* Hc = H2 + (size_t)base * 256;
    const dim3 gg(NCNe/128, 2, 1);
    k_conv1_lin<<<NCNe, 256, 0, stream>>>(ag1, h0, c1_lW, c1_lb, c1_rW, bufA, base);
    k_aggr256<<<NCNe, 256, 0, stream>>>(bufA, offs, esrc, t2, base);
    k_bgemm<GF_BIAS|GF_RELU><<<gg, 256, 0, stream>>>(bufA, pC2, c2_lb, nullptr, Hc, NCNe, 256, 512, 512);
  }
  // H2 = h2 (full)

  // ---- 5. p1 = MLP pool (M=256, K=131072, split-K atomic, f32) ----
  k_rowbias<<<256, 256, 0, stream>>>(mlp_b, p1, 256, 65536);
  k_gemm<GF_ATOMIC><<<dim3(2, 2, 64), 256, 0, stream>>>(H2, mlp_W, nullptr, nullptr, p1, 256, 256, NN);

  // ---- 6. GRU v7b (register-resident Whh; 32 blocks; gi slab in bufA) ----
  k_gru7<<<32, 512, 0, stream>>>(H2, pIh, pHh, bcomb, bufA, p2);

  // ---- 7. ST packs + set transformer, chunked ----
  k_packb<<<256, 256, 0, stream>>>(stWq,        pQ0, 256, 256);
  k_packb<<<256, 256, 0, stream>>>(stWk,        pK0, 256, 256);
  k_packb<<<256, 256, 0, stream>>>(stWv,        pV0, 256, 256);
  k_packb<<<256, 256, 0, stream>>>(stWo,        pO0, 256, 256);
  k_packb<<<256, 256, 0, stream>>>(stlW,        pL0, 256, 256);
  k_packb<<<256, 256, 0, stream>>>(pma_lW,      pPma,256, 256);
  k_packb<<<256, 256, 0, stream>>>(stWk + ls0,  pK1, 256, 256);
  k_packb<<<256, 256, 0, stream>>>(stWv + ls0,  pV1, 256, 256);
  k_packb<<<256, 256, 0, stream>>>(stWo + ls0,  pO1, 256, 256);
  k_packb<<<256, 256, 0, stream>>>(stlW + ls0,  pL1, 256, 256);
  k_packb<<<256, 256, 0, stream>>>(stWv + 2*ls0,pV2, 256, 256);
  k_packb<<<256, 256, 0, stream>>>(stWo + 2*ls0,pO2, 256, 256);
  k_packb<<<256, 256, 0, stream>>>(stlW + 2*ls0,pL2, 256, 256);
  k_packb<<<2304, 256, 0, stream>>>(fin_W,      pFin,768, 768);
  k_qvec<<<1, 256, 0, stream>>>(seed, stWq + ls0, stbq + ls1, qv);

  for (int cg = 0; cg < NCHUNKe; ++cg){
    const int base = cg * NCNe;
    float* Hc = H2 + (size_t)base * 256;
    const dim3 gg(NCNe/128, 2, 1);
    k_bgemm<GF_BIAS><<<gg, 256, 0, stream>>>(Hc, pQ0, stbq, nullptr, bufA, NCNe, 256, 256, 256);          // Q f32
    k_bgemm<GF_BIAS|GF_BF16><<<gg, 256, 0, stream>>>(Hc, pK0, stbk, nullptr, bufB, NCNe, 256, 256, 256);  // K bf16
    k_bgemm<GF_BIAS|GF_BF16><<<gg, 256, 0, stream>>>(Hc, pV0, stbv, nullptr, bufC, NCNe, 256, 256, 256);  // V bf16
    k_attn<<<dim3(64, CHe), 256, 0, stream>>>(bufA, (const __hip_bfloat16*)bufB, (const __hip_bfloat16*)bufC);
    k_bgemm<GF_BIAS|GF_RESID><<<gg, 256, 0, stream>>>(bufA, pO0, stbo, Hc, Hc, NCNe, 256, 256, 256);      // h_sab in-place
    k_bgemm<GF_BIAS|GF_RELU|GF_RESID><<<gg, 256, 0, stream>>>(Hc, pL0, stlb, Hc, bufA, NCNe, 256, 256, 256); // h_enc
    k_bgemm<GF_BIAS|GF_RELU><<<gg, 256, 0, stream>>>(bufA, pPma, pma_lb, nullptr, bufB, NCNe, 256, 256, 256); // kk
    k_bgemm<GF_BIAS><<<gg, 256, 0, stream>>>(bufB, pK1, stbk + ls1, nullptr, bufA, NCNe, 256, 256, 256);  // K2 f32
    k_bgemm<GF_BIAS><<<gg, 256, 0, stream>>>(bufB, pV1, stbv + ls1, nullptr, bufC, NCNe, 256, 256, 256);  // V2 f32
    k_attn2<<<CHe, 256, 0, stream>>>(bufA, bufC, qv, av2 + (size_t)cg*CHe*256);
  }

  // ---- 8. PMA tail + decoder SAB ----
  k_bgemm<GF_BIAS|GF_RESID_B><<<dim3(2, 2, 1), 256, 0, stream>>>(av2, pO1, stbo + ls1, seed, s1, 256, 256, 256, 256);
  k_bgemm<GF_BIAS|GF_RELU|GF_RESID><<<dim3(2, 2, 1), 256, 0, stream>>>(s1, pL1, stlb + ls1, s1, s2v, 256, 256, 256, 256);
  k_bgemm<GF_BIAS><<<dim3(2, 2, 1), 256, 0, stream>>>(s2v, pV2, stbv + 2*ls1, nullptr, v3, 256, 256, 256, 256);
  k_bgemm<GF_BIAS|GF_RESID><<<dim3(2, 2, 1), 256, 0, stream>>>(v3, pO2, stbo + 2*ls1, s2v, h3, 256, 256, 256, 256);
  k_bgemm<GF_BIAS|GF_RELU|GF_RESID><<<dim3(2, 2, 1), 256, 0, stream>>>(h3, pL2, stlb + 2*ls1, h3, p3, 256, 256, 256, 256);

  // ---- 9. concat + final linear ----
  k_concat<<<768, 256, 0, stream>>>(p1, p2, p3, pooled);
  k_bgemm<GF_BIAS><<<dim3(2, 6, 1), 256, 0, stream>>>(pooled, pFin, fin_b, nullptr, out, 256, 768, 768, 768);
}

// Round 8
// 5421.604 us; speedup vs baseline: 2.2870x; 2.2870x over previous
//
#include <hip/hip_runtime.h>
#include <hip/hip_bf16.h>
#include <math.h>

// ---- problem constants ----
constexpr int NN   = 131072;   // total nodes (B*NPG)
constexpr int NE   = 262144;   // edges
constexpr int BG   = 256;      // graphs

typedef __bf16 bf16x8 __attribute__((ext_vector_type(8)));
typedef float  f32x4  __attribute__((ext_vector_type(4)));

__device__ inline float sigm(float x){ return 1.f/(1.f+__expf(-x)); }
__device__ inline float blo(unsigned u){ union{unsigned a;float f;}v; v.a=u<<16; return v.f; }
__device__ inline float bhi(unsigned u){ union{unsigned a;float f;}v; v.a=u&0xffff0000u; return v.f; }
__device__ inline unsigned short f2bu(float f){
  union{float f;unsigned u;}v; v.f=f;
  unsigned u = v.u + 0x7fffu + ((v.u>>16)&1u);
  return (unsigned short)(u>>16);
}
__device__ inline bf16x8 cvt8(float4 a, float4 b){
  union { ushort u[8]; bf16x8 v; } r;
  r.u[0]=f2bu(a.x); r.u[1]=f2bu(a.y); r.u[2]=f2bu(a.z); r.u[3]=f2bu(a.w);
  r.u[4]=f2bu(b.x); r.u[5]=f2bu(b.y); r.u[6]=f2bu(b.z); r.u[7]=f2bu(b.w);
  return r.v;
}

__global__ void k_zero(int* __restrict__ p, int n){
  int i = blockIdx.x*256 + threadIdx.x;
  if (i < n) p[i] = 0;
}

// ---------------- node encoder ----------------
__global__ void k_node_enc(const int* __restrict__ x, const float* __restrict__ emb,
                           float* __restrict__ h0){
  int n = blockIdx.x*256 + threadIdx.x;
  if (n >= NN) return;
  int nt = x[2*n], ninv = x[2*n+1];
  float4 v; v.x = emb[nt*3+0]; v.y = emb[nt*3+1]; v.z = emb[nt*3+2]; v.w = (float)ninv;
  reinterpret_cast<float4*>(h0)[n] = v;
}

// ---------------- CSR build (by dst) ----------------
__global__ void k_count(const int* __restrict__ ei, int* __restrict__ deg){
  int e = blockIdx.x*256 + threadIdx.x;
  if (e >= NE) return;
  atomicAdd(&deg[ei[NE + e]], 1);
}
__global__ void k_blocksum(const int* __restrict__ deg, int* __restrict__ bsum){
  __shared__ int sd[256];
  int t = threadIdx.x;
  const int* p = deg + blockIdx.x*1024;
  int s = p[t*4] + p[t*4+1] + p[t*4+2] + p[t*4+3];
  sd[t]=s; __syncthreads();
  for (int d=128; d>0; d>>=1){ if (t<d) sd[t]+=sd[t+d]; __syncthreads(); }
  if (!t) bsum[blockIdx.x] = sd[0];
}
__global__ void k_scanbsum(const int* __restrict__ bsum, int* __restrict__ boff, int* __restrict__ offN){
  __shared__ int s[128];
  int t = threadIdx.x;
  int mine = bsum[t];
  s[t]=mine; __syncthreads();
  for (int d=1; d<128; d<<=1){ int v = (t>=d)? s[t-d]:0; __syncthreads(); s[t]+=v; __syncthreads(); }
  boff[t] = s[t]-mine;
  if (t==127) offN[0] = s[127];
}
__global__ void k_scanchunk(const int* __restrict__ deg, const int* __restrict__ boff, int* __restrict__ offs){
  __shared__ int ts[256];
  int t = threadIdx.x, b = blockIdx.x;
  const int* p = deg + b*1024;
  int v0=p[t*4],v1=p[t*4+1],v2=p[t*4+2],v3=p[t*4+3];
  int mysum=v0+v1+v2+v3;
  ts[t]=mysum; __syncthreads();
  for (int d=1; d<256; d<<=1){ int v=(t>=d)?ts[t-d]:0; __syncthreads(); ts[t]+=v; __syncthreads(); }
  int ex = ts[t]-mysum + boff[b];
  int* o = offs + b*1024 + t*4;
  o[0]=ex; o[1]=ex+v0; o[2]=ex+v0+v1; o[3]=ex+v0+v1+v2;
}
__global__ void k_fill(const int* __restrict__ ei, const int* __restrict__ offs,
                       int* __restrict__ cur, int* __restrict__ esrc){
  int e = blockIdx.x*256 + threadIdx.x;
  if (e >= NE) return;
  int dst = ei[NE+e];
  int pos = offs[dst] + atomicAdd(&cur[dst],1);
  esrc[pos] = ei[e];
}

// ---------------- softmax aggregation, 4-channel (conv1), no-max (exact) ----------------
__global__ void k_aggr4(const float* __restrict__ h, const int* __restrict__ offs,
                        const int* __restrict__ esrc, const float* __restrict__ tptr,
                        float* __restrict__ ag){
  int n = blockIdx.x*256 + threadIdx.x;
  if (n >= NN) return;
  int s = offs[n], e = offs[n+1];
  float4 z = {0,0,0,0};
  if (s == e){ reinterpret_cast<float4*>(ag)[n] = z; return; }
  float t = *tptr;
  float4 num=z, den=z;
  for (int i=s;i<e;++i){
    float4 v = reinterpret_cast<const float4*>(h)[esrc[i]];
    float ex;
    ex=__expf(v.x*t); num.x+=v.x*ex; den.x+=ex;
    ex=__expf(v.y*t); num.y+=v.y*ex; den.y+=ex;
    ex=__expf(v.z*t); num.z+=v.z*ex; den.z+=ex;
    ex=__expf(v.w*t); num.w+=v.w*ex; den.w+=ex;
  }
  float4 r = {num.x/den.x, num.y/den.y, num.z/den.z, num.w/den.w};
  reinterpret_cast<float4*>(ag)[n] = r;
}

// ---------------- softmax aggregation (no-max, 1 pass), fused [h1|ag] layout ----------------
// buf rows are 512-wide: cols 0..255 = h1, cols 256..511 = ag (written here)
__global__ __launch_bounds__(256) void k_aggr256(float* __restrict__ buf, const int* __restrict__ offs,
                          const int* __restrict__ esrc, const float* __restrict__ tptr, int base){
  int n = base + blockIdx.x, c = threadIdx.x;
  int s = offs[n], e = offs[n+1];
  float* outp = buf + (size_t)blockIdx.x*512 + 256 + c;
  if (s == e){ *outp = 0.f; return; }
  float t = *tptr;
  float num=0.f, den=0.f;
  for (int i=s;i<e;++i){
    float v = buf[(size_t)(esrc[i]-base)*512 + c];
    float ex = __expf(v*t);
    num += v*ex; den += ex;
  }
  *outp = num/den;
}

// ---------------- conv1 linear (K=4, fused), writes [n][512] col 0..255 ----------------
__global__ __launch_bounds__(256) void k_conv1_lin(const float* __restrict__ ag, const float* __restrict__ h0,
                            const float* __restrict__ lW, const float* __restrict__ lb,
                            const float* __restrict__ rW, float* __restrict__ out, int base){
  int n = base + blockIdx.x, c = threadIdx.x;
  float4 a  = reinterpret_cast<const float4*>(ag)[n];
  float4 xv = reinterpret_cast<const float4*>(h0)[n];
  float acc = lb[c];
  acc += a.x*lW[c]  + a.y*lW[256+c]  + a.z*lW[512+c]  + a.w*lW[768+c];
  acc += xv.x*rW[c] + xv.y*rW[256+c] + xv.z*rW[512+c] + xv.w*rW[768+c];
  out[(size_t)blockIdx.x*512 + c] = fmaxf(acc, 0.f);
}

// ---------------- flags ----------------
#define GF_BIAS    1
#define GF_RELU    2
#define GF_RESID   4
#define GF_RESID_B 8
#define GF_ADDC    32
#define GF_ATOMIC  64
#define GF_BF16    128

// ---------------- old f32 GEMM (kept for MLP-pool split-K atomic) ----------------
template<int FLAGS>
__global__ __launch_bounds__(256) void k_gemm(const float* __restrict__ A, const float* __restrict__ Bm,
                       const float* __restrict__ bias, const float* __restrict__ resid,
                       float* __restrict__ C, int M, int Nn, int K){
  __shared__ float As[16][128];
  __shared__ float Bs[16][128];
  const int m0 = blockIdx.x*128, n0 = blockIdx.y*128;
  const int kChunk = K / gridDim.z;
  const int kBeg = blockIdx.z * kChunk;
  const int tid = threadIdx.x;
  const int tm = tid>>4, tn = tid&15;
  const int mA = tid>>2, kA = (tid&3)*4;
  const int kB = tid>>4, nB = (tid&15)*8;
  float acc[8][8] = {};
  for (int k0=kBeg; k0<kBeg+kChunk; k0+=16){
    float4 a0 = *reinterpret_cast<const float4*>(A + (size_t)(m0+mA)*K + k0 + kA);
    float4 a1 = *reinterpret_cast<const float4*>(A + (size_t)(m0+mA+64)*K + k0 + kA);
    float4 b0 = *reinterpret_cast<const float4*>(Bm + (size_t)(k0+kB)*Nn + n0 + nB);
    float4 b1 = *reinterpret_cast<const float4*>(Bm + (size_t)(k0+kB)*Nn + n0 + nB + 4);
    __syncthreads();
    As[kA+0][mA]=a0.x; As[kA+1][mA]=a0.y; As[kA+2][mA]=a0.z; As[kA+3][mA]=a0.w;
    As[kA+0][mA+64]=a1.x; As[kA+1][mA+64]=a1.y; As[kA+2][mA+64]=a1.z; As[kA+3][mA+64]=a1.w;
    *reinterpret_cast<float4*>(&Bs[kB][nB])   = b0;
    *reinterpret_cast<float4*>(&Bs[kB][nB+4]) = b1;
    __syncthreads();
    #pragma unroll
    for (int kk=0;kk<16;++kk){
      float4 x0 = *reinterpret_cast<const float4*>(&As[kk][tm*8]);
      float4 x1 = *reinterpret_cast<const float4*>(&As[kk][tm*8+4]);
      float4 y0 = *reinterpret_cast<const float4*>(&Bs[kk][tn*8]);
      float4 y1 = *reinterpret_cast<const float4*>(&Bs[kk][tn*8+4]);
      float av[8]={x0.x,x0.y,x0.z,x0.w,x1.x,x1.y,x1.z,x1.w};
      float bv[8]={y0.x,y0.y,y0.z,y0.w,y1.x,y1.y,y1.z,y1.w};
      #pragma unroll
      for (int i=0;i<8;++i){
        #pragma unroll
        for (int j=0;j<8;++j) acc[i][j] += av[i]*bv[j];
      }
    }
  }
  #pragma unroll
  for (int i=0;i<8;++i){
    const size_t m = (size_t)m0 + tm*8 + i;
    #pragma unroll
    for (int j=0;j<8;++j){
      const int n = n0 + tn*8 + j;
      size_t idx = m*(size_t)Nn + n;
      float v = acc[i][j];
      if (FLAGS & GF_ATOMIC){ atomicAdd(&C[idx], v); }
      else {
        if (FLAGS & GF_BIAS)    v += bias[n];
        if (FLAGS & GF_ADDC)    v += C[idx];
        if (FLAGS & GF_RELU)    v = fmaxf(v, 0.f);
        if (FLAGS & GF_RESID)   v += resid[idx];
        if (FLAGS & GF_RESID_B) v += resid[n];
        if (FLAGS & GF_BF16) reinterpret_cast<__hip_bfloat16*>(C)[idx] = __float2bfloat16(v);
        else C[idx] = v;
      }
    }
  }
}

// ---------------- weight pack: f32 W[K][N] -> MFMA-B bf16 Bp[((k>>3)*N + j)*8 + (k&7)] ----
__global__ void k_packb(const float* __restrict__ W, ushort* __restrict__ Bp, int K, int N){
  int idx = blockIdx.x*256 + threadIdx.x;
  if (idx >= K*N) return;
  int k = idx / N, j = idx - k*N;
  Bp[((size_t)(k>>3)*N + j)*8 + (k&7)] = f2bu(W[idx]);
}
// transposed source: W is [N][K] row-major; B[k][j] = W[j][k]
__global__ void k_packbT(const float* __restrict__ W, ushort* __restrict__ Bp, int K, int N){
  int idx = blockIdx.x*256 + threadIdx.x;
  if (idx >= K*N) return;
  int j = idx / K, k = idx - j*K;
  Bp[((size_t)(k>>3)*N + j)*8 + (k&7)] = f2bu(W[idx]);
}
// combined GRU biases: [0..255]=bir+bhr, [256..511]=biz+bhz, [512..767]=bin, [768..1023]=bhn
__global__ void k_packbias(const float* __restrict__ gbih, const float* __restrict__ gbhh,
                           float* __restrict__ bc){
  int i = blockIdx.x*256 + threadIdx.x;
  if (i >= 1024) return;
  int c = i & 255;
  float v;
  if (i < 256)      v = gbih[c] + gbhh[c];
  else if (i < 512) v = gbih[256+c] + gbhh[256+c];
  else if (i < 768) v = gbih[512+c];
  else              v = gbhh[512+c];
  bc[i] = v;
}

// ---------------- MFMA GEMM: LDS-free, A f32 (cvt in-reg), B pre-packed bf16 ----------------
template<int FLAGS>
__global__ __launch_bounds__(256) void k_bgemm(const float* __restrict__ A, const ushort* __restrict__ Bp,
                       const float* __restrict__ bias, const float* __restrict__ resid,
                       float* __restrict__ C, int M, int Nn, int K, int lda){
  const int tid = threadIdx.x;
  const int wv = tid>>6, lane = tid&63;
  const int mw = wv>>1, nw = wv&1;
  const int arow = lane&15, ks = lane>>4;
  const int m0 = blockIdx.x*128 + mw*64, n0 = blockIdx.y*128 + nw*64;
  const int kChunk = K / gridDim.z, kBeg = blockIdx.z * kChunk;
  f32x4 acc[4][4] = {};
  const float* Arow0 = A + (size_t)(m0 + 0*16 + arow)*lda;
  const float* Arow1 = A + (size_t)(m0 + 1*16 + arow)*lda;
  const float* Arow2 = A + (size_t)(m0 + 2*16 + arow)*lda;
  const float* Arow3 = A + (size_t)(m0 + 3*16 + arow)*lda;
  #pragma unroll 2
  for (int k0 = kBeg; k0 < kBeg+kChunk; k0 += 32){
    const int kb = (k0>>3) + ks;
    bf16x8 af[4];
    {
      const float4* p0 = reinterpret_cast<const float4*>(Arow0 + k0 + ks*8);
      const float4* p1 = reinterpret_cast<const float4*>(Arow1 + k0 + ks*8);
      const float4* p2 = reinterpret_cast<const float4*>(Arow2 + k0 + ks*8);
      const float4* p3 = reinterpret_cast<const float4*>(Arow3 + k0 + ks*8);
      af[0] = cvt8(p0[0], p0[1]);
      af[1] = cvt8(p1[0], p1[1]);
      af[2] = cvt8(p2[0], p2[1]);
      af[3] = cvt8(p3[0], p3[1]);
    }
    #pragma unroll
    for (int nf=0; nf<4; ++nf){
      const int col = n0 + nf*16 + arow;
      bf16x8 bfr = *reinterpret_cast<const bf16x8*>(Bp + ((size_t)kb*Nn + col)*8);
      #pragma unroll
      for (int mf=0; mf<4; ++mf)
        acc[mf][nf] = __builtin_amdgcn_mfma_f32_16x16x32_bf16(af[mf], bfr, acc[mf][nf], 0, 0, 0);
    }
  }
  #pragma unroll
  for (int nf=0; nf<4; ++nf){
    const int n = n0 + nf*16 + arow;
    float bv  = (FLAGS & GF_BIAS)    ? bias[n]  : 0.f;
    float rbv = (FLAGS & GF_RESID_B) ? resid[n] : 0.f;
    #pragma unroll
    for (int mf=0; mf<4; ++mf){
      #pragma unroll
      for (int r=0; r<4; ++r){
        const size_t m = (size_t)m0 + mf*16 + ks*4 + r;
        size_t idx = m*(size_t)Nn + n;
        float v = acc[mf][nf][r];
        if (FLAGS & GF_ATOMIC){ atomicAdd(&C[idx], v); }
        else {
          v += bv;
          if (FLAGS & GF_ADDC)  v += C[idx];
          if (FLAGS & GF_RELU)  v = fmaxf(v, 0.f);
          if (FLAGS & GF_RESID) v += resid[idx];
          v += rbv;
          if (FLAGS & GF_BF16) reinterpret_cast<__hip_bfloat16*>(C)[idx] = __float2bfloat16(v);
          else C[idx] = v;
        }
      }
    }
  }
}

// ---------------- small utilities ----------------
__global__ void k_rowbias(const float* __restrict__ bias, float* __restrict__ C, int Nn, int total){
  int i = blockIdx.x*256 + threadIdx.x;
  if (i < total) C[i] = bias[i % Nn];
}
__global__ void k_qvec(const float* __restrict__ seed, const float* __restrict__ Wq,
                       const float* __restrict__ bq, float* __restrict__ qv){
  __shared__ float s[256];
  int t = threadIdx.x;
  s[t] = seed[t]; __syncthreads();
  float acc = bq[t];
  for (int c = 0; c < 256; ++c) acc += s[c] * Wq[c*256 + t];
  qv[t] = acc;
}
__global__ void k_concat(const float* __restrict__ p1, const float* __restrict__ p2,
                         const float* __restrict__ p3, float* __restrict__ pooled){
  int idx = blockIdx.x*256 + threadIdx.x;
  int b = idx / 768, j = idx % 768;
  float v = (j < 256) ? p1[b*256+j] : (j < 512) ? p2[b*256+j-256] : p3[b*256+j-512];
  pooled[idx] = v;
}

// ---------------- GRU v8: 1 graph/block, 256 blocks, 512 thr (8 waves) ----------------
// Whh register-resident: wave wv holds cols [wv*96, wv*96+96) as 48 bf16x8 frags
// (192 VGPR), pinned via asm so the compiler cannot rematerialize the loads.
// gi computed per 32-step window into LDS (98KB) — no global round-trip.
// Per step: M=1 MFMA (A row0 = h from 512B LDS), gh -> LDS, 256 gate threads.
__global__ __launch_bounds__(512,2) void k_gru8(const float* __restrict__ X,
                      const ushort* __restrict__ pIh, const ushort* __restrict__ pHh,
                      const float* __restrict__ bc, float* __restrict__ p2){
  extern __shared__ char gsm[];
  float*  GIw = (float*)gsm;                    // [32][768]  98304 B
  float*  gh  = (float*)(gsm + 98304);          // [768]      3072 B
  float*  bcl = (float*)(gsm + 101376);         // [1024]     4096 B
  ushort* hbf = (ushort*)(gsm + 105472);        // [256]      512 B
  const int g = blockIdx.x;
  const int tid = threadIdx.x;
  const int wv = tid>>6, lane = tid&63;
  const int arow = lane&15, ks = lane>>4;
  // Whh fragments: wave wv owns cols [wv*96, wv*96+96)
  bf16x8 whh[8][6];
  #pragma unroll
  for (int kt=0;kt<8;++kt)
    #pragma unroll
    for (int nt=0;nt<6;++nt)
      whh[kt][nt] = *reinterpret_cast<const bf16x8*>(pHh + ((size_t)(kt*4+ks)*768 + wv*96+nt*16+arow)*8);
  #pragma unroll
  for (int kt=0;kt<8;++kt)
    #pragma unroll
    for (int nt=0;nt<6;++nt)
      asm volatile("" : "+v"(whh[kt][nt]));     // opaque: forbid remat/re-load
  for (int i=tid;i<1024;i+=512) bcl[i] = bc[i];
  if (tid < 256) hbf[tid] = 0;
  float h_reg = 0.f;
  const float* Xg = X + (size_t)g*512*256;
  __syncthreads();
  for (int w=0; w<16; ++w){
    const int t0 = w*32;
    // ---- window GEMM: GIw[32][768] = X[t0..t0+31][256] @ Wih (per-wave col stripe) ----
    #pragma unroll
    for (int mt=0; mt<2; ++mt){
      const float* xr = Xg + (size_t)(t0 + mt*16 + arow)*256;
      f32x4 acc[6] = {};
      #pragma unroll
      for (int kt=0; kt<8; ++kt){
        const float4* xp = reinterpret_cast<const float4*>(xr + kt*32 + ks*8);
        bf16x8 af = cvt8(xp[0], xp[1]);
        #pragma unroll
        for (int nt=0; nt<6; ++nt){
          bf16x8 bfr = *reinterpret_cast<const bf16x8*>(pIh + ((size_t)(kt*4+ks)*768 + wv*96+nt*16+arow)*8);
          acc[nt] = __builtin_amdgcn_mfma_f32_16x16x32_bf16(af, bfr, acc[nt], 0,0,0);
        }
      }
      #pragma unroll
      for (int nt=0; nt<6; ++nt){
        const int col = wv*96 + nt*16 + arow;
        #pragma unroll
        for (int r=0;r<4;++r)
          GIw[(size_t)(mt*16 + ks*4 + r)*768 + col] = acc[nt][r];
      }
    }
    // GIw writes become visible at the barrier inside the first step below
    for (int dt=0; dt<32; ++dt){
      // gh = h @ Whh : A row0 = h (rows 1..15 zero), 48 MFMA per wave
      f32x4 sacc[6] = {};
      #pragma unroll
      for (int kt=0; kt<8; ++kt){
        bf16x8 af = {};
        if (arow == 0) af = *reinterpret_cast<const bf16x8*>(hbf + kt*32 + ks*8);
        #pragma unroll
        for (int nt=0; nt<6; ++nt)
          sacc[nt] = __builtin_amdgcn_mfma_f32_16x16x32_bf16(af, whh[kt][nt], sacc[nt], 0,0,0);
      }
      if (ks == 0){     // D row0 lives in reg 0 of lanes 0..15
        #pragma unroll
        for (int nt=0; nt<6; ++nt) gh[wv*96 + nt*16 + arow] = sacc[nt][0];
      }
      __syncthreads();   // gh + GIw ready; hbf reads done
      if (tid < 256){
        const int c = tid;
        const float* gir = GIw + (size_t)dt*768;
        float rr = sigm(gir[c]     + gh[c]     + bcl[c]);
        float zz = sigm(gir[256+c] + gh[256+c] + bcl[256+c]);
        float nn = tanhf(gir[512+c] + bcl[512+c] + rr*(gh[512+c] + bcl[768+c]));
        h_reg = (1.f-zz)*nn + zz*h_reg;
        hbf[c] = f2bu(h_reg);
      }
      __syncthreads();   // hbf ready for next step
    }
  }
  if (tid < 256) p2[(size_t)g*256 + tid] = h_reg;
}

// ---------------- fused SAB attention, bf16 K/V: per (graph-in-chunk, 8 q-rows) ----
__global__ __launch_bounds__(256) void k_attn(float* __restrict__ Q, const __hip_bfloat16* __restrict__ K,
                       const __hip_bfloat16* __restrict__ V){
  __shared__ float Qs[8*256];
  __shared__ float S [8*512];
  __shared__ uint4 Ks[32*32];
  const int g = blockIdx.y, q0 = blockIdx.x*8, tid = threadIdx.x;
  const size_t gb = (size_t)g*512*256;
  for (int i=tid;i<2048;i+=256) Qs[i] = Q[gb + (size_t)q0*256 + i];
  const int q = tid>>5, kl = tid&31;
  const float* qp = Qs + q*256;
  float* Sq = S + q*512;
  for (int kt=0; kt<512; kt+=32){
    __syncthreads();
    for (int i=tid;i<1024;i+=256){
      int row = i>>5, c8 = i&31;
      Ks[row*32 + (c8^row)] =
        reinterpret_cast<const uint4*>(K + gb + (size_t)(kt+row)*256)[c8];
    }
    __syncthreads();
    float d = 0.f;
    #pragma unroll
    for (int c8=0;c8<32;++c8){
      uint4 kv = Ks[kl*32 + (c8^kl)];
      const float* qq = qp + c8*8;
      d += qq[0]*blo(kv.x) + qq[1]*bhi(kv.x) + qq[2]*blo(kv.y) + qq[3]*bhi(kv.y)
         + qq[4]*blo(kv.z) + qq[5]*bhi(kv.z) + qq[6]*blo(kv.w) + qq[7]*bhi(kv.w);
    }
    Sq[kt+kl] = d;
  }
  __syncthreads();
  float m = -3e38f;
  for (int j=kl;j<512;j+=32) m = fmaxf(m, Sq[j]);
  #pragma unroll
  for (int o=1;o<32;o<<=1) m = fmaxf(m, __shfl_xor(m,o));
  float sum = 0.f;
  for (int j=kl;j<512;j+=32){ float e = __expf((Sq[j]-m)*0.0625f); Sq[j]=e; sum+=e; }
  #pragma unroll
  for (int o=1;o<32;o<<=1) sum += __shfl_xor(sum,o);
  const float inv = 1.f/sum;
  __syncthreads();
  const int c0 = kl*8;
  float a0=0,a1=0,a2=0,a3=0,a4=0,a5=0,a6=0,a7=0;
  for (int k=0;k<512;++k){
    float a = Sq[k];
    uint4 vv = *reinterpret_cast<const uint4*>(V + gb + (size_t)k*256 + c0);
    a0+=a*blo(vv.x); a1+=a*bhi(vv.x); a2+=a*blo(vv.y); a3+=a*bhi(vv.y);
    a4+=a*blo(vv.z); a5+=a*bhi(vv.z); a6+=a*blo(vv.w); a7+=a*bhi(vv.w);
  }
  float* op = Q + gb + (size_t)(q0+q)*256 + c0;
  float4 o0 = {a0*inv,a1*inv,a2*inv,a3*inv};
  float4 o1 = {a4*inv,a5*inv,a6*inv,a7*inv};
  *reinterpret_cast<float4*>(op)   = o0;
  *reinterpret_cast<float4*>(op+4) = o1;
}

// ---------------- PMA attention (1 query per graph), chunked ----------------
__global__ __launch_bounds__(256) void k_attn2(const float* __restrict__ K2, const float* __restrict__ V2,
                        const float* __restrict__ qv, float* __restrict__ av2){
  int g = blockIdx.x, tid = threadIdx.x;
  __shared__ float qs[256];
  __shared__ float sc[512];
  __shared__ float red[4];
  qs[tid] = qv[tid];
  __syncthreads();
  const size_t gb = (size_t)g*512*256;
  float l0=0.f, l1=0.f;
  for (int j0=0;j0<2;++j0){
    int j = tid + j0*256;
    const float* kr = K2 + gb + (size_t)j*256;
    float a = 0.f;
    for (int c=0;c<256;c+=4){
      float4 k4 = *reinterpret_cast<const float4*>(kr + c);
      a += k4.x*qs[c] + k4.y*qs[c+1] + k4.z*qs[c+2] + k4.w*qs[c+3];
    }
    a *= 0.0625f;
    if (j0) l1=a; else l0=a;
  }
  float m = fmaxf(l0,l1);
  #pragma unroll
  for (int o=1;o<64;o<<=1) m = fmaxf(m, __shfl_xor(m,o));
  if ((tid&63)==0) red[tid>>6] = m;
  __syncthreads();
  m = fmaxf(fmaxf(red[0],red[1]), fmaxf(red[2],red[3]));
  __syncthreads();
  float e0 = __expf(l0-m), e1 = __expf(l1-m);
  sc[tid]=e0; sc[tid+256]=e1;
  float s = e0+e1;
  #pragma unroll
  for (int o=1;o<64;o<<=1) s += __shfl_xor(s,o);
  if ((tid&63)==0) red[tid>>6] = s;
  __syncthreads();
  s = red[0]+red[1]+red[2]+red[3];
  float invs = 1.f/s;
  float acc = 0.f;
  for (int j=0;j<512;++j) acc += sc[j] * V2[gb + (size_t)j*256 + tid];
  av2[(size_t)g*256+tid] = acc*invs;
}

// =====================================================================
extern "C" void kernel_launch(void* const* d_in, const int* in_sizes, int n_in,
                              void* d_out, int out_size, void* d_ws, size_t ws_size,
                              hipStream_t stream){
  const int*   x      = (const int*)  d_in[0];
  const int*   ei     = (const int*)  d_in[1];
  const float* emb_w  = (const float*)d_in[3];
  const float* c1_lW  = (const float*)d_in[4];
  const float* c1_lb  = (const float*)d_in[5];
  const float* c1_rW  = (const float*)d_in[6];
  const float* t1     = (const float*)d_in[7];
  const float* c2_lW  = (const float*)d_in[8];
  const float* c2_lb  = (const float*)d_in[9];
  const float* c2_rW  = (const float*)d_in[10];
  const float* t2     = (const float*)d_in[11];
  const float* mlp_W  = (const float*)d_in[12];
  const float* mlp_b  = (const float*)d_in[13];
  const float* gWih   = (const float*)d_in[14];
  const float* gWhh   = (const float*)d_in[15];
  const float* gbih   = (const float*)d_in[16];
  const float* gbhh   = (const float*)d_in[17];
  const float* stWq   = (const float*)d_in[18];
  const float* stbq   = (const float*)d_in[19];
  const float* stWk   = (const float*)d_in[20];
  const float* stbk   = (const float*)d_in[21];
  const float* stWv   = (const float*)d_in[22];
  const float* stbv   = (const float*)d_in[23];
  const float* stWo   = (const float*)d_in[24];
  const float* stbo   = (const float*)d_in[25];
  const float* stlW   = (const float*)d_in[26];
  const float* stlb   = (const float*)d_in[27];
  const float* pma_lW = (const float*)d_in[28];
  const float* pma_lb = (const float*)d_in[29];
  const float* seed   = (const float*)d_in[30];
  const float* fin_W  = (const float*)d_in[31];
  const float* fin_b  = (const float*)d_in[32];
  float* out = (float*)d_out;

  // ---- choose chunk size by available workspace ----
  auto needFor = [](int CHe)->size_t{
    size_t bufN = (size_t)CHe*512*512;
    size_t floats = (size_t)33554432 + 3*bufN + 2*524288 + 2*196608 + 8*65536 + 196608 + 320;
    size_t ints   = 131072 + 131200 + 131072 + 262144 + 128 + 128;
    return floats*4 + ints*4 + 4096;
  };
  const int CHe = (ws_size >= needFor(64)) ? 64 : 32;
  if (ws_size < needFor(32)) return;
  const int NCHUNKe = BG / CHe;
  const int NCNe = CHe * 512;
  const size_t bufN = (size_t)CHe*512*512;

  // ---- workspace carve ----
  float* H2   = (float*)d_ws;                    // NN*256 f32 (persists)
  float* bufA = H2   + (size_t)33554432;         // CHe*512*512 (conv fused staging / ST bufs)
  float* bufB = bufA + bufN;
  float* bufC = bufB + bufN;
  float* h0   = bufC + bufN;                     // NN*4
  float* ag1  = h0   + (size_t)524288;           // NN*4
  float* wT1  = ag1  + (size_t)524288;           // GRU packs (pIh/pHh)
  float* wT2  = wT1  + (size_t)196608;           // pC2 + bcomb
  float* p1   = wT2  + (size_t)196608;
  float* p2   = p1   + (size_t)65536;
  float* p3   = p2   + (size_t)65536;
  float* av2  = p3   + (size_t)65536;
  float* s1   = av2  + (size_t)65536;
  float* s2v  = s1   + (size_t)65536;
  float* v3   = s2v  + (size_t)65536;
  float* h3   = v3   + (size_t)65536;
  float* pooled = h3 + (size_t)65536;
  float* qv   = pooled + (size_t)196608;
  int*   deg  = (int*)(qv + 320);
  int*   offs = deg  + 131072;
  int*   cur  = offs + 131200;
  int*   esrc = cur  + 131072;
  int*   bsum = esrc + 262144;
  int*   boff = bsum + 128;

  ushort* pIh  = (ushort*)wT1;                   // 196608 ush
  ushort* pHh  = (ushort*)(wT1 + 98304);         // 196608 ush
  ushort* pC2  = (ushort*)wT2;                   // 131072 ush (k 0..255=rW, 256..511=lW)
  float*  bcomb= wT2 + 65536;                    // 1024 f32
  float*  pa   = h0;                             // dead after conv phase -> ST packs
  ushort* pQ0  = (ushort*)(pa);
  ushort* pK0  = (ushort*)(pa + 32768);
  ushort* pV0  = (ushort*)(pa + 65536);
  ushort* pO0  = (ushort*)(pa + 98304);
  ushort* pL0  = (ushort*)(pa + 131072);
  ushort* pPma = (ushort*)(pa + 163840);
  ushort* pK1  = (ushort*)(pa + 196608);
  ushort* pV1  = (ushort*)(pa + 229376);
  ushort* pO1  = (ushort*)(pa + 262144);
  ushort* pL1  = (ushort*)(pa + 294912);
  ushort* pV2  = (ushort*)(pa + 327680);
  ushort* pO2  = (ushort*)(pa + 360448);
  ushort* pL2  = (ushort*)(pa + 393216);
  ushort* pFin = (ushort*)(pa + 425984);

  const int ls0 = 65536, ls1 = 256;

  // ---- 1. node encoder ----
  k_node_enc<<<NN/256, 256, 0, stream>>>(x, emb_w, h0);

  // ---- 2. CSR ----
  k_zero<<<NN/256, 256, 0, stream>>>(deg, NN);
  k_count<<<NE/256, 256, 0, stream>>>(ei, deg);
  k_blocksum<<<128, 256, 0, stream>>>(deg, bsum);
  k_scanbsum<<<1, 128, 0, stream>>>(bsum, boff, offs + NN);
  k_scanchunk<<<128, 256, 0, stream>>>(deg, boff, offs);
  k_zero<<<NN/256, 256, 0, stream>>>(cur, NN);
  k_fill<<<NE/256, 256, 0, stream>>>(ei, offs, cur, esrc);

  // ---- 3. conv1 aggregation + early packs ----
  k_aggr4<<<NN/256, 256, 0, stream>>>(h0, offs, esrc, t1, ag1);
  k_packb <<<256, 256, 0, stream>>>(c2_rW, pC2, 256, 256);            // A cols 0..255 = h1
  k_packb <<<256, 256, 0, stream>>>(c2_lW, pC2 + 65536, 256, 256);    // A cols 256..511 = ag
  k_packbT<<<768, 256, 0, stream>>>(gWih, pIh, 256, 768);
  k_packbT<<<768, 256, 0, stream>>>(gWhh, pHh, 256, 768);
  k_packbias<<<4, 256, 0, stream>>>(gbih, gbhh, bcomb);

  // ---- 4. conv1 + conv2 (fused K=512), chunked ----
  for (int cg = 0; cg < NCHUNKe; ++cg){
    const int base = cg * NCNe;
    float* Hc = H2 + (size_t)base * 256;
    const dim3 gg(NCNe/128, 2, 1);
    k_conv1_lin<<<NCNe, 256, 0, stream>>>(ag1, h0, c1_lW, c1_lb, c1_rW, bufA, base);
    k_aggr256<<<NCNe, 256, 0, stream>>>(bufA, offs, esrc, t2, base);
    k_bgemm<GF_BIAS|GF_RELU><<<gg, 256, 0, stream>>>(bufA, pC2, c2_lb, nullptr, Hc, NCNe, 256, 512, 512);
  }
  // H2 = h2 (full)

  // ---- 5. p1 = MLP pool (M=256, K=131072, split-K atomic, f32) ----
  k_rowbias<<<256, 256, 0, stream>>>(mlp_b, p1, 256, 65536);
  k_gemm<GF_ATOMIC><<<dim3(2, 2, 64), 256, 0, stream>>>(H2, mlp_W, nullptr, nullptr, p1, 256, 256, NN);

  // ---- 6. GRU v8 (register-resident Whh, LDS gi windows; 256 blocks) ----
  k_gru8<<<BG, 512, 105984, stream>>>(H2, pIh, pHh, bcomb, p2);

  // ---- 7. ST packs + set transformer, chunked ----
  k_packb<<<256, 256, 0, stream>>>(stWq,        pQ0, 256, 256);
  k_packb<<<256, 256, 0, stream>>>(stWk,        pK0, 256, 256);
  k_packb<<<256, 256, 0, stream>>>(stWv,        pV0, 256, 256);
  k_packb<<<256, 256, 0, stream>>>(stWo,        pO0, 256, 256);
  k_packb<<<256, 256, 0, stream>>>(stlW,        pL0, 256, 256);
  k_packb<<<256, 256, 0, stream>>>(pma_lW,      pPma,256, 256);
  k_packb<<<256, 256, 0, stream>>>(stWk + ls0,  pK1, 256, 256);
  k_packb<<<256, 256, 0, stream>>>(stWv + ls0,  pV1, 256, 256);
  k_packb<<<256, 256, 0, stream>>>(stWo + ls0,  pO1, 256, 256);
  k_packb<<<256, 256, 0, stream>>>(stlW + ls0,  pL1, 256, 256);
  k_packb<<<256, 256, 0, stream>>>(stWv + 2*ls0,pV2, 256, 256);
  k_packb<<<256, 256, 0, stream>>>(stWo + 2*ls0,pO2, 256, 256);
  k_packb<<<256, 256, 0, stream>>>(stlW + 2*ls0,pL2, 256, 256);
  k_packb<<<2304, 256, 0, stream>>>(fin_W,      pFin,768, 768);
  k_qvec<<<1, 256, 0, stream>>>(seed, stWq + ls0, stbq + ls1, qv);

  for (int cg = 0; cg < NCHUNKe; ++cg){
    const int base = cg * NCNe;
    float* Hc = H2 + (size_t)base * 256;
    const dim3 gg(NCNe/128, 2, 1);
    k_bgemm<GF_BIAS><<<gg, 256, 0, stream>>>(Hc, pQ0, stbq, nullptr, bufA, NCNe, 256, 256, 256);          // Q f32
    k_bgemm<GF_BIAS|GF_BF16><<<gg, 256, 0, stream>>>(Hc, pK0, stbk, nullptr, bufB, NCNe, 256, 256, 256);  // K bf16
    k_bgemm<GF_BIAS|GF_BF16><<<gg, 256, 0, stream>>>(Hc, pV0, stbv, nullptr, bufC, NCNe, 256, 256, 256);  // V bf16
    k_attn<<<dim3(64, CHe), 256, 0, stream>>>(bufA, (const __hip_bfloat16*)bufB, (const __hip_bfloat16*)bufC);
    k_bgemm<GF_BIAS|GF_RESID><<<gg, 256, 0, stream>>>(bufA, pO0, stbo, Hc, Hc, NCNe, 256, 256, 256);      // h_sab in-place
    k_bgemm<GF_BIAS|GF_RELU|GF_RESID><<<gg, 256, 0, stream>>>(Hc, pL0, stlb, Hc, bufA, NCNe, 256, 256, 256); // h_enc
    k_bgemm<GF_BIAS|GF_RELU><<<gg, 256, 0, stream>>>(bufA, pPma, pma_lb, nullptr, bufB, NCNe, 256, 256, 256); // kk
    k_bgemm<GF_BIAS><<<gg, 256, 0, stream>>>(bufB, pK1, stbk + ls1, nullptr, bufA, NCNe, 256, 256, 256);  // K2 f32
    k_bgemm<GF_BIAS><<<gg, 256, 0, stream>>>(bufB, pV1, stbv + ls1, nullptr, bufC, NCNe, 256, 256, 256);  // V2 f32
    k_attn2<<<CHe, 256, 0, stream>>>(bufA, bufC, qv, av2 + (size_t)cg*CHe*256);
  }

  // ---- 8. PMA tail + decoder SAB ----
  k_bgemm<GF_BIAS|GF_RESID_B><<<dim3(2, 2, 1), 256, 0, stream>>>(av2, pO1, stbo + ls1, seed, s1, 256, 256, 256, 256);
  k_bgemm<GF_BIAS|GF_RELU|GF_RESID><<<dim3(2, 2, 1), 256, 0, stream>>>(s1, pL1, stlb + ls1, s1, s2v, 256, 256, 256, 256);
  k_bgemm<GF_BIAS><<<dim3(2, 2, 1), 256, 0, stream>>>(s2v, pV2, stbv + 2*ls1, nullptr, v3, 256, 256, 256, 256);
  k_bgemm<GF_BIAS|GF_RESID><<<dim3(2, 2, 1), 256, 0, stream>>>(v3, pO2, stbo + 2*ls1, s2v, h3, 256, 256, 256, 256);
  k_bgemm<GF_BIAS|GF_RELU|GF_RESID><<<dim3(2, 2, 1), 256, 0, stream>>>(h3, pL2, stlb + 2*ls1, h3, p3, 256, 256, 256, 256);

  // ---- 9. concat + final linear ----
  k_concat<<<768, 256, 0, stream>>>(p1, p2, p3, pooled);
  k_bgemm<GF_BIAS><<<dim3(2, 6, 1), 256, 0, stream>>>(pooled, pFin, fin_b, nullptr, out, 256, 768, 768, 768);
}

// Round 9
// 4014.313 us; speedup vs baseline: 3.0887x; 1.3506x over previous
//
#include <hip/hip_runtime.h>
#include <hip/hip_bf16.h>
#include <math.h>

// ---- problem constants ----
constexpr int NN   = 131072;   // total nodes (B*NPG)
constexpr int NE   = 262144;   // edges
constexpr int BG   = 256;      // graphs

typedef __bf16 bf16x8 __attribute__((ext_vector_type(8)));
typedef float  f32x4  __attribute__((ext_vector_type(4)));

__device__ inline float sigm(float x){ return 1.f/(1.f+__expf(-x)); }
__device__ inline unsigned short f2bu(float f){
  union{float f;unsigned u;}v; v.f=f;
  unsigned u = v.u + 0x7fffu + ((v.u>>16)&1u);
  return (unsigned short)(u>>16);
}
__device__ inline bf16x8 cvt8(float4 a, float4 b){
  union { ushort u[8]; bf16x8 v; } r;
  r.u[0]=f2bu(a.x); r.u[1]=f2bu(a.y); r.u[2]=f2bu(a.z); r.u[3]=f2bu(a.w);
  r.u[4]=f2bu(b.x); r.u[5]=f2bu(b.y); r.u[6]=f2bu(b.z); r.u[7]=f2bu(b.w);
  return r.v;
}

__global__ void k_zero(int* __restrict__ p, int n){
  int i = blockIdx.x*256 + threadIdx.x;
  if (i < n) p[i] = 0;
}

// ---------------- node encoder ----------------
__global__ void k_node_enc(const int* __restrict__ x, const float* __restrict__ emb,
                           float* __restrict__ h0){
  int n = blockIdx.x*256 + threadIdx.x;
  if (n >= NN) return;
  int nt = x[2*n], ninv = x[2*n+1];
  float4 v; v.x = emb[nt*3+0]; v.y = emb[nt*3+1]; v.z = emb[nt*3+2]; v.w = (float)ninv;
  reinterpret_cast<float4*>(h0)[n] = v;
}

// ---------------- CSR build (by dst) ----------------
__global__ void k_count(const int* __restrict__ ei, int* __restrict__ deg){
  int e = blockIdx.x*256 + threadIdx.x;
  if (e >= NE) return;
  atomicAdd(&deg[ei[NE + e]], 1);
}
__global__ void k_blocksum(const int* __restrict__ deg, int* __restrict__ bsum){
  __shared__ int sd[256];
  int t = threadIdx.x;
  const int* p = deg + blockIdx.x*1024;
  int s = p[t*4] + p[t*4+1] + p[t*4+2] + p[t*4+3];
  sd[t]=s; __syncthreads();
  for (int d=128; d>0; d>>=1){ if (t<d) sd[t]+=sd[t+d]; __syncthreads(); }
  if (!t) bsum[blockIdx.x] = sd[0];
}
__global__ void k_scanbsum(const int* __restrict__ bsum, int* __restrict__ boff, int* __restrict__ offN){
  __shared__ int s[128];
  int t = threadIdx.x;
  int mine = bsum[t];
  s[t]=mine; __syncthreads();
  for (int d=1; d<128; d<<=1){ int v = (t>=d)? s[t-d]:0; __syncthreads(); s[t]+=v; __syncthreads(); }
  boff[t] = s[t]-mine;
  if (t==127) offN[0] = s[127];
}
__global__ void k_scanchunk(const int* __restrict__ deg, const int* __restrict__ boff, int* __restrict__ offs){
  __shared__ int ts[256];
  int t = threadIdx.x, b = blockIdx.x;
  const int* p = deg + b*1024;
  int v0=p[t*4],v1=p[t*4+1],v2=p[t*4+2],v3=p[t*4+3];
  int mysum=v0+v1+v2+v3;
  ts[t]=mysum; __syncthreads();
  for (int d=1; d<256; d<<=1){ int v=(t>=d)?ts[t-d]:0; __syncthreads(); ts[t]+=v; __syncthreads(); }
  int ex = ts[t]-mysum + boff[b];
  int* o = offs + b*1024 + t*4;
  o[0]=ex; o[1]=ex+v0; o[2]=ex+v0+v1; o[3]=ex+v0+v1+v2;
}
__global__ void k_fill(const int* __restrict__ ei, const int* __restrict__ offs,
                       int* __restrict__ cur, int* __restrict__ esrc){
  int e = blockIdx.x*256 + threadIdx.x;
  if (e >= NE) return;
  int dst = ei[NE+e];
  int pos = offs[dst] + atomicAdd(&cur[dst],1);
  esrc[pos] = ei[e];
}

// ---------------- softmax aggregation, 4-channel (conv1), no-max (exact) ----------------
__global__ void k_aggr4(const float* __restrict__ h, const int* __restrict__ offs,
                        const int* __restrict__ esrc, const float* __restrict__ tptr,
                        float* __restrict__ ag){
  int n = blockIdx.x*256 + threadIdx.x;
  if (n >= NN) return;
  int s = offs[n], e = offs[n+1];
  float4 z = {0,0,0,0};
  if (s == e){ reinterpret_cast<float4*>(ag)[n] = z; return; }
  float t = *tptr;
  float4 num=z, den=z;
  for (int i=s;i<e;++i){
    float4 v = reinterpret_cast<const float4*>(h)[esrc[i]];
    float ex;
    ex=__expf(v.x*t); num.x+=v.x*ex; den.x+=ex;
    ex=__expf(v.y*t); num.y+=v.y*ex; den.y+=ex;
    ex=__expf(v.z*t); num.z+=v.z*ex; den.z+=ex;
    ex=__expf(v.w*t); num.w+=v.w*ex; den.w+=ex;
  }
  float4 r = {num.x/den.x, num.y/den.y, num.z/den.z, num.w/den.w};
  reinterpret_cast<float4*>(ag)[n] = r;
}

// ---------------- softmax aggregation (no-max, 1 pass), fused [h1|ag] layout ----------------
__global__ __launch_bounds__(256) void k_aggr256(float* __restrict__ buf, const int* __restrict__ offs,
                          const int* __restrict__ esrc, const float* __restrict__ tptr, int base){
  int n = base + blockIdx.x, c = threadIdx.x;
  int s = offs[n], e = offs[n+1];
  float* outp = buf + (size_t)blockIdx.x*512 + 256 + c;
  if (s == e){ *outp = 0.f; return; }
  float t = *tptr;
  float num=0.f, den=0.f;
  for (int i=s;i<e;++i){
    float v = buf[(size_t)(esrc[i]-base)*512 + c];
    float ex = __expf(v*t);
    num += v*ex; den += ex;
  }
  *outp = num/den;
}

// ---------------- conv1 linear (K=4, fused), writes [n][512] col 0..255 ----------------
__global__ __launch_bounds__(256) void k_conv1_lin(const float* __restrict__ ag, const float* __restrict__ h0,
                            const float* __restrict__ lW, const float* __restrict__ lb,
                            const float* __restrict__ rW, float* __restrict__ out, int base){
  int n = base + blockIdx.x, c = threadIdx.x;
  float4 a  = reinterpret_cast<const float4*>(ag)[n];
  float4 xv = reinterpret_cast<const float4*>(h0)[n];
  float acc = lb[c];
  acc += a.x*lW[c]  + a.y*lW[256+c]  + a.z*lW[512+c]  + a.w*lW[768+c];
  acc += xv.x*rW[c] + xv.y*rW[256+c] + xv.z*rW[512+c] + xv.w*rW[768+c];
  out[(size_t)blockIdx.x*512 + c] = fmaxf(acc, 0.f);
}

// ---------------- flags ----------------
#define GF_BIAS    1
#define GF_RELU    2
#define GF_RESID   4
#define GF_RESID_B 8
#define GF_ADDC    32
#define GF_ATOMIC  64
#define GF_BF16    128
#define GF_VTP     256   // write output as per-graph B-pack (for AV's V operand)

// ---------------- weight pack: f32 W[K][N] -> MFMA-B bf16 Bp[((k>>3)*N + j)*8 + (k&7)] ----
__global__ void k_packb(const float* __restrict__ W, ushort* __restrict__ Bp, int K, int N){
  int idx = blockIdx.x*256 + threadIdx.x;
  if (idx >= K*N) return;
  int k = idx / N, j = idx - k*N;
  Bp[((size_t)(k>>3)*N + j)*8 + (k&7)] = f2bu(W[idx]);
}
// transposed source: W is [N][K] row-major; B[k][j] = W[j][k]
__global__ void k_packbT(const float* __restrict__ W, ushort* __restrict__ Bp, int K, int N){
  int idx = blockIdx.x*256 + threadIdx.x;
  if (idx >= K*N) return;
  int j = idx / K, k = idx - j*K;
  Bp[((size_t)(k>>3)*N + j)*8 + (k&7)] = f2bu(W[idx]);
}
// combined GRU biases
__global__ void k_packbias(const float* __restrict__ gbih, const float* __restrict__ gbhh,
                           float* __restrict__ bc){
  int i = blockIdx.x*256 + threadIdx.x;
  if (i >= 1024) return;
  int c = i & 255;
  float v;
  if (i < 256)      v = gbih[c] + gbhh[c];
  else if (i < 512) v = gbih[256+c] + gbhh[256+c];
  else if (i < 768) v = gbih[512+c];
  else              v = gbhh[512+c];
  bc[i] = v;
}

// ---------------- MFMA GEMM: LDS-free, A f32 (cvt in-reg), B pre-packed bf16 ----------------
template<int FLAGS>
__global__ __launch_bounds__(256) void k_bgemm(const float* __restrict__ A, const ushort* __restrict__ Bp,
                       const float* __restrict__ bias, const float* __restrict__ resid,
                       float* __restrict__ C, int M, int Nn, int K, int lda){
  const int tid = threadIdx.x;
  const int wv = tid>>6, lane = tid&63;
  const int mw = wv>>1, nw = wv&1;
  const int arow = lane&15, ks = lane>>4;
  const int m0 = blockIdx.x*128 + mw*64, n0 = blockIdx.y*128 + nw*64;
  const int kChunk = K / gridDim.z, kBeg = blockIdx.z * kChunk;
  f32x4 acc[4][4] = {};
  const float* Arow0 = A + (size_t)(m0 + 0*16 + arow)*lda;
  const float* Arow1 = A + (size_t)(m0 + 1*16 + arow)*lda;
  const float* Arow2 = A + (size_t)(m0 + 2*16 + arow)*lda;
  const float* Arow3 = A + (size_t)(m0 + 3*16 + arow)*lda;
  #pragma unroll 2
  for (int k0 = kBeg; k0 < kBeg+kChunk; k0 += 32){
    const int kb = (k0>>3) + ks;
    bf16x8 af[4];
    {
      const float4* p0 = reinterpret_cast<const float4*>(Arow0 + k0 + ks*8);
      const float4* p1 = reinterpret_cast<const float4*>(Arow1 + k0 + ks*8);
      const float4* p2 = reinterpret_cast<const float4*>(Arow2 + k0 + ks*8);
      const float4* p3 = reinterpret_cast<const float4*>(Arow3 + k0 + ks*8);
      af[0] = cvt8(p0[0], p0[1]);
      af[1] = cvt8(p1[0], p1[1]);
      af[2] = cvt8(p2[0], p2[1]);
      af[3] = cvt8(p3[0], p3[1]);
    }
    #pragma unroll
    for (int nf=0; nf<4; ++nf){
      const int col = n0 + nf*16 + arow;
      bf16x8 bfr = *reinterpret_cast<const bf16x8*>(Bp + ((size_t)kb*Nn + col)*8);
      #pragma unroll
      for (int mf=0; mf<4; ++mf)
        acc[mf][nf] = __builtin_amdgcn_mfma_f32_16x16x32_bf16(af[mf], bfr, acc[mf][nf], 0, 0, 0);
    }
  }
  #pragma unroll
  for (int nf=0; nf<4; ++nf){
    const int n = n0 + nf*16 + arow;
    float bv  = (FLAGS & GF_BIAS)    ? bias[n]  : 0.f;
    float rbv = (FLAGS & GF_RESID_B) ? resid[n] : 0.f;
    #pragma unroll
    for (int mf=0; mf<4; ++mf){
      #pragma unroll
      for (int r=0; r<4; ++r){
        const int m = m0 + mf*16 + ks*4 + r;
        size_t idx = (size_t)m*Nn + n;
        float v = acc[mf][nf][r];
        if (FLAGS & GF_ATOMIC){ atomicAdd(&C[idx], v); }
        else {
          v += bv;
          if (FLAGS & GF_ADDC)  v += C[idx];
          if (FLAGS & GF_RELU)  v = fmaxf(v, 0.f);
          if (FLAGS & GF_RESID) v += resid[idx];
          v += rbv;
          if (FLAGS & GF_VTP){
            const int rr = m & 511, mg = m >> 9;
            ((ushort*)C)[(size_t)mg*131072 + (((rr>>3)*256 + n)<<3) + (rr&7)] = f2bu(v);
          }
          else if (FLAGS & GF_BF16) reinterpret_cast<__hip_bfloat16*>(C)[idx] = __float2bfloat16(v);
          else C[idx] = v;
        }
      }
    }
  }
}

// ---------------- batched QK^T: S[g][q][k] = Q[g*512+q][:] . K[g*512+k][:] ----------------
// B-fragment read DIRECTLY from row-major bf16 K: frag = K[key_row][kb*8..+8] (16B).
__global__ __launch_bounds__(256) void k_qk(const float* __restrict__ Q, const ushort* __restrict__ Kb,
                                            float* __restrict__ S){
  const int tid = threadIdx.x;
  const int wv = tid>>6, lane = tid&63;
  const int mw = wv>>1, nw = wv&1;
  const int arow = lane&15, ks = lane>>4;
  const int m0 = blockIdx.x*128 + mw*64;      // global q row in chunk
  const int n0 = blockIdx.y*128 + nw*64;      // key index 0..511
  const int g  = blockIdx.x>>2;
  const ushort* Kg = Kb + (size_t)g*131072;
  f32x4 acc[4][4] = {};
  const float* Ar0 = Q + (size_t)(m0 + 0*16 + arow)*256;
  const float* Ar1 = Q + (size_t)(m0 + 1*16 + arow)*256;
  const float* Ar2 = Q + (size_t)(m0 + 2*16 + arow)*256;
  const float* Ar3 = Q + (size_t)(m0 + 3*16 + arow)*256;
  #pragma unroll
  for (int k0 = 0; k0 < 256; k0 += 32){
    bf16x8 af[4];
    {
      const float4* p0 = reinterpret_cast<const float4*>(Ar0 + k0 + ks*8);
      const float4* p1 = reinterpret_cast<const float4*>(Ar1 + k0 + ks*8);
      const float4* p2 = reinterpret_cast<const float4*>(Ar2 + k0 + ks*8);
      const float4* p3 = reinterpret_cast<const float4*>(Ar3 + k0 + ks*8);
      af[0] = cvt8(p0[0], p0[1]);
      af[1] = cvt8(p1[0], p1[1]);
      af[2] = cvt8(p2[0], p2[1]);
      af[3] = cvt8(p3[0], p3[1]);
    }
    #pragma unroll
    for (int nf=0; nf<4; ++nf){
      const int j = n0 + nf*16 + arow;        // key row
      bf16x8 bfr = *reinterpret_cast<const bf16x8*>(Kg + (size_t)j*256 + k0 + ks*8);
      #pragma unroll
      for (int mf=0; mf<4; ++mf)
        acc[mf][nf] = __builtin_amdgcn_mfma_f32_16x16x32_bf16(af[mf], bfr, acc[mf][nf], 0, 0, 0);
    }
  }
  #pragma unroll
  for (int nf=0; nf<4; ++nf){
    const int n = n0 + nf*16 + arow;
    #pragma unroll
    for (int mf=0; mf<4; ++mf){
      #pragma unroll
      for (int r=0; r<4; ++r){
        const int m = m0 + mf*16 + ks*4 + r;
        S[(size_t)m*512 + n] = acc[mf][nf][r];
      }
    }
  }
}

// ---------------- row softmax (scale 1/16), f32 S -> normalized bf16 P ----------------
__global__ __launch_bounds__(256) void k_smrow(const float* __restrict__ S, ushort* __restrict__ P){
  const int row = blockIdx.x, tid = threadIdx.x;
  __shared__ float red[4];
  const float* sr = S + (size_t)row*512;
  float s0 = sr[tid], s1 = sr[tid+256];
  float m = fmaxf(s0, s1);
  #pragma unroll
  for (int o=1;o<64;o<<=1) m = fmaxf(m, __shfl_xor(m,o));
  if ((tid&63)==0) red[tid>>6] = m;
  __syncthreads();
  m = fmaxf(fmaxf(red[0],red[1]), fmaxf(red[2],red[3]));
  __syncthreads();
  float e0 = __expf((s0-m)*0.0625f), e1 = __expf((s1-m)*0.0625f);
  float s = e0+e1;
  #pragma unroll
  for (int o=1;o<64;o<<=1) s += __shfl_xor(s,o);
  if ((tid&63)==0) red[tid>>6] = s;
  __syncthreads();
  s = red[0]+red[1]+red[2]+red[3];
  float inv = 1.f/s;
  P[(size_t)row*512 + tid]       = f2bu(e0*inv);
  P[(size_t)row*512 + 256 + tid] = f2bu(e1*inv);
}

// ---------------- batched AV: O[g*512+q][c] = sum_k P[q][k] V[k][c] ----------------
// A = P bf16 direct frags; B = per-graph packed VTp.
__global__ __launch_bounds__(256) void k_av(const ushort* __restrict__ Pb, const ushort* __restrict__ VTp,
                                            float* __restrict__ O){
  const int tid = threadIdx.x;
  const int wv = tid>>6, lane = tid&63;
  const int mw = wv>>1, nw = wv&1;
  const int arow = lane&15, ks = lane>>4;
  const int m0 = blockIdx.x*128 + mw*64;
  const int n0 = blockIdx.y*128 + nw*64;      // c 0..255
  const int g  = blockIdx.x>>2;
  const ushort* Vg = VTp + (size_t)g*131072;
  f32x4 acc[4][4] = {};
  const ushort* Pr0 = Pb + (size_t)(m0 + 0*16 + arow)*512;
  const ushort* Pr1 = Pb + (size_t)(m0 + 1*16 + arow)*512;
  const ushort* Pr2 = Pb + (size_t)(m0 + 2*16 + arow)*512;
  const ushort* Pr3 = Pb + (size_t)(m0 + 3*16 + arow)*512;
  #pragma unroll 2
  for (int k0 = 0; k0 < 512; k0 += 32){
    const int kb = (k0>>3) + ks;
    bf16x8 af[4];
    af[0] = *reinterpret_cast<const bf16x8*>(Pr0 + k0 + ks*8);
    af[1] = *reinterpret_cast<const bf16x8*>(Pr1 + k0 + ks*8);
    af[2] = *reinterpret_cast<const bf16x8*>(Pr2 + k0 + ks*8);
    af[3] = *reinterpret_cast<const bf16x8*>(Pr3 + k0 + ks*8);
    #pragma unroll
    for (int nf=0; nf<4; ++nf){
      const int col = n0 + nf*16 + arow;
      bf16x8 bfr = *reinterpret_cast<const bf16x8*>(Vg + ((size_t)kb*256 + col)*8);
      #pragma unroll
      for (int mf=0; mf<4; ++mf)
        acc[mf][nf] = __builtin_amdgcn_mfma_f32_16x16x32_bf16(af[mf], bfr, acc[mf][nf], 0, 0, 0);
    }
  }
  #pragma unroll
  for (int nf=0; nf<4; ++nf){
    const int n = n0 + nf*16 + arow;
    #pragma unroll
    for (int mf=0; mf<4; ++mf){
      #pragma unroll
      for (int r=0; r<4; ++r){
        const int m = m0 + mf*16 + ks*4 + r;
        O[(size_t)m*256 + n] = acc[mf][nf][r];
      }
    }
  }
}

// ---------------- small utilities ----------------
__global__ void k_rowbias(const float* __restrict__ bias, float* __restrict__ C, int Nn, int total){
  int i = blockIdx.x*256 + threadIdx.x;
  if (i < total) C[i] = bias[i % Nn];
}
__global__ void k_qvec(const float* __restrict__ seed, const float* __restrict__ Wq,
                       const float* __restrict__ bq, float* __restrict__ qv){
  __shared__ float s[256];
  int t = threadIdx.x;
  s[t] = seed[t]; __syncthreads();
  float acc = bq[t];
  for (int c = 0; c < 256; ++c) acc += s[c] * Wq[c*256 + t];
  qv[t] = acc;
}
__global__ void k_concat(const float* __restrict__ p1, const float* __restrict__ p2,
                         const float* __restrict__ p3, float* __restrict__ pooled){
  int idx = blockIdx.x*256 + threadIdx.x;
  int b = idx / 768, j = idx % 768;
  float v = (j < 256) ? p1[b*256+j] : (j < 512) ? p2[b*256+j-256] : p3[b*256+j-512];
  pooled[idx] = v;
}

// ---------------- GRU v9: 1 graph/block, 256 blocks, 256 thr (4 waves) ----------------
// Register-resident Whh: wave wv holds cols [wv*192, +192) = 96 bf16x8 frags (384 VGPR),
// asm-pinned. 4-wave block => 1 wave/SIMD => 512-VGPR budget (m08: no spill <=450).
// MFMA/gate phases split in halves to cap peak pressure.
__global__ __launch_bounds__(256,1) void k_gru9(const float* __restrict__ X,
                      const ushort* __restrict__ pIh, const ushort* __restrict__ pHh,
                      const float* __restrict__ bc, float* __restrict__ p2){
  extern __shared__ char gsm[];
  float*  GIw = (float*)gsm;                    // [32][768]  98304 B
  float*  gh  = (float*)(gsm + 98304);          // [768]
  float*  bcl = (float*)(gsm + 101376);         // [1024]
  ushort* hbf = (ushort*)(gsm + 105472);        // [256]
  const int g = blockIdx.x;
  const int tid = threadIdx.x;
  const int wv = tid>>6, lane = tid&63;
  const int arow = lane&15, ks = lane>>4;
  bf16x8 whh[8][12];
  #pragma unroll
  for (int kt=0;kt<8;++kt)
    #pragma unroll
    for (int nt=0;nt<12;++nt)
      whh[kt][nt] = *reinterpret_cast<const bf16x8*>(pHh + ((size_t)(kt*4+ks)*768 + wv*192+nt*16+arow)*8);
  #pragma unroll
  for (int kt=0;kt<8;++kt)
    #pragma unroll
    for (int nt=0;nt<12;++nt)
      asm volatile("" : "+v"(whh[kt][nt]));
  for (int i=tid;i<1024;i+=256) bcl[i] = bc[i];
  hbf[tid] = 0;
  float h_reg = 0.f;
  const float* Xg = X + (size_t)g*512*256;
  __syncthreads();
  for (int w=0; w<16; ++w){
    const int t0 = w*32;
    // ---- window GEMM: GIw[32][768] = X[t0..+32][256] @ Wih (per-wave 192-col stripe) ----
    #pragma unroll
    for (int mt=0; mt<2; ++mt){
      const float* xr = Xg + (size_t)(t0 + mt*16 + arow)*256;
      #pragma unroll
      for (int half=0; half<2; ++half){
        f32x4 acc[6] = {};
        #pragma unroll
        for (int kt=0; kt<8; ++kt){
          const float4* xp = reinterpret_cast<const float4*>(xr + kt*32 + ks*8);
          bf16x8 af = cvt8(xp[0], xp[1]);
          #pragma unroll
          for (int nt=0; nt<6; ++nt){
            const int col = wv*192 + (half*6+nt)*16 + arow;
            bf16x8 bfr = *reinterpret_cast<const bf16x8*>(pIh + ((size_t)(kt*4+ks)*768 + col)*8);
            acc[nt] = __builtin_amdgcn_mfma_f32_16x16x32_bf16(af, bfr, acc[nt], 0,0,0);
          }
        }
        #pragma unroll
        for (int nt=0; nt<6; ++nt){
          const int col = wv*192 + (half*6+nt)*16 + arow;
          #pragma unroll
          for (int r=0;r<4;++r)
            GIw[(size_t)(mt*16 + ks*4 + r)*768 + col] = acc[nt][r];
        }
      }
    }
    // GIw published by the barrier inside the first step
    for (int dt=0; dt<32; ++dt){
      #pragma unroll
      for (int half=0; half<2; ++half){
        f32x4 sacc[6] = {};
        #pragma unroll
        for (int kt=0; kt<8; ++kt){
          bf16x8 af = {};
          if (arow == 0) af = *reinterpret_cast<const bf16x8*>(hbf + kt*32 + ks*8);
          #pragma unroll
          for (int nt=0; nt<6; ++nt)
            sacc[nt] = __builtin_amdgcn_mfma_f32_16x16x32_bf16(af, whh[kt][half*6+nt], sacc[nt], 0,0,0);
        }
        if (ks == 0){
          #pragma unroll
          for (int nt=0; nt<6; ++nt) gh[wv*192 + (half*6+nt)*16 + arow] = sacc[nt][0];
        }
      }
      __syncthreads();   // gh + GIw ready; hbf reads done
      {
        const int c = tid;
        const float* gir = GIw + (size_t)dt*768;
        float rr = sigm(gir[c]     + gh[c]     + bcl[c]);
        float zz = sigm(gir[256+c] + gh[256+c] + bcl[256+c]);
        float nn = tanhf(gir[512+c] + bcl[512+c] + rr*(gh[512+c] + bcl[768+c]));
        h_reg = (1.f-zz)*nn + zz*h_reg;
        hbf[c] = f2bu(h_reg);
      }
      __syncthreads();   // hbf ready for next step
    }
  }
  p2[(size_t)g*256 + tid] = h_reg;
}

// ---------------- PMA attention (1 query per graph), chunked ----------------
__global__ __launch_bounds__(256) void k_attn2(const float* __restrict__ K2, const float* __restrict__ V2,
                        const float* __restrict__ qv, float* __restrict__ av2){
  int g = blockIdx.x, tid = threadIdx.x;
  __shared__ float qs[256];
  __shared__ float sc[512];
  __shared__ float red[4];
  qs[tid] = qv[tid];
  __syncthreads();
  const size_t gb = (size_t)g*512*256;
  float l0=0.f, l1=0.f;
  for (int j0=0;j0<2;++j0){
    int j = tid + j0*256;
    const float* kr = K2 + gb + (size_t)j*256;
    float a = 0.f;
    for (int c=0;c<256;c+=4){
      float4 k4 = *reinterpret_cast<const float4*>(kr + c);
      a += k4.x*qs[c] + k4.y*qs[c+1] + k4.z*qs[c+2] + k4.w*qs[c+3];
    }
    a *= 0.0625f;
    if (j0) l1=a; else l0=a;
  }
  float m = fmaxf(l0,l1);
  #pragma unroll
  for (int o=1;o<64;o<<=1) m = fmaxf(m, __shfl_xor(m,o));
  if ((tid&63)==0) red[tid>>6] = m;
  __syncthreads();
  m = fmaxf(fmaxf(red[0],red[1]), fmaxf(red[2],red[3]));
  __syncthreads();
  float e0 = __expf(l0-m), e1 = __expf(l1-m);
  sc[tid]=e0; sc[tid+256]=e1;
  float s = e0+e1;
  #pragma unroll
  for (int o=1;o<64;o<<=1) s += __shfl_xor(s,o);
  if ((tid&63)==0) red[tid>>6] = s;
  __syncthreads();
  s = red[0]+red[1]+red[2]+red[3];
  float invs = 1.f/s;
  float acc = 0.f;
  for (int j=0;j<512;++j) acc += sc[j] * V2[gb + (size_t)j*256 + tid];
  av2[(size_t)g*256+tid] = acc*invs;
}

// =====================================================================
extern "C" void kernel_launch(void* const* d_in, const int* in_sizes, int n_in,
                              void* d_out, int out_size, void* d_ws, size_t ws_size,
                              hipStream_t stream){
  const int*   x      = (const int*)  d_in[0];
  const int*   ei     = (const int*)  d_in[1];
  const float* emb_w  = (const float*)d_in[3];
  const float* c1_lW  = (const float*)d_in[4];
  const float* c1_lb  = (const float*)d_in[5];
  const float* c1_rW  = (const float*)d_in[6];
  const float* t1     = (const float*)d_in[7];
  const float* c2_lW  = (const float*)d_in[8];
  const float* c2_lb  = (const float*)d_in[9];
  const float* c2_rW  = (const float*)d_in[10];
  const float* t2     = (const float*)d_in[11];
  const float* mlp_W  = (const float*)d_in[12];
  const float* mlp_b  = (const float*)d_in[13];
  const float* gWih   = (const float*)d_in[14];
  const float* gWhh   = (const float*)d_in[15];
  const float* gbih   = (const float*)d_in[16];
  const float* gbhh   = (const float*)d_in[17];
  const float* stWq   = (const float*)d_in[18];
  const float* stbq   = (const float*)d_in[19];
  const float* stWk   = (const float*)d_in[20];
  const float* stbk   = (const float*)d_in[21];
  const float* stWv   = (const float*)d_in[22];
  const float* stbv   = (const float*)d_in[23];
  const float* stWo   = (const float*)d_in[24];
  const float* stbo   = (const float*)d_in[25];
  const float* stlW   = (const float*)d_in[26];
  const float* stlb   = (const float*)d_in[27];
  const float* pma_lW = (const float*)d_in[28];
  const float* pma_lb = (const float*)d_in[29];
  const float* seed   = (const float*)d_in[30];
  const float* fin_W  = (const float*)d_in[31];
  const float* fin_b  = (const float*)d_in[32];
  float* out = (float*)d_out;

  // ---- choose chunk size by available workspace ----
  auto needFor = [](int CHe)->size_t{
    size_t bufN = (size_t)CHe*512*512;
    size_t floats = (size_t)33554432 + 3*bufN + 2*524288 + 2*196608 + 8*65536 + 196608 + 320;
    size_t ints   = 131072 + 131200 + 131072 + 262144 + 128 + 128;
    return floats*4 + ints*4 + 4096;
  };
  const int CHe = (ws_size >= needFor(64)) ? 64 : 32;
  if (ws_size < needFor(32)) return;
  const int NCHUNKe = BG / CHe;
  const int NCNe = CHe * 512;
  const size_t bufN = (size_t)CHe*512*512;

  // ---- workspace carve ----
  float* H2   = (float*)d_ws;                    // NN*256 f32 (persists)
  float* bufA = H2   + (size_t)33554432;         // bufN floats
  float* bufB = bufA + bufN;
  float* bufC = bufB + bufN;
  float* h0   = bufC + bufN;                     // NN*4
  float* ag1  = h0   + (size_t)524288;           // NN*4
  float* wT1  = ag1  + (size_t)524288;           // GRU packs (pIh/pHh)
  float* wT2  = wT1  + (size_t)196608;           // pC2 + bcomb
  float* p1   = wT2  + (size_t)196608;
  float* p2   = p1   + (size_t)65536;
  float* p3   = p2   + (size_t)65536;
  float* av2  = p3   + (size_t)65536;
  float* s1   = av2  + (size_t)65536;
  float* s2v  = s1   + (size_t)65536;
  float* v3   = s2v  + (size_t)65536;
  float* h3   = v3   + (size_t)65536;
  float* pooled = h3 + (size_t)65536;
  float* qv   = pooled + (size_t)196608;
  int*   deg  = (int*)(qv + 320);
  int*   offs = deg  + 131072;
  int*   cur  = offs + 131200;
  int*   esrc = cur  + 131072;
  int*   bsum = esrc + 262144;
  int*   boff = bsum + 128;

  ushort* pIh  = (ushort*)wT1;                   // 196608 ush
  ushort* pHh  = (ushort*)(wT1 + 98304);         // 196608 ush
  ushort* pC2  = (ushort*)wT2;                   // 131072 ush
  float*  bcomb= wT2 + 65536;                    // 1024 f32
  float*  pa   = h0;                             // dead after conv -> ST packs
  ushort* pQ0  = (ushort*)(pa);
  ushort* pK0  = (ushort*)(pa + 32768);
  ushort* pV0  = (ushort*)(pa + 65536);
  ushort* pO0  = (ushort*)(pa + 98304);
  ushort* pL0  = (ushort*)(pa + 131072);
  ushort* pPma = (ushort*)(pa + 163840);
  ushort* pK1  = (ushort*)(pa + 196608);
  ushort* pV1  = (ushort*)(pa + 229376);
  ushort* pO1  = (ushort*)(pa + 262144);
  ushort* pL1  = (ushort*)(pa + 294912);
  ushort* pV2  = (ushort*)(pa + 327680);
  ushort* pO2  = (ushort*)(pa + 360448);
  ushort* pL2  = (ushort*)(pa + 393216);
  ushort* pFin = (ushort*)(pa + 425984);

  // attention sub-buffers (inside bufA/bufB/bufC)
  ushort* VTp = (ushort*)(bufA + bufN/2);        // per-graph packed V (bufN/4 floats)
  ushort* Kbf = (ushort*)bufB;                   // K bf16 rows (bufN/4 floats)
  ushort* Pbf = (ushort*)(bufB + bufN/4);        // P bf16 (bufN/2 floats)

  const int ls0 = 65536, ls1 = 256;

  // ---- 1. node encoder ----
  k_node_enc<<<NN/256, 256, 0, stream>>>(x, emb_w, h0);

  // ---- 2. CSR ----
  k_zero<<<NN/256, 256, 0, stream>>>(deg, NN);
  k_count<<<NE/256, 256, 0, stream>>>(ei, deg);
  k_blocksum<<<128, 256, 0, stream>>>(deg, bsum);
  k_scanbsum<<<1, 128, 0, stream>>>(bsum, boff, offs + NN);
  k_scanchunk<<<128, 256, 0, stream>>>(deg, boff, offs);
  k_zero<<<NN/256, 256, 0, stream>>>(cur, NN);
  k_fill<<<NE/256, 256, 0, stream>>>(ei, offs, cur, esrc);

  // ---- 3. conv1 aggregation + early packs ----
  k_aggr4<<<NN/256, 256, 0, stream>>>(h0, offs, esrc, t1, ag1);
  k_packb <<<256, 256, 0, stream>>>(c2_rW, pC2, 256, 256);
  k_packb <<<256, 256, 0, stream>>>(c2_lW, pC2 + 65536, 256, 256);
  k_packbT<<<768, 256, 0, stream>>>(gWih, pIh, 256, 768);
  k_packbT<<<768, 256, 0, stream>>>(gWhh, pHh, 256, 768);
  k_packbias<<<4, 256, 0, stream>>>(gbih, gbhh, bcomb);

  // ---- 4. conv1 + conv2 (fused K=512), chunked ----
  for (int cg = 0; cg < NCHUNKe; ++cg){
    const int base = cg * NCNe;
    float* Hc = H2 + (size_t)base * 256;
    const dim3 gg(NCNe/128, 2, 1);
    k_conv1_lin<<<NCNe, 256, 0, stream>>>(ag1, h0, c1_lW, c1_lb, c1_rW, bufA, base);
    k_aggr256<<<NCNe, 256, 0, stream>>>(bufA, offs, esrc, t2, base);
    k_bgemm<GF_BIAS|GF_RELU><<<gg, 256, 0, stream>>>(bufA, pC2, c2_lb, nullptr, Hc, NCNe, 256, 512, 512);
  }
  // H2 = h2 (full)

  // ---- 5. p1 = MLP pool via MFMA (pack mlp_W bf16 into free bufB; split-K atomic) ----
  k_packb<<<131072, 256, 0, stream>>>(mlp_W, (ushort*)bufB, 131072, 256);
  k_rowbias<<<256, 256, 0, stream>>>(mlp_b, p1, 256, 65536);
  k_bgemm<GF_ATOMIC><<<dim3(2, 2, 64), 256, 0, stream>>>(H2, (ushort*)bufB, nullptr, nullptr, p1, 256, 256, NN, 131072);

  // ---- 6. GRU v9 (register-resident Whh, 4-wave blocks; 256 blocks) ----
  k_gru9<<<BG, 256, 105984, stream>>>(H2, pIh, pHh, bcomb, p2);

  // ---- 7. ST packs + set transformer (MFMA attention), chunked ----
  k_packb<<<256, 256, 0, stream>>>(stWq,        pQ0, 256, 256);
  k_packb<<<256, 256, 0, stream>>>(stWk,        pK0, 256, 256);
  k_packb<<<256, 256, 0, stream>>>(stWv,        pV0, 256, 256);
  k_packb<<<256, 256, 0, stream>>>(stWo,        pO0, 256, 256);
  k_packb<<<256, 256, 0, stream>>>(stlW,        pL0, 256, 256);
  k_packb<<<256, 256, 0, stream>>>(pma_lW,      pPma,256, 256);
  k_packb<<<256, 256, 0, stream>>>(stWk + ls0,  pK1, 256, 256);
  k_packb<<<256, 256, 0, stream>>>(stWv + ls0,  pV1, 256, 256);
  k_packb<<<256, 256, 0, stream>>>(stWo + ls0,  pO1, 256, 256);
  k_packb<<<256, 256, 0, stream>>>(stlW + ls0,  pL1, 256, 256);
  k_packb<<<256, 256, 0, stream>>>(stWv + 2*ls0,pV2, 256, 256);
  k_packb<<<256, 256, 0, stream>>>(stWo + 2*ls0,pO2, 256, 256);
  k_packb<<<256, 256, 0, stream>>>(stlW + 2*ls0,pL2, 256, 256);
  k_packb<<<2304, 256, 0, stream>>>(fin_W,      pFin,768, 768);
  k_qvec<<<1, 256, 0, stream>>>(seed, stWq + ls0, stbq + ls1, qv);

  for (int cg = 0; cg < NCHUNKe; ++cg){
    const int base = cg * NCNe;
    float* Hc = H2 + (size_t)base * 256;
    const dim3 gg(NCNe/128, 2, 1);
    k_bgemm<GF_BIAS><<<gg, 256, 0, stream>>>(Hc, pQ0, stbq, nullptr, bufA, NCNe, 256, 256, 256);           // Q f32
    k_bgemm<GF_BIAS|GF_BF16><<<gg, 256, 0, stream>>>(Hc, pK0, stbk, nullptr, (float*)Kbf, NCNe, 256, 256, 256); // K bf16
    k_bgemm<GF_BIAS|GF_VTP><<<gg, 256, 0, stream>>>(Hc, pV0, stbv, nullptr, (float*)VTp, NCNe, 256, 256, 256);  // V packed
    k_qk<<<dim3(NCNe/128, 4), 256, 0, stream>>>(bufA, Kbf, bufC);                                          // S f32
    k_smrow<<<NCNe, 256, 0, stream>>>(bufC, Pbf);                                                          // P bf16
    k_av<<<dim3(NCNe/128, 2), 256, 0, stream>>>(Pbf, VTp, bufA);                                           // O -> bufA
    k_bgemm<GF_BIAS|GF_RESID><<<gg, 256, 0, stream>>>(bufA, pO0, stbo, Hc, Hc, NCNe, 256, 256, 256);       // h_sab in-place
    k_bgemm<GF_BIAS|GF_RELU|GF_RESID><<<gg, 256, 0, stream>>>(Hc, pL0, stlb, Hc, bufA, NCNe, 256, 256, 256); // h_enc
    k_bgemm<GF_BIAS|GF_RELU><<<gg, 256, 0, stream>>>(bufA, pPma, pma_lb, nullptr, bufB, NCNe, 256, 256, 256); // kk
    k_bgemm<GF_BIAS><<<gg, 256, 0, stream>>>(bufB, pK1, stbk + ls1, nullptr, bufA, NCNe, 256, 256, 256);   // K2 f32
    k_bgemm<GF_BIAS><<<gg, 256, 0, stream>>>(bufB, pV1, stbv + ls1, nullptr, bufC, NCNe, 256, 256, 256);   // V2 f32
    k_attn2<<<CHe, 256, 0, stream>>>(bufA, bufC, qv, av2 + (size_t)cg*CHe*256);
  }

  // ---- 8. PMA tail + decoder SAB ----
  k_bgemm<GF_BIAS|GF_RESID_B><<<dim3(2, 2, 1), 256, 0, stream>>>(av2, pO1, stbo + ls1, seed, s1, 256, 256, 256, 256);
  k_bgemm<GF_BIAS|GF_RELU|GF_RESID><<<dim3(2, 2, 1), 256, 0, stream>>>(s1, pL1, stlb + ls1, s1, s2v, 256, 256, 256, 256);
  k_bgemm<GF_BIAS><<<dim3(2, 2, 1), 256, 0, stream>>>(s2v, pV2, stbv + 2*ls1, nullptr, v3, 256, 256, 256, 256);
  k_bgemm<GF_BIAS|GF_RESID><<<dim3(2, 2, 1), 256, 0, stream>>>(v3, pO2, stbo + 2*ls1, s2v, h3, 256, 256, 256, 256);
  k_bgemm<GF_BIAS|GF_RELU|GF_RESID><<<dim3(2, 2, 1), 256, 0, stream>>>(h3, pL2, stlb + 2*ls1, h3, p3, 256, 256, 256, 256);

  // ---- 9. concat + final linear ----
  k_concat<<<768, 256, 0, stream>>>(p1, p2, p3, pooled);
  k_bgemm<GF_BIAS><<<dim3(2, 6, 1), 256, 0, stream>>>(pooled, pFin, fin_b, nullptr, out, 256, 768, 768, 768);
}

// Round 10
// 3283.915 us; speedup vs baseline: 3.7757x; 1.2224x over previous
//
#include <hip/hip_runtime.h>
#include <hip/hip_bf16.h>
#include <math.h>

// ---- problem constants ----
constexpr int NN   = 131072;   // total nodes (B*NPG)
constexpr int NE   = 262144;   // edges
constexpr int BG   = 256;      // graphs

typedef __bf16 bf16x8 __attribute__((ext_vector_type(8)));
typedef float  f32x4  __attribute__((ext_vector_type(4)));

__device__ inline float sigm(float x){ return 1.f/(1.f+__expf(-x)); }
__device__ inline unsigned short f2bu(float f){
  union{float f;unsigned u;}v; v.f=f;
  unsigned u = v.u + 0x7fffu + ((v.u>>16)&1u);
  return (unsigned short)(u>>16);
}
__device__ inline bf16x8 cvt8(float4 a, float4 b){
  union { ushort u[8]; bf16x8 v; } r;
  r.u[0]=f2bu(a.x); r.u[1]=f2bu(a.y); r.u[2]=f2bu(a.z); r.u[3]=f2bu(a.w);
  r.u[4]=f2bu(b.x); r.u[5]=f2bu(b.y); r.u[6]=f2bu(b.z); r.u[7]=f2bu(b.w);
  return r.v;
}

__global__ void k_zero(int* __restrict__ p, int n){
  int i = blockIdx.x*256 + threadIdx.x;
  if (i < n) p[i] = 0;
}

// ---------------- node encoder ----------------
__global__ void k_node_enc(const int* __restrict__ x, const float* __restrict__ emb,
                           float* __restrict__ h0){
  int n = blockIdx.x*256 + threadIdx.x;
  if (n >= NN) return;
  int nt = x[2*n], ninv = x[2*n+1];
  float4 v; v.x = emb[nt*3+0]; v.y = emb[nt*3+1]; v.z = emb[nt*3+2]; v.w = (float)ninv;
  reinterpret_cast<float4*>(h0)[n] = v;
}

// ---------------- CSR build (by dst) ----------------
__global__ void k_count(const int* __restrict__ ei, int* __restrict__ deg){
  int e = blockIdx.x*256 + threadIdx.x;
  if (e >= NE) return;
  atomicAdd(&deg[ei[NE + e]], 1);
}
__global__ void k_blocksum(const int* __restrict__ deg, int* __restrict__ bsum){
  __shared__ int sd[256];
  int t = threadIdx.x;
  const int* p = deg + blockIdx.x*1024;
  int s = p[t*4] + p[t*4+1] + p[t*4+2] + p[t*4+3];
  sd[t]=s; __syncthreads();
  for (int d=128; d>0; d>>=1){ if (t<d) sd[t]+=sd[t+d]; __syncthreads(); }
  if (!t) bsum[blockIdx.x] = sd[0];
}
__global__ void k_scanbsum(const int* __restrict__ bsum, int* __restrict__ boff, int* __restrict__ offN){
  __shared__ int s[128];
  int t = threadIdx.x;
  int mine = bsum[t];
  s[t]=mine; __syncthreads();
  for (int d=1; d<128; d<<=1){ int v = (t>=d)? s[t-d]:0; __syncthreads(); s[t]+=v; __syncthreads(); }
  boff[t] = s[t]-mine;
  if (t==127) offN[0] = s[127];
}
__global__ void k_scanchunk(const int* __restrict__ deg, const int* __restrict__ boff, int* __restrict__ offs){
  __shared__ int ts[256];
  int t = threadIdx.x, b = blockIdx.x;
  const int* p = deg + b*1024;
  int v0=p[t*4],v1=p[t*4+1],v2=p[t*4+2],v3=p[t*4+3];
  int mysum=v0+v1+v2+v3;
  ts[t]=mysum; __syncthreads();
  for (int d=1; d<256; d<<=1){ int v=(t>=d)?ts[t-d]:0; __syncthreads(); ts[t]+=v; __syncthreads(); }
  int ex = ts[t]-mysum + boff[b];
  int* o = offs + b*1024 + t*4;
  o[0]=ex; o[1]=ex+v0; o[2]=ex+v0+v1; o[3]=ex+v0+v1+v2;
}
__global__ void k_fill(const int* __restrict__ ei, const int* __restrict__ offs,
                       int* __restrict__ cur, int* __restrict__ esrc){
  int e = blockIdx.x*256 + threadIdx.x;
  if (e >= NE) return;
  int dst = ei[NE+e];
  int pos = offs[dst] + atomicAdd(&cur[dst],1);
  esrc[pos] = ei[e];
}

// ---------------- softmax aggregation, 4-channel (conv1), no-max (exact) ----------------
__global__ void k_aggr4(const float* __restrict__ h, const int* __restrict__ offs,
                        const int* __restrict__ esrc, const float* __restrict__ tptr,
                        float* __restrict__ ag){
  int n = blockIdx.x*256 + threadIdx.x;
  if (n >= NN) return;
  int s = offs[n], e = offs[n+1];
  float4 z = {0,0,0,0};
  if (s == e){ reinterpret_cast<float4*>(ag)[n] = z; return; }
  float t = *tptr;
  float4 num=z, den=z;
  for (int i=s;i<e;++i){
    float4 v = reinterpret_cast<const float4*>(h)[esrc[i]];
    float ex;
    ex=__expf(v.x*t); num.x+=v.x*ex; den.x+=ex;
    ex=__expf(v.y*t); num.y+=v.y*ex; den.y+=ex;
    ex=__expf(v.z*t); num.z+=v.z*ex; den.z+=ex;
    ex=__expf(v.w*t); num.w+=v.w*ex; den.w+=ex;
  }
  float4 r = {num.x/den.x, num.y/den.y, num.z/den.z, num.w/den.w};
  reinterpret_cast<float4*>(ag)[n] = r;
}

// ---------------- softmax aggregation (no-max, 1 pass), fused [h1|ag] layout ----------------
__global__ __launch_bounds__(256) void k_aggr256(float* __restrict__ buf, const int* __restrict__ offs,
                          const int* __restrict__ esrc, const float* __restrict__ tptr, int base){
  int n = base + blockIdx.x, c = threadIdx.x;
  int s = offs[n], e = offs[n+1];
  float* outp = buf + (size_t)blockIdx.x*512 + 256 + c;
  if (s == e){ *outp = 0.f; return; }
  float t = *tptr;
  float num=0.f, den=0.f;
  for (int i=s;i<e;++i){
    float v = buf[(size_t)(esrc[i]-base)*512 + c];
    float ex = __expf(v*t);
    num += v*ex; den += ex;
  }
  *outp = num/den;
}

// ---------------- conv1 linear (K=4, fused), writes [n][512] col 0..255 ----------------
__global__ __launch_bounds__(256) void k_conv1_lin(const float* __restrict__ ag, const float* __restrict__ h0,
                            const float* __restrict__ lW, const float* __restrict__ lb,
                            const float* __restrict__ rW, float* __restrict__ out, int base){
  int n = base + blockIdx.x, c = threadIdx.x;
  float4 a  = reinterpret_cast<const float4*>(ag)[n];
  float4 xv = reinterpret_cast<const float4*>(h0)[n];
  float acc = lb[c];
  acc += a.x*lW[c]  + a.y*lW[256+c]  + a.z*lW[512+c]  + a.w*lW[768+c];
  acc += xv.x*rW[c] + xv.y*rW[256+c] + xv.z*rW[512+c] + xv.w*rW[768+c];
  out[(size_t)blockIdx.x*512 + c] = fmaxf(acc, 0.f);
}

// ---------------- flags ----------------
#define GF_BIAS    1
#define GF_RELU    2
#define GF_RESID   4
#define GF_RESID_B 8
#define GF_ADDC    32
#define GF_ATOMIC  64
#define GF_BF16    128
#define GF_VTP     256   // write output as per-graph B-pack (for AV's V operand)

// ---------------- weight pack: f32 W[K][N] -> MFMA-B bf16 Bp[((k>>3)*N + j)*8 + (k&7)] ----
__global__ void k_packb(const float* __restrict__ W, ushort* __restrict__ Bp, int K, int N){
  int idx = blockIdx.x*256 + threadIdx.x;
  if (idx >= K*N) return;
  int k = idx / N, j = idx - k*N;
  Bp[((size_t)(k>>3)*N + j)*8 + (k&7)] = f2bu(W[idx]);
}
// transposed source: W is [N][K] row-major; B[k][j] = W[j][k]
__global__ void k_packbT(const float* __restrict__ W, ushort* __restrict__ Bp, int K, int N){
  int idx = blockIdx.x*256 + threadIdx.x;
  if (idx >= K*N) return;
  int j = idx / K, k = idx - j*K;
  Bp[((size_t)(k>>3)*N + j)*8 + (k&7)] = f2bu(W[idx]);
}
// combined GRU biases
__global__ void k_packbias(const float* __restrict__ gbih, const float* __restrict__ gbhh,
                           float* __restrict__ bc){
  int i = blockIdx.x*256 + threadIdx.x;
  if (i >= 1024) return;
  int c = i & 255;
  float v;
  if (i < 256)      v = gbih[c] + gbhh[c];
  else if (i < 512) v = gbih[256+c] + gbhh[256+c];
  else if (i < 768) v = gbih[512+c];
  else              v = gbhh[512+c];
  bc[i] = v;
}

// ---------------- MFMA GEMM: LDS-free, A f32 (cvt in-reg), B pre-packed bf16 ----------------
template<int FLAGS>
__global__ __launch_bounds__(256) void k_bgemm(const float* __restrict__ A, const ushort* __restrict__ Bp,
                       const float* __restrict__ bias, const float* __restrict__ resid,
                       float* __restrict__ C, int M, int Nn, int K, int lda){
  const int tid = threadIdx.x;
  const int wv = tid>>6, lane = tid&63;
  const int mw = wv>>1, nw = wv&1;
  const int arow = lane&15, ks = lane>>4;
  const int m0 = blockIdx.x*128 + mw*64, n0 = blockIdx.y*128 + nw*64;
  const int kChunk = K / gridDim.z, kBeg = blockIdx.z * kChunk;
  f32x4 acc[4][4] = {};
  const float* Arow0 = A + (size_t)(m0 + 0*16 + arow)*lda;
  const float* Arow1 = A + (size_t)(m0 + 1*16 + arow)*lda;
  const float* Arow2 = A + (size_t)(m0 + 2*16 + arow)*lda;
  const float* Arow3 = A + (size_t)(m0 + 3*16 + arow)*lda;
  #pragma unroll 2
  for (int k0 = kBeg; k0 < kBeg+kChunk; k0 += 32){
    const int kb = (k0>>3) + ks;
    bf16x8 af[4];
    {
      const float4* p0 = reinterpret_cast<const float4*>(Arow0 + k0 + ks*8);
      const float4* p1 = reinterpret_cast<const float4*>(Arow1 + k0 + ks*8);
      const float4* p2 = reinterpret_cast<const float4*>(Arow2 + k0 + ks*8);
      const float4* p3 = reinterpret_cast<const float4*>(Arow3 + k0 + ks*8);
      af[0] = cvt8(p0[0], p0[1]);
      af[1] = cvt8(p1[0], p1[1]);
      af[2] = cvt8(p2[0], p2[1]);
      af[3] = cvt8(p3[0], p3[1]);
    }
    #pragma unroll
    for (int nf=0; nf<4; ++nf){
      const int col = n0 + nf*16 + arow;
      bf16x8 bfr = *reinterpret_cast<const bf16x8*>(Bp + ((size_t)kb*Nn + col)*8);
      #pragma unroll
      for (int mf=0; mf<4; ++mf)
        acc[mf][nf] = __builtin_amdgcn_mfma_f32_16x16x32_bf16(af[mf], bfr, acc[mf][nf], 0, 0, 0);
    }
  }
  #pragma unroll
  for (int nf=0; nf<4; ++nf){
    const int n = n0 + nf*16 + arow;
    float bv  = (FLAGS & GF_BIAS)    ? bias[n]  : 0.f;
    float rbv = (FLAGS & GF_RESID_B) ? resid[n] : 0.f;
    #pragma unroll
    for (int mf=0; mf<4; ++mf){
      #pragma unroll
      for (int r=0; r<4; ++r){
        const int m = m0 + mf*16 + ks*4 + r;
        size_t idx = (size_t)m*Nn + n;
        float v = acc[mf][nf][r];
        if (FLAGS & GF_ATOMIC){ atomicAdd(&C[idx], v); }
        else {
          v += bv;
          if (FLAGS & GF_ADDC)  v += C[idx];
          if (FLAGS & GF_RELU)  v = fmaxf(v, 0.f);
          if (FLAGS & GF_RESID) v += resid[idx];
          v += rbv;
          if (FLAGS & GF_VTP){
            const int rr = m & 511, mg = m >> 9;
            ((ushort*)C)[(size_t)mg*131072 + (((rr>>3)*256 + n)<<3) + (rr&7)] = f2bu(v);
          }
          else if (FLAGS & GF_BF16) reinterpret_cast<__hip_bfloat16*>(C)[idx] = __float2bfloat16(v);
          else C[idx] = v;
        }
      }
    }
  }
}

// ---------------- batched QK^T: S[g][q][k] = Q[g*512+q][:] . K[g*512+k][:] ----------------
__global__ __launch_bounds__(256) void k_qk(const float* __restrict__ Q, const ushort* __restrict__ Kb,
                                            float* __restrict__ S){
  const int tid = threadIdx.x;
  const int wv = tid>>6, lane = tid&63;
  const int mw = wv>>1, nw = wv&1;
  const int arow = lane&15, ks = lane>>4;
  const int m0 = blockIdx.x*128 + mw*64;      // global q row in chunk
  const int n0 = blockIdx.y*128 + nw*64;      // key index 0..511
  const int g  = blockIdx.x>>2;
  const ushort* Kg = Kb + (size_t)g*131072;
  f32x4 acc[4][4] = {};
  const float* Ar0 = Q + (size_t)(m0 + 0*16 + arow)*256;
  const float* Ar1 = Q + (size_t)(m0 + 1*16 + arow)*256;
  const float* Ar2 = Q + (size_t)(m0 + 2*16 + arow)*256;
  const float* Ar3 = Q + (size_t)(m0 + 3*16 + arow)*256;
  #pragma unroll
  for (int k0 = 0; k0 < 256; k0 += 32){
    bf16x8 af[4];
    {
      const float4* p0 = reinterpret_cast<const float4*>(Ar0 + k0 + ks*8);
      const float4* p1 = reinterpret_cast<const float4*>(Ar1 + k0 + ks*8);
      const float4* p2 = reinterpret_cast<const float4*>(Ar2 + k0 + ks*8);
      const float4* p3 = reinterpret_cast<const float4*>(Ar3 + k0 + ks*8);
      af[0] = cvt8(p0[0], p0[1]);
      af[1] = cvt8(p1[0], p1[1]);
      af[2] = cvt8(p2[0], p2[1]);
      af[3] = cvt8(p3[0], p3[1]);
    }
    #pragma unroll
    for (int nf=0; nf<4; ++nf){
      const int j = n0 + nf*16 + arow;        // key row
      bf16x8 bfr = *reinterpret_cast<const bf16x8*>(Kg + (size_t)j*256 + k0 + ks*8);
      #pragma unroll
      for (int mf=0; mf<4; ++mf)
        acc[mf][nf] = __builtin_amdgcn_mfma_f32_16x16x32_bf16(af[mf], bfr, acc[mf][nf], 0, 0, 0);
    }
  }
  #pragma unroll
  for (int nf=0; nf<4; ++nf){
    const int n = n0 + nf*16 + arow;
    #pragma unroll
    for (int mf=0; mf<4; ++mf){
      #pragma unroll
      for (int r=0; r<4; ++r){
        const int m = m0 + mf*16 + ks*4 + r;
        S[(size_t)m*512 + n] = acc[mf][nf][r];
      }
    }
  }
}

// ---------------- row softmax (scale 1/16), f32 S -> normalized bf16 P ----------------
__global__ __launch_bounds__(256) void k_smrow(const float* __restrict__ S, ushort* __restrict__ P){
  const int row = blockIdx.x, tid = threadIdx.x;
  __shared__ float red[4];
  const float* sr = S + (size_t)row*512;
  float s0 = sr[tid], s1 = sr[tid+256];
  float m = fmaxf(s0, s1);
  #pragma unroll
  for (int o=1;o<64;o<<=1) m = fmaxf(m, __shfl_xor(m,o));
  if ((tid&63)==0) red[tid>>6] = m;
  __syncthreads();
  m = fmaxf(fmaxf(red[0],red[1]), fmaxf(red[2],red[3]));
  __syncthreads();
  float e0 = __expf((s0-m)*0.0625f), e1 = __expf((s1-m)*0.0625f);
  float s = e0+e1;
  #pragma unroll
  for (int o=1;o<64;o<<=1) s += __shfl_xor(s,o);
  if ((tid&63)==0) red[tid>>6] = s;
  __syncthreads();
  s = red[0]+red[1]+red[2]+red[3];
  float inv = 1.f/s;
  P[(size_t)row*512 + tid]       = f2bu(e0*inv);
  P[(size_t)row*512 + 256 + tid] = f2bu(e1*inv);
}

// ---------------- batched AV: O[g*512+q][c] = sum_k P[q][k] V[k][c] ----------------
__global__ __launch_bounds__(256) void k_av(const ushort* __restrict__ Pb, const ushort* __restrict__ VTp,
                                            float* __restrict__ O){
  const int tid = threadIdx.x;
  const int wv = tid>>6, lane = tid&63;
  const int mw = wv>>1, nw = wv&1;
  const int arow = lane&15, ks = lane>>4;
  const int m0 = blockIdx.x*128 + mw*64;
  const int n0 = blockIdx.y*128 + nw*64;      // c 0..255
  const int g  = blockIdx.x>>2;
  const ushort* Vg = VTp + (size_t)g*131072;
  f32x4 acc[4][4] = {};
  const ushort* Pr0 = Pb + (size_t)(m0 + 0*16 + arow)*512;
  const ushort* Pr1 = Pb + (size_t)(m0 + 1*16 + arow)*512;
  const ushort* Pr2 = Pb + (size_t)(m0 + 2*16 + arow)*512;
  const ushort* Pr3 = Pb + (size_t)(m0 + 3*16 + arow)*512;
  #pragma unroll 2
  for (int k0 = 0; k0 < 512; k0 += 32){
    const int kb = (k0>>3) + ks;
    bf16x8 af[4];
    af[0] = *reinterpret_cast<const bf16x8*>(Pr0 + k0 + ks*8);
    af[1] = *reinterpret_cast<const bf16x8*>(Pr1 + k0 + ks*8);
    af[2] = *reinterpret_cast<const bf16x8*>(Pr2 + k0 + ks*8);
    af[3] = *reinterpret_cast<const bf16x8*>(Pr3 + k0 + ks*8);
    #pragma unroll
    for (int nf=0; nf<4; ++nf){
      const int col = n0 + nf*16 + arow;
      bf16x8 bfr = *reinterpret_cast<const bf16x8*>(Vg + ((size_t)kb*256 + col)*8);
      #pragma unroll
      for (int mf=0; mf<4; ++mf)
        acc[mf][nf] = __builtin_amdgcn_mfma_f32_16x16x32_bf16(af[mf], bfr, acc[mf][nf], 0, 0, 0);
    }
  }
  #pragma unroll
  for (int nf=0; nf<4; ++nf){
    const int n = n0 + nf*16 + arow;
    #pragma unroll
    for (int mf=0; mf<4; ++mf){
      #pragma unroll
      for (int r=0; r<4; ++r){
        const int m = m0 + mf*16 + ks*4 + r;
        O[(size_t)m*256 + n] = acc[mf][nf][r];
      }
    }
  }
}

// ---------------- small utilities ----------------
__global__ void k_rowbias(const float* __restrict__ bias, float* __restrict__ C, int Nn, int total){
  int i = blockIdx.x*256 + threadIdx.x;
  if (i < total) C[i] = bias[i % Nn];
}
__global__ void k_qvec(const float* __restrict__ seed, const float* __restrict__ Wq,
                       const float* __restrict__ bq, float* __restrict__ qv){
  __shared__ float s[256];
  int t = threadIdx.x;
  s[t] = seed[t]; __syncthreads();
  float acc = bq[t];
  for (int c = 0; c < 256; ++c) acc += s[c] * Wq[c*256 + t];
  qv[t] = acc;
}
// wk2q[c] = sum_t Wk2[c][t]*qv[t]; wk2q[256] = bk2 . qv
__global__ __launch_bounds__(256) void k_wk2q(const float* __restrict__ Wk2, const float* __restrict__ bk2,
                      const float* __restrict__ qv, float* __restrict__ outv){
  __shared__ float qs[256];
  __shared__ float red[4];
  int t = threadIdx.x;
  qs[t] = qv[t]; __syncthreads();
  float a = 0.f;
  for (int c=0;c<256;c+=4){
    float4 w = *reinterpret_cast<const float4*>(Wk2 + t*256 + c);
    a += w.x*qs[c] + w.y*qs[c+1] + w.z*qs[c+2] + w.w*qs[c+3];
  }
  outv[t] = a;
  float bb = bk2[t]*qs[t];
  #pragma unroll
  for (int o=1;o<64;o<<=1) bb += __shfl_xor(bb,o);
  if ((t&63)==0) red[t>>6] = bb;
  __syncthreads();
  if (t==0) outv[256] = red[0]+red[1]+red[2]+red[3];
}
// fused PMA: logits = (kk @ wk2q + b2q)/16; alpha = softmax; wsum = sum_j alpha_j kk[j]
__global__ __launch_bounds__(256) void k_pmafuse(const float* __restrict__ kk, const float* __restrict__ wkq,
                        float* __restrict__ wsum){
  int g = blockIdx.x, tid = threadIdx.x;
  __shared__ float qs[256];
  __shared__ float sc[512];
  __shared__ float red[4];
  qs[tid] = wkq[tid];
  __syncthreads();
  const float b2q = wkq[256];
  const float* kg = kk + (size_t)g*512*256;
  float l0=0.f, l1=0.f;
  for (int j0=0;j0<2;++j0){
    int j = tid + j0*256;
    const float* kr = kg + (size_t)j*256;
    float a = 0.f;
    for (int c=0;c<256;c+=4){
      float4 k4 = *reinterpret_cast<const float4*>(kr + c);
      a += k4.x*qs[c] + k4.y*qs[c+1] + k4.z*qs[c+2] + k4.w*qs[c+3];
    }
    a = (a + b2q)*0.0625f;
    if (j0) l1=a; else l0=a;
  }
  float m = fmaxf(l0,l1);
  #pragma unroll
  for (int o=1;o<64;o<<=1) m = fmaxf(m, __shfl_xor(m,o));
  if ((tid&63)==0) red[tid>>6] = m;
  __syncthreads();
  m = fmaxf(fmaxf(red[0],red[1]), fmaxf(red[2],red[3]));
  __syncthreads();
  float e0 = __expf(l0-m), e1 = __expf(l1-m);
  sc[tid]=e0; sc[tid+256]=e1;
  float s = e0+e1;
  #pragma unroll
  for (int o=1;o<64;o<<=1) s += __shfl_xor(s,o);
  if ((tid&63)==0) red[tid>>6] = s;
  __syncthreads();
  s = red[0]+red[1]+red[2]+red[3];
  float invs = 1.f/s;
  float acc = 0.f;
  for (int j=0;j<512;++j) acc += sc[j] * kg[(size_t)j*256 + tid];
  wsum[(size_t)g*256+tid] = acc*invs;
}
__global__ void k_concat(const float* __restrict__ p1, const float* __restrict__ p2,
                         const float* __restrict__ p3, float* __restrict__ pooled){
  int idx = blockIdx.x*256 + threadIdx.x;
  int b = idx / 768, j = idx % 768;
  float v = (j < 256) ? p1[b*256+j] : (j < 512) ? p2[b*256+j-256] : p3[b*256+j-512];
  pooled[idx] = v;
}

// ---------------- GRU v8 (measured best): 1 graph/block, 256 blocks, 512 thr ----------------
// Streams Whh bf16 from L2 each step (at aggregate-L2 floor); gi windowed in LDS.
__global__ __launch_bounds__(512,2) void k_gru8(const float* __restrict__ X,
                      const ushort* __restrict__ pIh, const ushort* __restrict__ pHh,
                      const float* __restrict__ bc, float* __restrict__ p2){
  extern __shared__ char gsm[];
  float*  GIw = (float*)gsm;                    // [32][768]  98304 B
  float*  gh  = (float*)(gsm + 98304);          // [768]
  float*  bcl = (float*)(gsm + 101376);         // [1024]
  ushort* hbf = (ushort*)(gsm + 105472);        // [256]
  const int g = blockIdx.x;
  const int tid = threadIdx.x;
  const int wv = tid>>6, lane = tid&63;
  const int arow = lane&15, ks = lane>>4;
  bf16x8 whh[8][6];
  #pragma unroll
  for (int kt=0;kt<8;++kt)
    #pragma unroll
    for (int nt=0;nt<6;++nt)
      whh[kt][nt] = *reinterpret_cast<const bf16x8*>(pHh + ((size_t)(kt*4+ks)*768 + wv*96+nt*16+arow)*8);
  #pragma unroll
  for (int kt=0;kt<8;++kt)
    #pragma unroll
    for (int nt=0;nt<6;++nt)
      asm volatile("" : "+v"(whh[kt][nt]));
  for (int i=tid;i<1024;i+=512) bcl[i] = bc[i];
  if (tid < 256) hbf[tid] = 0;
  float h_reg = 0.f;
  const float* Xg = X + (size_t)g*512*256;
  __syncthreads();
  for (int w=0; w<16; ++w){
    const int t0 = w*32;
    #pragma unroll
    for (int mt=0; mt<2; ++mt){
      const float* xr = Xg + (size_t)(t0 + mt*16 + arow)*256;
      f32x4 acc[6] = {};
      #pragma unroll
      for (int kt=0; kt<8; ++kt){
        const float4* xp = reinterpret_cast<const float4*>(xr + kt*32 + ks*8);
        bf16x8 af = cvt8(xp[0], xp[1]);
        #pragma unroll
        for (int nt=0; nt<6; ++nt){
          bf16x8 bfr = *reinterpret_cast<const bf16x8*>(pIh + ((size_t)(kt*4+ks)*768 + wv*96+nt*16+arow)*8);
          acc[nt] = __builtin_amdgcn_mfma_f32_16x16x32_bf16(af, bfr, acc[nt], 0,0,0);
        }
      }
      #pragma unroll
      for (int nt=0; nt<6; ++nt){
        const int col = wv*96 + nt*16 + arow;
        #pragma unroll
        for (int r=0;r<4;++r)
          GIw[(size_t)(mt*16 + ks*4 + r)*768 + col] = acc[nt][r];
      }
    }
    for (int dt=0; dt<32; ++dt){
      f32x4 sacc[6] = {};
      #pragma unroll
      for (int kt=0; kt<8; ++kt){
        bf16x8 af = {};
        if (arow == 0) af = *reinterpret_cast<const bf16x8*>(hbf + kt*32 + ks*8);
        #pragma unroll
        for (int nt=0; nt<6; ++nt)
          sacc[nt] = __builtin_amdgcn_mfma_f32_16x16x32_bf16(af, whh[kt][nt], sacc[nt], 0,0,0);
      }
      if (ks == 0){
        #pragma unroll
        for (int nt=0; nt<6; ++nt) gh[wv*96 + nt*16 + arow] = sacc[nt][0];
      }
      __syncthreads();   // gh + GIw ready; hbf reads done
      if (tid < 256){
        const int c = tid;
        const float* gir = GIw + (size_t)dt*768;
        float rr = sigm(gir[c]     + gh[c]     + bcl[c]);
        float zz = sigm(gir[256+c] + gh[256+c] + bcl[256+c]);
        float nn = tanhf(gir[512+c] + bcl[512+c] + rr*(gh[512+c] + bcl[768+c]));
        h_reg = (1.f-zz)*nn + zz*h_reg;
        hbf[c] = f2bu(h_reg);
      }
      __syncthreads();   // hbf ready for next step
    }
  }
  if (tid < 256) p2[(size_t)g*256 + tid] = h_reg;
}

// =====================================================================
extern "C" void kernel_launch(void* const* d_in, const int* in_sizes, int n_in,
                              void* d_out, int out_size, void* d_ws, size_t ws_size,
                              hipStream_t stream){
  const int*   x      = (const int*)  d_in[0];
  const int*   ei     = (const int*)  d_in[1];
  const float* emb_w  = (const float*)d_in[3];
  const float* c1_lW  = (const float*)d_in[4];
  const float* c1_lb  = (const float*)d_in[5];
  const float* c1_rW  = (const float*)d_in[6];
  const float* t1     = (const float*)d_in[7];
  const float* c2_lW  = (const float*)d_in[8];
  const float* c2_lb  = (const float*)d_in[9];
  const float* c2_rW  = (const float*)d_in[10];
  const float* t2     = (const float*)d_in[11];
  const float* mlp_W  = (const float*)d_in[12];
  const float* mlp_b  = (const float*)d_in[13];
  const float* gWih   = (const float*)d_in[14];
  const float* gWhh   = (const float*)d_in[15];
  const float* gbih   = (const float*)d_in[16];
  const float* gbhh   = (const float*)d_in[17];
  const float* stWq   = (const float*)d_in[18];
  const float* stbq   = (const float*)d_in[19];
  const float* stWk   = (const float*)d_in[20];
  const float* stbk   = (const float*)d_in[21];
  const float* stWv   = (const float*)d_in[22];
  const float* stbv   = (const float*)d_in[23];
  const float* stWo   = (const float*)d_in[24];
  const float* stbo   = (const float*)d_in[25];
  const float* stlW   = (const float*)d_in[26];
  const float* stlb   = (const float*)d_in[27];
  const float* pma_lW = (const float*)d_in[28];
  const float* pma_lb = (const float*)d_in[29];
  const float* seed   = (const float*)d_in[30];
  const float* fin_W  = (const float*)d_in[31];
  const float* fin_b  = (const float*)d_in[32];
  float* out = (float*)d_out;

  // ---- choose chunk size by available workspace ----
  auto needFor = [](int CHe)->size_t{
    size_t bufN = (size_t)CHe*512*512;
    size_t floats = (size_t)33554432 + 3*bufN + 2*524288 + 2*196608 + 8*65536 + 196608 + 320 + 512;
    size_t ints   = 131072 + 131200 + 131072 + 262144 + 128 + 128;
    return floats*4 + ints*4 + 4096;
  };
  const int CHe = (ws_size >= needFor(64)) ? 64 : 32;
  if (ws_size < needFor(32)) return;
  const int NCHUNKe = BG / CHe;
  const int NCNe = CHe * 512;
  const size_t bufN = (size_t)CHe*512*512;

  // ---- workspace carve ----
  float* H2   = (float*)d_ws;                    // NN*256 f32 (persists)
  float* bufA = H2   + (size_t)33554432;
  float* bufB = bufA + bufN;
  float* bufC = bufB + bufN;
  float* h0   = bufC + bufN;                     // NN*4
  float* ag1  = h0   + (size_t)524288;           // NN*4
  float* wT1  = ag1  + (size_t)524288;           // GRU packs (pIh/pHh)
  float* wT2  = wT1  + (size_t)196608;           // pC2 + bcomb
  float* p1   = wT2  + (size_t)196608;
  float* p2   = p1   + (size_t)65536;
  float* p3   = p2   + (size_t)65536;
  float* av2  = p3   + (size_t)65536;            // (= PMA wsum)
  float* s1   = av2  + (size_t)65536;
  float* s2v  = s1   + (size_t)65536;
  float* v3   = s2v  + (size_t)65536;
  float* h3   = v3   + (size_t)65536;
  float* pooled = h3 + (size_t)65536;
  float* qv   = pooled + (size_t)196608;
  int*   deg  = (int*)(qv + 320);
  int*   offs = deg  + 131072;
  int*   cur  = offs + 131200;
  int*   esrc = cur  + 131072;
  int*   bsum = esrc + 262144;
  int*   boff = bsum + 128;
  float* wkq  = (float*)(boff + 128);            // 512 floats (wk2q[256] + b2q)

  ushort* pIh  = (ushort*)wT1;
  ushort* pHh  = (ushort*)(wT1 + 98304);
  ushort* pC2  = (ushort*)wT2;
  float*  bcomb= wT2 + 65536;
  float*  pa   = h0;                             // dead after conv -> ST packs
  ushort* pQ0  = (ushort*)(pa);
  ushort* pK0  = (ushort*)(pa + 32768);
  ushort* pV0  = (ushort*)(pa + 65536);
  ushort* pO0  = (ushort*)(pa + 98304);
  ushort* pL0  = (ushort*)(pa + 131072);
  ushort* pPma = (ushort*)(pa + 163840);
  ushort* pV1  = (ushort*)(pa + 229376);
  ushort* pO1  = (ushort*)(pa + 262144);
  ushort* pL1  = (ushort*)(pa + 294912);
  ushort* pV2  = (ushort*)(pa + 327680);
  ushort* pO2  = (ushort*)(pa + 360448);
  ushort* pL2  = (ushort*)(pa + 393216);
  ushort* pFin = (ushort*)(pa + 425984);

  // attention sub-buffers (inside bufA/bufB)
  ushort* VTp = (ushort*)(bufA + bufN/2);
  ushort* Kbf = (ushort*)bufB;
  ushort* Pbf = (ushort*)(bufB + bufN/4);

  const int ls0 = 65536, ls1 = 256;

  // ---- 1. node encoder ----
  k_node_enc<<<NN/256, 256, 0, stream>>>(x, emb_w, h0);

  // ---- 2. CSR ----
  k_zero<<<NN/256, 256, 0, stream>>>(deg, NN);
  k_count<<<NE/256, 256, 0, stream>>>(ei, deg);
  k_blocksum<<<128, 256, 0, stream>>>(deg, bsum);
  k_scanbsum<<<1, 128, 0, stream>>>(bsum, boff, offs + NN);
  k_scanchunk<<<128, 256, 0, stream>>>(deg, boff, offs);
  k_zero<<<NN/256, 256, 0, stream>>>(cur, NN);
  k_fill<<<NE/256, 256, 0, stream>>>(ei, offs, cur, esrc);

  // ---- 3. conv1 aggregation + early packs ----
  k_aggr4<<<NN/256, 256, 0, stream>>>(h0, offs, esrc, t1, ag1);
  k_packb <<<256, 256, 0, stream>>>(c2_rW, pC2, 256, 256);
  k_packb <<<256, 256, 0, stream>>>(c2_lW, pC2 + 65536, 256, 256);
  k_packbT<<<768, 256, 0, stream>>>(gWih, pIh, 256, 768);
  k_packbT<<<768, 256, 0, stream>>>(gWhh, pHh, 256, 768);
  k_packbias<<<4, 256, 0, stream>>>(gbih, gbhh, bcomb);

  // ---- 4. conv1 + conv2 (fused K=512), chunked ----
  for (int cg = 0; cg < NCHUNKe; ++cg){
    const int base = cg * NCNe;
    float* Hc = H2 + (size_t)base * 256;
    const dim3 gg(NCNe/128, 2, 1);
    k_conv1_lin<<<NCNe, 256, 0, stream>>>(ag1, h0, c1_lW, c1_lb, c1_rW, bufA, base);
    k_aggr256<<<NCNe, 256, 0, stream>>>(bufA, offs, esrc, t2, base);
    k_bgemm<GF_BIAS|GF_RELU><<<gg, 256, 0, stream>>>(bufA, pC2, c2_lb, nullptr, Hc, NCNe, 256, 512, 512);
  }
  // H2 = h2 (full)

  // ---- 5. p1 = MLP pool via MFMA (pack mlp_W bf16 into free bufB; split-K atomic) ----
  k_packb<<<131072, 256, 0, stream>>>(mlp_W, (ushort*)bufB, 131072, 256);
  k_rowbias<<<256, 256, 0, stream>>>(mlp_b, p1, 256, 65536);
  k_bgemm<GF_ATOMIC><<<dim3(2, 2, 64), 256, 0, stream>>>(H2, (ushort*)bufB, nullptr, nullptr, p1, 256, 256, NN, 131072);

  // ---- 6. GRU v8 (measured best; 256 blocks, 8 waves) ----
  k_gru8<<<BG, 512, 105984, stream>>>(H2, pIh, pHh, bcomb, p2);

  // ---- 7. ST packs + set transformer (MFMA attention + fused PMA), chunked ----
  k_packb<<<256, 256, 0, stream>>>(stWq,        pQ0, 256, 256);
  k_packb<<<256, 256, 0, stream>>>(stWk,        pK0, 256, 256);
  k_packb<<<256, 256, 0, stream>>>(stWv,        pV0, 256, 256);
  k_packb<<<256, 256, 0, stream>>>(stWo,        pO0, 256, 256);
  k_packb<<<256, 256, 0, stream>>>(stlW,        pL0, 256, 256);
  k_packb<<<256, 256, 0, stream>>>(pma_lW,      pPma,256, 256);
  k_packb<<<256, 256, 0, stream>>>(stWv + ls0,  pV1, 256, 256);
  k_packb<<<256, 256, 0, stream>>>(stWo + ls0,  pO1, 256, 256);
  k_packb<<<256, 256, 0, stream>>>(stlW + ls0,  pL1, 256, 256);
  k_packb<<<256, 256, 0, stream>>>(stWv + 2*ls0,pV2, 256, 256);
  k_packb<<<256, 256, 0, stream>>>(stWo + 2*ls0,pO2, 256, 256);
  k_packb<<<256, 256, 0, stream>>>(stlW + 2*ls0,pL2, 256, 256);
  k_packb<<<2304, 256, 0, stream>>>(fin_W,      pFin,768, 768);
  k_qvec<<<1, 256, 0, stream>>>(seed, stWq + ls0, stbq + ls1, qv);
  k_wk2q<<<1, 256, 0, stream>>>(stWk + ls0, stbk + ls1, qv, wkq);

  for (int cg = 0; cg < NCHUNKe; ++cg){
    const int base = cg * NCNe;
    float* Hc = H2 + (size_t)base * 256;
    const dim3 gg(NCNe/128, 2, 1);
    k_bgemm<GF_BIAS><<<gg, 256, 0, stream>>>(Hc, pQ0, stbq, nullptr, bufA, NCNe, 256, 256, 256);           // Q f32
    k_bgemm<GF_BIAS|GF_BF16><<<gg, 256, 0, stream>>>(Hc, pK0, stbk, nullptr, (float*)Kbf, NCNe, 256, 256, 256); // K bf16
    k_bgemm<GF_BIAS|GF_VTP><<<gg, 256, 0, stream>>>(Hc, pV0, stbv, nullptr, (float*)VTp, NCNe, 256, 256, 256);  // V packed
    k_qk<<<dim3(NCNe/128, 4), 256, 0, stream>>>(bufA, Kbf, bufC);                                          // S f32
    k_smrow<<<NCNe, 256, 0, stream>>>(bufC, Pbf);                                                          // P bf16
    k_av<<<dim3(NCNe/128, 2), 256, 0, stream>>>(Pbf, VTp, bufA);                                           // O -> bufA
    k_bgemm<GF_BIAS|GF_RESID><<<gg, 256, 0, stream>>>(bufA, pO0, stbo, Hc, Hc, NCNe, 256, 256, 256);       // h_sab in-place
    k_bgemm<GF_BIAS|GF_RELU|GF_RESID><<<gg, 256, 0, stream>>>(Hc, pL0, stlb, Hc, bufA, NCNe, 256, 256, 256); // h_enc
    k_bgemm<GF_BIAS|GF_RELU><<<gg, 256, 0, stream>>>(bufA, pPma, pma_lb, nullptr, bufB, NCNe, 256, 256, 256); // kk
    k_pmafuse<<<CHe, 256, 0, stream>>>(bufB, wkq, av2 + (size_t)cg*CHe*256);                               // wsum
  }

  // ---- 8. PMA tail + decoder SAB ----
  k_bgemm<GF_BIAS><<<dim3(2, 2, 1), 256, 0, stream>>>(av2, pV1, stbv + ls1, nullptr, v3, 256, 256, 256, 256);   // true av2
  k_bgemm<GF_BIAS|GF_RESID_B><<<dim3(2, 2, 1), 256, 0, stream>>>(v3, pO1, stbo + ls1, seed, s1, 256, 256, 256, 256);
  k_bgemm<GF_BIAS|GF_RELU|GF_RESID><<<dim3(2, 2, 1), 256, 0, stream>>>(s1, pL1, stlb + ls1, s1, s2v, 256, 256, 256, 256);
  k_bgemm<GF_BIAS><<<dim3(2, 2, 1), 256, 0, stream>>>(s2v, pV2, stbv + 2*ls1, nullptr, v3, 256, 256, 256, 256);
  k_bgemm<GF_BIAS|GF_RESID><<<dim3(2, 2, 1), 256, 0, stream>>>(v3, pO2, stbo + 2*ls1, s2v, h3, 256, 256, 256, 256);
  k_bgemm<GF_BIAS|GF_RELU|GF_RESID><<<dim3(2, 2, 1), 256, 0, stream>>>(h3, pL2, stlb + 2*ls1, h3, p3, 256, 256, 256, 256);

  // ---- 9. concat + final linear ----
  k_concat<<<768, 256, 0, stream>>>(p1, p2, p3, pooled);
  k_bgemm<GF_BIAS><<<dim3(2, 6, 1), 256, 0, stream>>>(pooled, pFin, fin_b, nullptr, out, 256, 768, 768, 768);
}

// Round 11
// 3152.141 us; speedup vs baseline: 3.9335x; 1.0418x over previous
//
#include <hip/hip_runtime.h>
#include <hip/hip_bf16.h>
#include <math.h>

// ---- problem constants ----
constexpr int NN   = 131072;   // total nodes (B*NPG)
constexpr int NE   = 262144;   // edges
constexpr int BG   = 256;      // graphs

typedef __bf16 bf16x8 __attribute__((ext_vector_type(8)));
typedef float  f32x4  __attribute__((ext_vector_type(4)));
typedef int    i32x4  __attribute__((ext_vector_type(4)));

__device__ inline float sigm(float x){ return 1.f/(1.f+__expf(-x)); }
__device__ inline unsigned short f2bu(float f){
  union{float f;unsigned u;}v; v.f=f;
  unsigned u = v.u + 0x7fffu + ((v.u>>16)&1u);
  return (unsigned short)(u>>16);
}
__device__ inline bf16x8 cvt8(float4 a, float4 b){
  union { ushort u[8]; bf16x8 v; } r;
  r.u[0]=f2bu(a.x); r.u[1]=f2bu(a.y); r.u[2]=f2bu(a.z); r.u[3]=f2bu(a.w);
  r.u[4]=f2bu(b.x); r.u[5]=f2bu(b.y); r.u[6]=f2bu(b.z); r.u[7]=f2bu(b.w);
  return r.v;
}

__global__ void k_zero(int* __restrict__ p, int n){
  int i = blockIdx.x*256 + threadIdx.x;
  if (i < n) p[i] = 0;
}

// ---------------- node encoder ----------------
__global__ void k_node_enc(const int* __restrict__ x, const float* __restrict__ emb,
                           float* __restrict__ h0){
  int n = blockIdx.x*256 + threadIdx.x;
  if (n >= NN) return;
  int nt = x[2*n], ninv = x[2*n+1];
  float4 v; v.x = emb[nt*3+0]; v.y = emb[nt*3+1]; v.z = emb[nt*3+2]; v.w = (float)ninv;
  reinterpret_cast<float4*>(h0)[n] = v;
}

// ---------------- CSR build (by dst) ----------------
__global__ void k_count(const int* __restrict__ ei, int* __restrict__ deg){
  int e = blockIdx.x*256 + threadIdx.x;
  if (e >= NE) return;
  atomicAdd(&deg[ei[NE + e]], 1);
}
__global__ void k_blocksum(const int* __restrict__ deg, int* __restrict__ bsum){
  __shared__ int sd[256];
  int t = threadIdx.x;
  const int* p = deg + blockIdx.x*1024;
  int s = p[t*4] + p[t*4+1] + p[t*4+2] + p[t*4+3];
  sd[t]=s; __syncthreads();
  for (int d=128; d>0; d>>=1){ if (t<d) sd[t]+=sd[t+d]; __syncthreads(); }
  if (!t) bsum[blockIdx.x] = sd[0];
}
__global__ void k_scanbsum(const int* __restrict__ bsum, int* __restrict__ boff, int* __restrict__ offN){
  __shared__ int s[128];
  int t = threadIdx.x;
  int mine = bsum[t];
  s[t]=mine; __syncthreads();
  for (int d=1; d<128; d<<=1){ int v = (t>=d)? s[t-d]:0; __syncthreads(); s[t]+=v; __syncthreads(); }
  boff[t] = s[t]-mine;
  if (t==127) offN[0] = s[127];
}
__global__ void k_scanchunk(const int* __restrict__ deg, const int* __restrict__ boff, int* __restrict__ offs){
  __shared__ int ts[256];
  int t = threadIdx.x, b = blockIdx.x;
  const int* p = deg + b*1024;
  int v0=p[t*4],v1=p[t*4+1],v2=p[t*4+2],v3=p[t*4+3];
  int mysum=v0+v1+v2+v3;
  ts[t]=mysum; __syncthreads();
  for (int d=1; d<256; d<<=1){ int v=(t>=d)?ts[t-d]:0; __syncthreads(); ts[t]+=v; __syncthreads(); }
  int ex = ts[t]-mysum + boff[b];
  int* o = offs + b*1024 + t*4;
  o[0]=ex; o[1]=ex+v0; o[2]=ex+v0+v1; o[3]=ex+v0+v1+v2;
}
__global__ void k_fill(const int* __restrict__ ei, const int* __restrict__ offs,
                       int* __restrict__ cur, int* __restrict__ esrc){
  int e = blockIdx.x*256 + threadIdx.x;
  if (e >= NE) return;
  int dst = ei[NE+e];
  int pos = offs[dst] + atomicAdd(&cur[dst],1);
  esrc[pos] = ei[e];
}

// ---------------- softmax aggregation, 4-channel (conv1), no-max (exact) ----------------
__global__ void k_aggr4(const float* __restrict__ h, const int* __restrict__ offs,
                        const int* __restrict__ esrc, const float* __restrict__ tptr,
                        float* __restrict__ ag){
  int n = blockIdx.x*256 + threadIdx.x;
  if (n >= NN) return;
  int s = offs[n], e = offs[n+1];
  float4 z = {0,0,0,0};
  if (s == e){ reinterpret_cast<float4*>(ag)[n] = z; return; }
  float t = *tptr;
  float4 num=z, den=z;
  for (int i=s;i<e;++i){
    float4 v = reinterpret_cast<const float4*>(h)[esrc[i]];
    float ex;
    ex=__expf(v.x*t); num.x+=v.x*ex; den.x+=ex;
    ex=__expf(v.y*t); num.y+=v.y*ex; den.y+=ex;
    ex=__expf(v.z*t); num.z+=v.z*ex; den.z+=ex;
    ex=__expf(v.w*t); num.w+=v.w*ex; den.w+=ex;
  }
  float4 r = {num.x/den.x, num.y/den.y, num.z/den.z, num.w/den.w};
  reinterpret_cast<float4*>(ag)[n] = r;
}

// ---------------- softmax aggregation (no-max, 1 pass), fused [h1|ag] layout ----------------
__global__ __launch_bounds__(256) void k_aggr256(float* __restrict__ buf, const int* __restrict__ offs,
                          const int* __restrict__ esrc, const float* __restrict__ tptr, int base){
  int n = base + blockIdx.x, c = threadIdx.x;
  int s = offs[n], e = offs[n+1];
  float* outp = buf + (size_t)blockIdx.x*512 + 256 + c;
  if (s == e){ *outp = 0.f; return; }
  float t = *tptr;
  float num=0.f, den=0.f;
  for (int i=s;i<e;++i){
    float v = buf[(size_t)(esrc[i]-base)*512 + c];
    float ex = __expf(v*t);
    num += v*ex; den += ex;
  }
  *outp = num/den;
}

// ---------------- conv1 linear (K=4, fused), writes [n][512] col 0..255 ----------------
__global__ __launch_bounds__(256) void k_conv1_lin(const float* __restrict__ ag, const float* __restrict__ h0,
                            const float* __restrict__ lW, const float* __restrict__ lb,
                            const float* __restrict__ rW, float* __restrict__ out, int base){
  int n = base + blockIdx.x, c = threadIdx.x;
  float4 a  = reinterpret_cast<const float4*>(ag)[n];
  float4 xv = reinterpret_cast<const float4*>(h0)[n];
  float acc = lb[c];
  acc += a.x*lW[c]  + a.y*lW[256+c]  + a.z*lW[512+c]  + a.w*lW[768+c];
  acc += xv.x*rW[c] + xv.y*rW[256+c] + xv.z*rW[512+c] + xv.w*rW[768+c];
  out[(size_t)blockIdx.x*512 + c] = fmaxf(acc, 0.f);
}

// ---------------- flags ----------------
#define GF_BIAS    1
#define GF_RELU    2
#define GF_RESID   4
#define GF_RESID_B 8
#define GF_ADDC    32
#define GF_ATOMIC  64
#define GF_BF16    128
#define GF_VTP     256   // write output as per-graph B-pack (for AV's V operand)

// ---------------- weight pack: f32 W[K][N] -> MFMA-B bf16 Bp[((k>>3)*N + j)*8 + (k&7)] ----
__global__ void k_packb(const float* __restrict__ W, ushort* __restrict__ Bp, int K, int N){
  int idx = blockIdx.x*256 + threadIdx.x;
  if (idx >= K*N) return;
  int k = idx / N, j = idx - k*N;
  Bp[((size_t)(k>>3)*N + j)*8 + (k&7)] = f2bu(W[idx]);
}
// transposed source: W is [N][K] row-major; B[k][j] = W[j][k]
__global__ void k_packbT(const float* __restrict__ W, ushort* __restrict__ Bp, int K, int N){
  int idx = blockIdx.x*256 + threadIdx.x;
  if (idx >= K*N) return;
  int j = idx / K, k = idx - j*K;
  Bp[((size_t)(k>>3)*N + j)*8 + (k&7)] = f2bu(W[idx]);
}
// Whh -> i8 B-pack with per-column scales. B[k][j] = gWhh[j][k] (gWhh is [768][256]).
// Bp8[((k>>3)*768 + j)*8 + (k&7)] = round(w*127/max_j); cs[j] = max_j/(127*127) (folds h scale)
__global__ __launch_bounds__(256) void k_packhh8(const float* __restrict__ gWhh,
                        char* __restrict__ Bp8, float* __restrict__ cs){
  int j = blockIdx.x, k = threadIdx.x;
  float w = gWhh[(size_t)j*256 + k];
  __shared__ float red[256];
  red[k] = fabsf(w); __syncthreads();
  for (int d=128; d>0; d>>=1){ if (k<d) red[k]=fmaxf(red[k],red[k+d]); __syncthreads(); }
  float mx = fmaxf(red[0], 1e-20f);
  int q = (int)lrintf(w * (127.f/mx));
  q = max(-127, min(127, q));
  Bp8[((size_t)(k>>3)*768 + j)*8 + (k&7)] = (char)q;
  if (k==0) cs[j] = mx/(127.f*127.f);
}
// combined GRU biases
__global__ void k_packbias(const float* __restrict__ gbih, const float* __restrict__ gbhh,
                           float* __restrict__ bc){
  int i = blockIdx.x*256 + threadIdx.x;
  if (i >= 1024) return;
  int c = i & 255;
  float v;
  if (i < 256)      v = gbih[c] + gbhh[c];
  else if (i < 512) v = gbih[256+c] + gbhh[256+c];
  else if (i < 768) v = gbih[512+c];
  else              v = gbhh[512+c];
  bc[i] = v;
}

// ---------------- MFMA GEMM: LDS-free, A f32 (cvt in-reg), B pre-packed bf16 ----------------
template<int FLAGS>
__global__ __launch_bounds__(256) void k_bgemm(const float* __restrict__ A, const ushort* __restrict__ Bp,
                       const float* __restrict__ bias, const float* __restrict__ resid,
                       float* __restrict__ C, int M, int Nn, int K, int lda){
  const int tid = threadIdx.x;
  const int wv = tid>>6, lane = tid&63;
  const int mw = wv>>1, nw = wv&1;
  const int arow = lane&15, ks = lane>>4;
  const int m0 = blockIdx.x*128 + mw*64, n0 = blockIdx.y*128 + nw*64;
  const int kChunk = K / gridDim.z, kBeg = blockIdx.z * kChunk;
  f32x4 acc[4][4] = {};
  const float* Arow0 = A + (size_t)(m0 + 0*16 + arow)*lda;
  const float* Arow1 = A + (size_t)(m0 + 1*16 + arow)*lda;
  const float* Arow2 = A + (size_t)(m0 + 2*16 + arow)*lda;
  const float* Arow3 = A + (size_t)(m0 + 3*16 + arow)*lda;
  #pragma unroll 2
  for (int k0 = kBeg; k0 < kBeg+kChunk; k0 += 32){
    const int kb = (k0>>3) + ks;
    bf16x8 af[4];
    {
      const float4* p0 = reinterpret_cast<const float4*>(Arow0 + k0 + ks*8);
      const float4* p1 = reinterpret_cast<const float4*>(Arow1 + k0 + ks*8);
      const float4* p2 = reinterpret_cast<const float4*>(Arow2 + k0 + ks*8);
      const float4* p3 = reinterpret_cast<const float4*>(Arow3 + k0 + ks*8);
      af[0] = cvt8(p0[0], p0[1]);
      af[1] = cvt8(p1[0], p1[1]);
      af[2] = cvt8(p2[0], p2[1]);
      af[3] = cvt8(p3[0], p3[1]);
    }
    #pragma unroll
    for (int nf=0; nf<4; ++nf){
      const int col = n0 + nf*16 + arow;
      bf16x8 bfr = *reinterpret_cast<const bf16x8*>(Bp + ((size_t)kb*Nn + col)*8);
      #pragma unroll
      for (int mf=0; mf<4; ++mf)
        acc[mf][nf] = __builtin_amdgcn_mfma_f32_16x16x32_bf16(af[mf], bfr, acc[mf][nf], 0, 0, 0);
    }
  }
  #pragma unroll
  for (int nf=0; nf<4; ++nf){
    const int n = n0 + nf*16 + arow;
    float bv  = (FLAGS & GF_BIAS)    ? bias[n]  : 0.f;
    float rbv = (FLAGS & GF_RESID_B) ? resid[n] : 0.f;
    #pragma unroll
    for (int mf=0; mf<4; ++mf){
      #pragma unroll
      for (int r=0; r<4; ++r){
        const int m = m0 + mf*16 + ks*4 + r;
        size_t idx = (size_t)m*Nn + n;
        float v = acc[mf][nf][r];
        if (FLAGS & GF_ATOMIC){ atomicAdd(&C[idx], v); }
        else {
          v += bv;
          if (FLAGS & GF_ADDC)  v += C[idx];
          if (FLAGS & GF_RELU)  v = fmaxf(v, 0.f);
          if (FLAGS & GF_RESID) v += resid[idx];
          v += rbv;
          if (FLAGS & GF_VTP){
            const int rr = m & 511, mg = m >> 9;
            ((ushort*)C)[(size_t)mg*131072 + (((rr>>3)*256 + n)<<3) + (rr&7)] = f2bu(v);
          }
          else if (FLAGS & GF_BF16) reinterpret_cast<__hip_bfloat16*>(C)[idx] = __float2bfloat16(v);
          else C[idx] = v;
        }
      }
    }
  }
}

// ---------------- batched QK^T: S[g][q][k] = Q[g*512+q][:] . K[g*512+k][:] ----------------
__global__ __launch_bounds__(256) void k_qk(const float* __restrict__ Q, const ushort* __restrict__ Kb,
                                            float* __restrict__ S){
  const int tid = threadIdx.x;
  const int wv = tid>>6, lane = tid&63;
  const int mw = wv>>1, nw = wv&1;
  const int arow = lane&15, ks = lane>>4;
  const int m0 = blockIdx.x*128 + mw*64;      // global q row in chunk
  const int n0 = blockIdx.y*128 + nw*64;      // key index 0..511
  const int g  = blockIdx.x>>2;
  const ushort* Kg = Kb + (size_t)g*131072;
  f32x4 acc[4][4] = {};
  const float* Ar0 = Q + (size_t)(m0 + 0*16 + arow)*256;
  const float* Ar1 = Q + (size_t)(m0 + 1*16 + arow)*256;
  const float* Ar2 = Q + (size_t)(m0 + 2*16 + arow)*256;
  const float* Ar3 = Q + (size_t)(m0 + 3*16 + arow)*256;
  #pragma unroll
  for (int k0 = 0; k0 < 256; k0 += 32){
    bf16x8 af[4];
    {
      const float4* p0 = reinterpret_cast<const float4*>(Ar0 + k0 + ks*8);
      const float4* p1 = reinterpret_cast<const float4*>(Ar1 + k0 + ks*8);
      const float4* p2 = reinterpret_cast<const float4*>(Ar2 + k0 + ks*8);
      const float4* p3 = reinterpret_cast<const float4*>(Ar3 + k0 + ks*8);
      af[0] = cvt8(p0[0], p0[1]);
      af[1] = cvt8(p1[0], p1[1]);
      af[2] = cvt8(p2[0], p2[1]);
      af[3] = cvt8(p3[0], p3[1]);
    }
    #pragma unroll
    for (int nf=0; nf<4; ++nf){
      const int j = n0 + nf*16 + arow;        // key row
      bf16x8 bfr = *reinterpret_cast<const bf16x8*>(Kg + (size_t)j*256 + k0 + ks*8);
      #pragma unroll
      for (int mf=0; mf<4; ++mf)
        acc[mf][nf] = __builtin_amdgcn_mfma_f32_16x16x32_bf16(af[mf], bfr, acc[mf][nf], 0, 0, 0);
    }
  }
  #pragma unroll
  for (int nf=0; nf<4; ++nf){
    const int n = n0 + nf*16 + arow;
    #pragma unroll
    for (int mf=0; mf<4; ++mf){
      #pragma unroll
      for (int r=0; r<4; ++r){
        const int m = m0 + mf*16 + ks*4 + r;
        S[(size_t)m*512 + n] = acc[mf][nf][r];
      }
    }
  }
}

// ---------------- row softmax (scale 1/16), f32 S -> normalized bf16 P ----------------
__global__ __launch_bounds__(256) void k_smrow(const float* __restrict__ S, ushort* __restrict__ P){
  const int row = blockIdx.x, tid = threadIdx.x;
  __shared__ float red[4];
  const float* sr = S + (size_t)row*512;
  float s0 = sr[tid], s1 = sr[tid+256];
  float m = fmaxf(s0, s1);
  #pragma unroll
  for (int o=1;o<64;o<<=1) m = fmaxf(m, __shfl_xor(m,o));
  if ((tid&63)==0) red[tid>>6] = m;
  __syncthreads();
  m = fmaxf(fmaxf(red[0],red[1]), fmaxf(red[2],red[3]));
  __syncthreads();
  float e0 = __expf((s0-m)*0.0625f), e1 = __expf((s1-m)*0.0625f);
  float s = e0+e1;
  #pragma unroll
  for (int o=1;o<64;o<<=1) s += __shfl_xor(s,o);
  if ((tid&63)==0) red[tid>>6] = s;
  __syncthreads();
  s = red[0]+red[1]+red[2]+red[3];
  float inv = 1.f/s;
  P[(size_t)row*512 + tid]       = f2bu(e0*inv);
  P[(size_t)row*512 + 256 + tid] = f2bu(e1*inv);
}

// ---------------- batched AV: O[g*512+q][c] = sum_k P[q][k] V[k][c] ----------------
__global__ __launch_bounds__(256) void k_av(const ushort* __restrict__ Pb, const ushort* __restrict__ VTp,
                                            float* __restrict__ O){
  const int tid = threadIdx.x;
  const int wv = tid>>6, lane = tid&63;
  const int mw = wv>>1, nw = wv&1;
  const int arow = lane&15, ks = lane>>4;
  const int m0 = blockIdx.x*128 + mw*64;
  const int n0 = blockIdx.y*128 + nw*64;      // c 0..255
  const int g  = blockIdx.x>>2;
  const ushort* Vg = VTp + (size_t)g*131072;
  f32x4 acc[4][4] = {};
  const ushort* Pr0 = Pb + (size_t)(m0 + 0*16 + arow)*512;
  const ushort* Pr1 = Pb + (size_t)(m0 + 1*16 + arow)*512;
  const ushort* Pr2 = Pb + (size_t)(m0 + 2*16 + arow)*512;
  const ushort* Pr3 = Pb + (size_t)(m0 + 3*16 + arow)*512;
  #pragma unroll 2
  for (int k0 = 0; k0 < 512; k0 += 32){
    const int kb = (k0>>3) + ks;
    bf16x8 af[4];
    af[0] = *reinterpret_cast<const bf16x8*>(Pr0 + k0 + ks*8);
    af[1] = *reinterpret_cast<const bf16x8*>(Pr1 + k0 + ks*8);
    af[2] = *reinterpret_cast<const bf16x8*>(Pr2 + k0 + ks*8);
    af[3] = *reinterpret_cast<const bf16x8*>(Pr3 + k0 + ks*8);
    #pragma unroll
    for (int nf=0; nf<4; ++nf){
      const int col = n0 + nf*16 + arow;
      bf16x8 bfr = *reinterpret_cast<const bf16x8*>(Vg + ((size_t)kb*256 + col)*8);
      #pragma unroll
      for (int mf=0; mf<4; ++mf)
        acc[mf][nf] = __builtin_amdgcn_mfma_f32_16x16x32_bf16(af[mf], bfr, acc[mf][nf], 0, 0, 0);
    }
  }
  #pragma unroll
  for (int nf=0; nf<4; ++nf){
    const int n = n0 + nf*16 + arow;
    #pragma unroll
    for (int mf=0; mf<4; ++mf){
      #pragma unroll
      for (int r=0; r<4; ++r){
        const int m = m0 + mf*16 + ks*4 + r;
        O[(size_t)m*256 + n] = acc[mf][nf][r];
      }
    }
  }
}

// ---------------- small utilities ----------------
__global__ void k_rowbias(const float* __restrict__ bias, float* __restrict__ C, int Nn, int total){
  int i = blockIdx.x*256 + threadIdx.x;
  if (i < total) C[i] = bias[i % Nn];
}
__global__ void k_qvec(const float* __restrict__ seed, const float* __restrict__ Wq,
                       const float* __restrict__ bq, float* __restrict__ qv){
  __shared__ float s[256];
  int t = threadIdx.x;
  s[t] = seed[t]; __syncthreads();
  float acc = bq[t];
  for (int c = 0; c < 256; ++c) acc += s[c] * Wq[c*256 + t];
  qv[t] = acc;
}
// wk2q[c] = sum_t Wk2[c][t]*qv[t]; wk2q[256] = bk2 . qv
__global__ __launch_bounds__(256) void k_wk2q(const float* __restrict__ Wk2, const float* __restrict__ bk2,
                      const float* __restrict__ qv, float* __restrict__ outv){
  __shared__ float qs[256];
  __shared__ float red[4];
  int t = threadIdx.x;
  qs[t] = qv[t]; __syncthreads();
  float a = 0.f;
  for (int c=0;c<256;c+=4){
    float4 w = *reinterpret_cast<const float4*>(Wk2 + t*256 + c);
    a += w.x*qs[c] + w.y*qs[c+1] + w.z*qs[c+2] + w.w*qs[c+3];
  }
  outv[t] = a;
  float bb = bk2[t]*qs[t];
  #pragma unroll
  for (int o=1;o<64;o<<=1) bb += __shfl_xor(bb,o);
  if ((t&63)==0) red[t>>6] = bb;
  __syncthreads();
  if (t==0) outv[256] = red[0]+red[1]+red[2]+red[3];
}
// fused PMA: logits = (kk @ wk2q + b2q)/16; alpha = softmax; wsum = sum_j alpha_j kk[j]
__global__ __launch_bounds__(256) void k_pmafuse(const float* __restrict__ kk, const float* __restrict__ wkq,
                        float* __restrict__ wsum){
  int g = blockIdx.x, tid = threadIdx.x;
  __shared__ float qs[256];
  __shared__ float sc[512];
  __shared__ float red[4];
  qs[tid] = wkq[tid];
  __syncthreads();
  const float b2q = wkq[256];
  const float* kg = kk + (size_t)g*512*256;
  float l0=0.f, l1=0.f;
  for (int j0=0;j0<2;++j0){
    int j = tid + j0*256;
    const float* kr = kg + (size_t)j*256;
    float a = 0.f;
    for (int c=0;c<256;c+=4){
      float4 k4 = *reinterpret_cast<const float4*>(kr + c);
      a += k4.x*qs[c] + k4.y*qs[c+1] + k4.z*qs[c+2] + k4.w*qs[c+3];
    }
    a = (a + b2q)*0.0625f;
    if (j0) l1=a; else l0=a;
  }
  float m = fmaxf(l0,l1);
  #pragma unroll
  for (int o=1;o<64;o<<=1) m = fmaxf(m, __shfl_xor(m,o));
  if ((tid&63)==0) red[tid>>6] = m;
  __syncthreads();
  m = fmaxf(fmaxf(red[0],red[1]), fmaxf(red[2],red[3]));
  __syncthreads();
  float e0 = __expf(l0-m), e1 = __expf(l1-m);
  sc[tid]=e0; sc[tid+256]=e1;
  float s = e0+e1;
  #pragma unroll
  for (int o=1;o<64;o<<=1) s += __shfl_xor(s,o);
  if ((tid&63)==0) red[tid>>6] = s;
  __syncthreads();
  s = red[0]+red[1]+red[2]+red[3];
  float invs = 1.f/s;
  float acc = 0.f;
  for (int j=0;j<512;++j) acc += sc[j] * kg[(size_t)j*256 + tid];
  wsum[(size_t)g*256+tid] = acc*invs;
}
__global__ void k_concat(const float* __restrict__ p1, const float* __restrict__ p2,
                         const float* __restrict__ p3, float* __restrict__ pooled){
  int idx = blockIdx.x*256 + threadIdx.x;
  int b = idx / 768, j = idx % 768;
  float v = (j < 256) ? p1[b*256+j] : (j < 512) ? p2[b*256+j-256] : p3[b*256+j-512];
  pooled[idx] = v;
}

// ---------------- GRU v10: i8 Whh stream (per-col scales). 1 graph/block, 512 thr ----------
// Per-step L2 traffic halves vs bf16 (192 KB). h quantized to i8 (|h|<1 guaranteed);
// f32 master h kept in gate threads. gi windowed in LDS via bf16 MFMA (unchanged).
__global__ __launch_bounds__(512) void k_gru10(const float* __restrict__ X,
                      const ushort* __restrict__ pIh, const char* __restrict__ pHh8,
                      const float* __restrict__ csg, const float* __restrict__ bc,
                      float* __restrict__ p2){
  extern __shared__ char gsm[];
  float*  GIw  = (float*)gsm;                   // [32][768]  98304 B
  float*  gh   = (float*)(gsm + 98304);         // [768]      3072 B
  float*  bcl  = (float*)(gsm + 101376);        // [1024]     4096 B
  float*  csl  = (float*)(gsm + 105472);        // [768]      3072 B
  char*   hbf8 = (char*) (gsm + 108544);        // [256]      256 B (8-aligned)
  const int g = blockIdx.x;
  const int tid = threadIdx.x;
  const int wv = tid>>6, lane = tid&63;
  const int arow = lane&15, ks = lane>>4;
  for (int i=tid;i<1024;i+=512) bcl[i] = bc[i];
  for (int i=tid;i<768;i+=512)  csl[i] = csg[i];
  if (tid < 256) hbf8[tid] = 0;
  float h_reg = 0.f;
  const float* Xg = X + (size_t)g*512*256;
  __syncthreads();
  for (int w=0; w<16; ++w){
    const int t0 = w*32;
    // ---- window GEMM: GIw[32][768] = X[t0..+32][256] @ Wih (bf16, per-wave 96-col stripe) ----
    #pragma unroll
    for (int mt=0; mt<2; ++mt){
      const float* xr = Xg + (size_t)(t0 + mt*16 + arow)*256;
      f32x4 acc[6] = {};
      #pragma unroll
      for (int kt=0; kt<8; ++kt){
        const float4* xp = reinterpret_cast<const float4*>(xr + kt*32 + ks*8);
        bf16x8 af = cvt8(xp[0], xp[1]);
        #pragma unroll
        for (int nt=0; nt<6; ++nt){
          bf16x8 bfr = *reinterpret_cast<const bf16x8*>(pIh + ((size_t)(kt*4+ks)*768 + wv*96+nt*16+arow)*8);
          acc[nt] = __builtin_amdgcn_mfma_f32_16x16x32_bf16(af, bfr, acc[nt], 0,0,0);
        }
      }
      #pragma unroll
      for (int nt=0; nt<6; ++nt){
        const int col = wv*96 + nt*16 + arow;
        #pragma unroll
        for (int r=0;r<4;++r)
          GIw[(size_t)(mt*16 + ks*4 + r)*768 + col] = acc[nt][r];
      }
    }
    for (int dt=0; dt<32; ++dt){
      // gh_i32 = h8 @ Whh8 : A row0 = h8 (rows 1..15 zero); i8 MFMA K=32
      i32x4 sacc[6] = {};
      #pragma unroll
      for (int kt=0; kt<8; ++kt){
        long a8 = 0;
        if (arow == 0) a8 = *reinterpret_cast<const long*>(hbf8 + kt*32 + ks*8);
        #pragma unroll
        for (int nt=0; nt<6; ++nt){
          const int col = wv*96 + nt*16 + arow;
          long b8 = *reinterpret_cast<const long*>(pHh8 + ((size_t)(kt*4+ks)*768 + col)*8);
          sacc[nt] = __builtin_amdgcn_mfma_i32_16x16x32_i8(a8, b8, sacc[nt], 0,0,0);
        }
      }
      if (ks == 0){     // D row0 lives in reg 0 of lanes 0..15
        #pragma unroll
        for (int nt=0; nt<6; ++nt){
          const int col = wv*96 + nt*16 + arow;
          gh[col] = (float)sacc[nt][0] * csl[col];
        }
      }
      __syncthreads();   // gh + GIw ready; hbf8 reads done
      if (tid < 256){
        const int c = tid;
        const float* gir = GIw + (size_t)dt*768;
        float rr = sigm(gir[c]     + gh[c]     + bcl[c]);
        float zz = sigm(gir[256+c] + gh[256+c] + bcl[256+c]);
        float nn = tanhf(gir[512+c] + bcl[512+c] + rr*(gh[512+c] + bcl[768+c]));
        h_reg = (1.f-zz)*nn + zz*h_reg;
        int q = (int)lrintf(h_reg*127.f);
        q = max(-127, min(127, q));
        hbf8[c] = (char)q;
      }
      __syncthreads();   // hbf8 ready for next step
    }
  }
  if (tid < 256) p2[(size_t)g*256 + tid] = h_reg;
}

// =====================================================================
extern "C" void kernel_launch(void* const* d_in, const int* in_sizes, int n_in,
                              void* d_out, int out_size, void* d_ws, size_t ws_size,
                              hipStream_t stream){
  const int*   x      = (const int*)  d_in[0];
  const int*   ei     = (const int*)  d_in[1];
  const float* emb_w  = (const float*)d_in[3];
  const float* c1_lW  = (const float*)d_in[4];
  const float* c1_lb  = (const float*)d_in[5];
  const float* c1_rW  = (const float*)d_in[6];
  const float* t1     = (const float*)d_in[7];
  const float* c2_lW  = (const float*)d_in[8];
  const float* c2_lb  = (const float*)d_in[9];
  const float* c2_rW  = (const float*)d_in[10];
  const float* t2     = (const float*)d_in[11];
  const float* mlp_W  = (const float*)d_in[12];
  const float* mlp_b  = (const float*)d_in[13];
  const float* gWih   = (const float*)d_in[14];
  const float* gWhh   = (const float*)d_in[15];
  const float* gbih   = (const float*)d_in[16];
  const float* gbhh   = (const float*)d_in[17];
  const float* stWq   = (const float*)d_in[18];
  const float* stbq   = (const float*)d_in[19];
  const float* stWk   = (const float*)d_in[20];
  const float* stbk   = (const float*)d_in[21];
  const float* stWv   = (const float*)d_in[22];
  const float* stbv   = (const float*)d_in[23];
  const float* stWo   = (const float*)d_in[24];
  const float* stbo   = (const float*)d_in[25];
  const float* stlW   = (const float*)d_in[26];
  const float* stlb   = (const float*)d_in[27];
  const float* pma_lW = (const float*)d_in[28];
  const float* pma_lb = (const float*)d_in[29];
  const float* seed   = (const float*)d_in[30];
  const float* fin_W  = (const float*)d_in[31];
  const float* fin_b  = (const float*)d_in[32];
  float* out = (float*)d_out;

  // ---- choose chunk size by available workspace ----
  auto needFor = [](int CHe)->size_t{
    size_t bufN = (size_t)CHe*512*512;
    size_t floats = (size_t)33554432 + 3*bufN + 2*524288 + 2*196608 + 8*65536 + 196608 + 320 + 512;
    size_t ints   = 131072 + 131200 + 131072 + 262144 + 128 + 128;
    return floats*4 + ints*4 + 4096;
  };
  const int CHe = (ws_size >= needFor(64)) ? 64 : 32;
  if (ws_size < needFor(32)) return;
  const int NCHUNKe = BG / CHe;
  const int NCNe = CHe * 512;
  const size_t bufN = (size_t)CHe*512*512;

  // ---- workspace carve ----
  float* H2   = (float*)d_ws;                    // NN*256 f32 (persists)
  float* bufA = H2   + (size_t)33554432;
  float* bufB = bufA + bufN;
  float* bufC = bufB + bufN;
  float* h0   = bufC + bufN;                     // NN*4
  float* ag1  = h0   + (size_t)524288;           // NN*4
  float* wT1  = ag1  + (size_t)524288;           // GRU packs (pIh / pHh8+cs)
  float* wT2  = wT1  + (size_t)196608;           // pC2 + bcomb
  float* p1   = wT2  + (size_t)196608;
  float* p2   = p1   + (size_t)65536;
  float* p3   = p2   + (size_t)65536;
  float* av2  = p3   + (size_t)65536;            // (= PMA wsum)
  float* s1   = av2  + (size_t)65536;
  float* s2v  = s1   + (size_t)65536;
  float* v3   = s2v  + (size_t)65536;
  float* h3   = v3   + (size_t)65536;
  float* pooled = h3 + (size_t)65536;
  float* qv   = pooled + (size_t)196608;
  int*   deg  = (int*)(qv + 320);
  int*   offs = deg  + 131072;
  int*   cur  = offs + 131200;
  int*   esrc = cur  + 131072;
  int*   bsum = esrc + 262144;
  int*   boff = bsum + 128;
  float* wkq  = (float*)(boff + 128);            // 512 floats (wk2q[256] + b2q)

  ushort* pIh  = (ushort*)wT1;                   // 196608 ush = 98304 f
  char*   pHh8 = (char*)(wT1 + 98304);           // 196608 B = 49152 f
  float*  csHh = wT1 + 98304 + 49152;            // 768 f
  ushort* pC2  = (ushort*)wT2;
  float*  bcomb= wT2 + 65536;
  float*  pa   = h0;                             // dead after conv -> ST packs
  ushort* pQ0  = (ushort*)(pa);
  ushort* pK0  = (ushort*)(pa + 32768);
  ushort* pV0  = (ushort*)(pa + 65536);
  ushort* pO0  = (ushort*)(pa + 98304);
  ushort* pL0  = (ushort*)(pa + 131072);
  ushort* pPma = (ushort*)(pa + 163840);
  ushort* pV1  = (ushort*)(pa + 229376);
  ushort* pO1  = (ushort*)(pa + 262144);
  ushort* pL1  = (ushort*)(pa + 294912);
  ushort* pV2  = (ushort*)(pa + 327680);
  ushort* pO2  = (ushort*)(pa + 360448);
  ushort* pL2  = (ushort*)(pa + 393216);
  ushort* pFin = (ushort*)(pa + 425984);

  // attention sub-buffers (inside bufA/bufB)
  ushort* VTp = (ushort*)(bufA + bufN/2);
  ushort* Kbf = (ushort*)bufB;
  ushort* Pbf = (ushort*)(bufB + bufN/4);

  const int ls0 = 65536, ls1 = 256;

  // ---- 1. node encoder ----
  k_node_enc<<<NN/256, 256, 0, stream>>>(x, emb_w, h0);

  // ---- 2. CSR ----
  k_zero<<<NN/256, 256, 0, stream>>>(deg, NN);
  k_count<<<NE/256, 256, 0, stream>>>(ei, deg);
  k_blocksum<<<128, 256, 0, stream>>>(deg, bsum);
  k_scanbsum<<<1, 128, 0, stream>>>(bsum, boff, offs + NN);
  k_scanchunk<<<128, 256, 0, stream>>>(deg, boff, offs);
  k_zero<<<NN/256, 256, 0, stream>>>(cur, NN);
  k_fill<<<NE/256, 256, 0, stream>>>(ei, offs, cur, esrc);

  // ---- 3. conv1 aggregation + early packs ----
  k_aggr4<<<NN/256, 256, 0, stream>>>(h0, offs, esrc, t1, ag1);
  k_packb <<<256, 256, 0, stream>>>(c2_rW, pC2, 256, 256);
  k_packb <<<256, 256, 0, stream>>>(c2_lW, pC2 + 65536, 256, 256);
  k_packbT<<<768, 256, 0, stream>>>(gWih, pIh, 256, 768);
  k_packhh8<<<768, 256, 0, stream>>>(gWhh, pHh8, csHh);
  k_packbias<<<4, 256, 0, stream>>>(gbih, gbhh, bcomb);

  // ---- 4. conv1 + conv2 (fused K=512), chunked ----
  for (int cg = 0; cg < NCHUNKe; ++cg){
    const int base = cg * NCNe;
    float* Hc = H2 + (size_t)base * 256;
    const dim3 gg(NCNe/128, 2, 1);
    k_conv1_lin<<<NCNe, 256, 0, stream>>>(ag1, h0, c1_lW, c1_lb, c1_rW, bufA, base);
    k_aggr256<<<NCNe, 256, 0, stream>>>(bufA, offs, esrc, t2, base);
    k_bgemm<GF_BIAS|GF_RELU><<<gg, 256, 0, stream>>>(bufA, pC2, c2_lb, nullptr, Hc, NCNe, 256, 512, 512);
  }
  // H2 = h2 (full)

  // ---- 5. p1 = MLP pool via MFMA (pack mlp_W bf16 into free bufB; split-K atomic) ----
  k_packb<<<131072, 256, 0, stream>>>(mlp_W, (ushort*)bufB, 131072, 256);
  k_rowbias<<<256, 256, 0, stream>>>(mlp_b, p1, 256, 65536);
  k_bgemm<GF_ATOMIC><<<dim3(2, 2, 64), 256, 0, stream>>>(H2, (ushort*)bufB, nullptr, nullptr, p1, 256, 256, NN, 131072);

  // ---- 6. GRU v10 (i8 Whh stream; 256 blocks, 8 waves) ----
  k_gru10<<<BG, 512, 108800, stream>>>(H2, pIh, pHh8, csHh, bcomb, p2);

  // ---- 7. ST packs + set transformer (MFMA attention + fused PMA), chunked ----
  k_packb<<<256, 256, 0, stream>>>(stWq,        pQ0, 256, 256);
  k_packb<<<256, 256, 0, stream>>>(stWk,        pK0, 256, 256);
  k_packb<<<256, 256, 0, stream>>>(stWv,        pV0, 256, 256);
  k_packb<<<256, 256, 0, stream>>>(stWo,        pO0, 256, 256);
  k_packb<<<256, 256, 0, stream>>>(stlW,        pL0, 256, 256);
  k_packb<<<256, 256, 0, stream>>>(pma_lW,      pPma,256, 256);
  k_packb<<<256, 256, 0, stream>>>(stWv + ls0,  pV1, 256, 256);
  k_packb<<<256, 256, 0, stream>>>(stWo + ls0,  pO1, 256, 256);
  k_packb<<<256, 256, 0, stream>>>(stlW + ls0,  pL1, 256, 256);
  k_packb<<<256, 256, 0, stream>>>(stWv + 2*ls0,pV2, 256, 256);
  k_packb<<<256, 256, 0, stream>>>(stWo + 2*ls0,pO2, 256, 256);
  k_packb<<<256, 256, 0, stream>>>(stlW + 2*ls0,pL2, 256, 256);
  k_packb<<<2304, 256, 0, stream>>>(fin_W,      pFin,768, 768);
  k_qvec<<<1, 256, 0, stream>>>(seed, stWq + ls0, stbq + ls1, qv);
  k_wk2q<<<1, 256, 0, stream>>>(stWk + ls0, stbk + ls1, qv, wkq);

  for (int cg = 0; cg < NCHUNKe; ++cg){
    const int base = cg * NCNe;
    float* Hc = H2 + (size_t)base * 256;
    const dim3 gg(NCNe/128, 2, 1);
    k_bgemm<GF_BIAS><<<gg, 256, 0, stream>>>(Hc, pQ0, stbq, nullptr, bufA, NCNe, 256, 256, 256);           // Q f32
    k_bgemm<GF_BIAS|GF_BF16><<<gg, 256, 0, stream>>>(Hc, pK0, stbk, nullptr, (float*)Kbf, NCNe, 256, 256, 256); // K bf16
    k_bgemm<GF_BIAS|GF_VTP><<<gg, 256, 0, stream>>>(Hc, pV0, stbv, nullptr, (float*)VTp, NCNe, 256, 256, 256);  // V packed
    k_qk<<<dim3(NCNe/128, 4), 256, 0, stream>>>(bufA, Kbf, bufC);                                          // S f32
    k_smrow<<<NCNe, 256, 0, stream>>>(bufC, Pbf);                                                          // P bf16
    k_av<<<dim3(NCNe/128, 2), 256, 0, stream>>>(Pbf, VTp, bufA);                                           // O -> bufA
    k_bgemm<GF_BIAS|GF_RESID><<<gg, 256, 0, stream>>>(bufA, pO0, stbo, Hc, Hc, NCNe, 256, 256, 256);       // h_sab in-place
    k_bgemm<GF_BIAS|GF_RELU|GF_RESID><<<gg, 256, 0, stream>>>(Hc, pL0, stlb, Hc, bufA, NCNe, 256, 256, 256); // h_enc
    k_bgemm<GF_BIAS|GF_RELU><<<gg, 256, 0, stream>>>(bufA, pPma, pma_lb, nullptr, bufB, NCNe, 256, 256, 256); // kk
    k_pmafuse<<<CHe, 256, 0, stream>>>(bufB, wkq, av2 + (size_t)cg*CHe*256);                               // wsum
  }

  // ---- 8. PMA tail + decoder SAB ----
  k_bgemm<GF_BIAS><<<dim3(2, 2, 1), 256, 0, stream>>>(av2, pV1, stbv + ls1, nullptr, v3, 256, 256, 256, 256);   // true av2
  k_bgemm<GF_BIAS|GF_RESID_B><<<dim3(2, 2, 1), 256, 0, stream>>>(v3, pO1, stbo + ls1, seed, s1, 256, 256, 256, 256);
  k_bgemm<GF_BIAS|GF_RELU|GF_RESID><<<dim3(2, 2, 1), 256, 0, stream>>>(s1, pL1, stlb + ls1, s1, s2v, 256, 256, 256, 256);
  k_bgemm<GF_BIAS><<<dim3(2, 2, 1), 256, 0, stream>>>(s2v, pV2, stbv + 2*ls1, nullptr, v3, 256, 256, 256, 256);
  k_bgemm<GF_BIAS|GF_RESID><<<dim3(2, 2, 1), 256, 0, stream>>>(v3, pO2, stbo + 2*ls1, s2v, h3, 256, 256, 256, 256);
  k_bgemm<GF_BIAS|GF_RELU|GF_RESID><<<dim3(2, 2, 1), 256, 0, stream>>>(h3, pL2, stlb + 2*ls1, h3, p3, 256, 256, 256, 256);

  // ---- 9. concat + final linear ----
  k_concat<<<768, 256, 0, stream>>>(p1, p2, p3, pooled);
  k_bgemm<GF_BIAS><<<dim3(2, 6, 1), 256, 0, stream>>>(pooled, pFin, fin_b, nullptr, out, 256, 768, 768, 768);
}

// Round 12
// 3145.252 us; speedup vs baseline: 3.9421x; 1.0022x over previous
//
#include <hip/hip_runtime.h>
#include <hip/hip_bf16.h>
#include <math.h>

// ---- problem constants ----
constexpr int NN   = 131072;   // total nodes (B*NPG)
constexpr int NE   = 262144;   // edges
constexpr int BG   = 256;      // graphs

typedef __bf16 bf16x8 __attribute__((ext_vector_type(8)));
typedef float  f32x4  __attribute__((ext_vector_type(4)));
typedef int    i32x4  __attribute__((ext_vector_type(4)));

__device__ inline float sigm(float x){ return 1.f/(1.f+__expf(-x)); }
__device__ inline unsigned short f2bu(float f){
  union{float f;unsigned u;}v; v.f=f;
  unsigned u = v.u + 0x7fffu + ((v.u>>16)&1u);
  return (unsigned short)(u>>16);
}
__device__ inline bf16x8 cvt8(float4 a, float4 b){
  union { ushort u[8]; bf16x8 v; } r;
  r.u[0]=f2bu(a.x); r.u[1]=f2bu(a.y); r.u[2]=f2bu(a.z); r.u[3]=f2bu(a.w);
  r.u[4]=f2bu(b.x); r.u[5]=f2bu(b.y); r.u[6]=f2bu(b.z); r.u[7]=f2bu(b.w);
  return r.v;
}

__global__ void k_zero(int* __restrict__ p, int n){
  int i = blockIdx.x*256 + threadIdx.x;
  if (i < n) p[i] = 0;
}

// ---------------- node encoder ----------------
__global__ void k_node_enc(const int* __restrict__ x, const float* __restrict__ emb,
                           float* __restrict__ h0){
  int n = blockIdx.x*256 + threadIdx.x;
  if (n >= NN) return;
  int nt = x[2*n], ninv = x[2*n+1];
  float4 v; v.x = emb[nt*3+0]; v.y = emb[nt*3+1]; v.z = emb[nt*3+2]; v.w = (float)ninv;
  reinterpret_cast<float4*>(h0)[n] = v;
}

// ---------------- CSR build (by dst) ----------------
__global__ void k_count(const int* __restrict__ ei, int* __restrict__ deg){
  int e = blockIdx.x*256 + threadIdx.x;
  if (e >= NE) return;
  atomicAdd(&deg[ei[NE + e]], 1);
}
__global__ void k_blocksum(const int* __restrict__ deg, int* __restrict__ bsum){
  __shared__ int sd[256];
  int t = threadIdx.x;
  const int* p = deg + blockIdx.x*1024;
  int s = p[t*4] + p[t*4+1] + p[t*4+2] + p[t*4+3];
  sd[t]=s; __syncthreads();
  for (int d=128; d>0; d>>=1){ if (t<d) sd[t]+=sd[t+d]; __syncthreads(); }
  if (!t) bsum[blockIdx.x] = sd[0];
}
__global__ void k_scanbsum(const int* __restrict__ bsum, int* __restrict__ boff, int* __restrict__ offN){
  __shared__ int s[128];
  int t = threadIdx.x;
  int mine = bsum[t];
  s[t]=mine; __syncthreads();
  for (int d=1; d<128; d<<=1){ int v = (t>=d)? s[t-d]:0; __syncthreads(); s[t]+=v; __syncthreads(); }
  boff[t] = s[t]-mine;
  if (t==127) offN[0] = s[127];
}
__global__ void k_scanchunk(const int* __restrict__ deg, const int* __restrict__ boff, int* __restrict__ offs){
  __shared__ int ts[256];
  int t = threadIdx.x, b = blockIdx.x;
  const int* p = deg + b*1024;
  int v0=p[t*4],v1=p[t*4+1],v2=p[t*4+2],v3=p[t*4+3];
  int mysum=v0+v1+v2+v3;
  ts[t]=mysum; __syncthreads();
  for (int d=1; d<256; d<<=1){ int v=(t>=d)?ts[t-d]:0; __syncthreads(); ts[t]+=v; __syncthreads(); }
  int ex = ts[t]-mysum + boff[b];
  int* o = offs + b*1024 + t*4;
  o[0]=ex; o[1]=ex+v0; o[2]=ex+v0+v1; o[3]=ex+v0+v1+v2;
}
__global__ void k_fill(const int* __restrict__ ei, const int* __restrict__ offs,
                       int* __restrict__ cur, int* __restrict__ esrc){
  int e = blockIdx.x*256 + threadIdx.x;
  if (e >= NE) return;
  int dst = ei[NE+e];
  int pos = offs[dst] + atomicAdd(&cur[dst],1);
  esrc[pos] = ei[e];
}

// ---------------- softmax aggregation, 4-channel (conv1), no-max (exact) ----------------
__global__ void k_aggr4(const float* __restrict__ h, const int* __restrict__ offs,
                        const int* __restrict__ esrc, const float* __restrict__ tptr,
                        float* __restrict__ ag){
  int n = blockIdx.x*256 + threadIdx.x;
  if (n >= NN) return;
  int s = offs[n], e = offs[n+1];
  float4 z = {0,0,0,0};
  if (s == e){ reinterpret_cast<float4*>(ag)[n] = z; return; }
  float t = *tptr;
  float4 num=z, den=z;
  for (int i=s;i<e;++i){
    float4 v = reinterpret_cast<const float4*>(h)[esrc[i]];
    float ex;
    ex=__expf(v.x*t); num.x+=v.x*ex; den.x+=ex;
    ex=__expf(v.y*t); num.y+=v.y*ex; den.y+=ex;
    ex=__expf(v.z*t); num.z+=v.z*ex; den.z+=ex;
    ex=__expf(v.w*t); num.w+=v.w*ex; den.w+=ex;
  }
  float4 r = {num.x/den.x, num.y/den.y, num.z/den.z, num.w/den.w};
  reinterpret_cast<float4*>(ag)[n] = r;
}

// ---------------- softmax aggregation (no-max, 1 pass), fused [h1|ag] layout ----------------
__global__ __launch_bounds__(256) void k_aggr256(float* __restrict__ buf, const int* __restrict__ offs,
                          const int* __restrict__ esrc, const float* __restrict__ tptr, int base){
  int n = base + blockIdx.x, c = threadIdx.x;
  int s = offs[n], e = offs[n+1];
  float* outp = buf + (size_t)blockIdx.x*512 + 256 + c;
  if (s == e){ *outp = 0.f; return; }
  float t = *tptr;
  float num=0.f, den=0.f;
  for (int i=s;i<e;++i){
    float v = buf[(size_t)(esrc[i]-base)*512 + c];
    float ex = __expf(v*t);
    num += v*ex; den += ex;
  }
  *outp = num/den;
}

// ---------------- conv1 linear (K=4, fused), writes [n][512] col 0..255 ----------------
__global__ __launch_bounds__(256) void k_conv1_lin(const float* __restrict__ ag, const float* __restrict__ h0,
                            const float* __restrict__ lW, const float* __restrict__ lb,
                            const float* __restrict__ rW, float* __restrict__ out, int base){
  int n = base + blockIdx.x, c = threadIdx.x;
  float4 a  = reinterpret_cast<const float4*>(ag)[n];
  float4 xv = reinterpret_cast<const float4*>(h0)[n];
  float acc = lb[c];
  acc += a.x*lW[c]  + a.y*lW[256+c]  + a.z*lW[512+c]  + a.w*lW[768+c];
  acc += xv.x*rW[c] + xv.y*rW[256+c] + xv.z*rW[512+c] + xv.w*rW[768+c];
  out[(size_t)blockIdx.x*512 + c] = fmaxf(acc, 0.f);
}

// ---------------- flags ----------------
#define GF_BIAS    1
#define GF_RELU    2
#define GF_RESID   4
#define GF_RESID_B 8
#define GF_ADDC    32
#define GF_ATOMIC  64
#define GF_BF16    128
#define GF_VTP     256   // write output as per-graph B-pack (for AV's V operand)

// ---------------- weight pack: f32 W[K][N] -> MFMA-B bf16 Bp[((k>>3)*N + j)*8 + (k&7)] ----
__global__ void k_packb(const float* __restrict__ W, ushort* __restrict__ Bp, int K, int N){
  int idx = blockIdx.x*256 + threadIdx.x;
  if (idx >= K*N) return;
  int k = idx / N, j = idx - k*N;
  Bp[((size_t)(k>>3)*N + j)*8 + (k&7)] = f2bu(W[idx]);
}
// transposed source: W is [N][K] row-major; B[k][j] = W[j][k]
__global__ void k_packbT(const float* __restrict__ W, ushort* __restrict__ Bp, int K, int N){
  int idx = blockIdx.x*256 + threadIdx.x;
  if (idx >= K*N) return;
  int j = idx / K, k = idx - j*K;
  Bp[((size_t)(k>>3)*N + j)*8 + (k&7)] = f2bu(W[idx]);
}
// Whh -> i8 B-pack with per-column scales. B[k][j] = gWhh[j][k] (gWhh is [768][256]).
__global__ __launch_bounds__(256) void k_packhh8(const float* __restrict__ gWhh,
                        char* __restrict__ Bp8, float* __restrict__ cs){
  int j = blockIdx.x, k = threadIdx.x;
  float w = gWhh[(size_t)j*256 + k];
  __shared__ float red[256];
  red[k] = fabsf(w); __syncthreads();
  for (int d=128; d>0; d>>=1){ if (k<d) red[k]=fmaxf(red[k],red[k+d]); __syncthreads(); }
  float mx = fmaxf(red[0], 1e-20f);
  int q = (int)lrintf(w * (127.f/mx));
  q = max(-127, min(127, q));
  Bp8[((size_t)(k>>3)*768 + j)*8 + (k&7)] = (char)q;
  if (k==0) cs[j] = mx/(127.f*127.f);
}
// combined GRU biases
__global__ void k_packbias(const float* __restrict__ gbih, const float* __restrict__ gbhh,
                           float* __restrict__ bc){
  int i = blockIdx.x*256 + threadIdx.x;
  if (i >= 1024) return;
  int c = i & 255;
  float v;
  if (i < 256)      v = gbih[c] + gbhh[c];
  else if (i < 512) v = gbih[256+c] + gbhh[256+c];
  else if (i < 768) v = gbih[512+c];
  else              v = gbhh[512+c];
  bc[i] = v;
}

// ---------------- MFMA GEMM: LDS-free, A f32 (cvt in-reg), B pre-packed bf16 ----------------
template<int FLAGS>
__global__ __launch_bounds__(256) void k_bgemm(const float* __restrict__ A, const ushort* __restrict__ Bp,
                       const float* __restrict__ bias, const float* __restrict__ resid,
                       float* __restrict__ C, int M, int Nn, int K, int lda){
  const int tid = threadIdx.x;
  const int wv = tid>>6, lane = tid&63;
  const int mw = wv>>1, nw = wv&1;
  const int arow = lane&15, ks = lane>>4;
  const int m0 = blockIdx.x*128 + mw*64, n0 = blockIdx.y*128 + nw*64;
  const int kChunk = K / gridDim.z, kBeg = blockIdx.z * kChunk;
  f32x4 acc[4][4] = {};
  const float* Arow0 = A + (size_t)(m0 + 0*16 + arow)*lda;
  const float* Arow1 = A + (size_t)(m0 + 1*16 + arow)*lda;
  const float* Arow2 = A + (size_t)(m0 + 2*16 + arow)*lda;
  const float* Arow3 = A + (size_t)(m0 + 3*16 + arow)*lda;
  #pragma unroll 2
  for (int k0 = kBeg; k0 < kBeg+kChunk; k0 += 32){
    const int kb = (k0>>3) + ks;
    bf16x8 af[4];
    {
      const float4* p0 = reinterpret_cast<const float4*>(Arow0 + k0 + ks*8);
      const float4* p1 = reinterpret_cast<const float4*>(Arow1 + k0 + ks*8);
      const float4* p2 = reinterpret_cast<const float4*>(Arow2 + k0 + ks*8);
      const float4* p3 = reinterpret_cast<const float4*>(Arow3 + k0 + ks*8);
      af[0] = cvt8(p0[0], p0[1]);
      af[1] = cvt8(p1[0], p1[1]);
      af[2] = cvt8(p2[0], p2[1]);
      af[3] = cvt8(p3[0], p3[1]);
    }
    #pragma unroll
    for (int nf=0; nf<4; ++nf){
      const int col = n0 + nf*16 + arow;
      bf16x8 bfr = *reinterpret_cast<const bf16x8*>(Bp + ((size_t)kb*Nn + col)*8);
      #pragma unroll
      for (int mf=0; mf<4; ++mf)
        acc[mf][nf] = __builtin_amdgcn_mfma_f32_16x16x32_bf16(af[mf], bfr, acc[mf][nf], 0, 0, 0);
    }
  }
  #pragma unroll
  for (int nf=0; nf<4; ++nf){
    const int n = n0 + nf*16 + arow;
    float bv  = (FLAGS & GF_BIAS)    ? bias[n]  : 0.f;
    float rbv = (FLAGS & GF_RESID_B) ? resid[n] : 0.f;
    #pragma unroll
    for (int mf=0; mf<4; ++mf){
      #pragma unroll
      for (int r=0; r<4; ++r){
        const int m = m0 + mf*16 + ks*4 + r;
        size_t idx = (size_t)m*Nn + n;
        float v = acc[mf][nf][r];
        if (FLAGS & GF_ATOMIC){ atomicAdd(&C[idx], v); }
        else {
          v += bv;
          if (FLAGS & GF_ADDC)  v += C[idx];
          if (FLAGS & GF_RELU)  v = fmaxf(v, 0.f);
          if (FLAGS & GF_RESID) v += resid[idx];
          v += rbv;
          if (FLAGS & GF_VTP){
            const int rr = m & 511, mg = m >> 9;
            ((ushort*)C)[(size_t)mg*131072 + (((rr>>3)*256 + n)<<3) + (rr&7)] = f2bu(v);
          }
          else if (FLAGS & GF_BF16) reinterpret_cast<__hip_bfloat16*>(C)[idx] = __float2bfloat16(v);
          else C[idx] = v;
        }
      }
    }
  }
}

// ---------------- batched QK^T: S[g][q][k] = Q[g*512+q][:] . K[g*512+k][:] ----------------
__global__ __launch_bounds__(256) void k_qk(const float* __restrict__ Q, const ushort* __restrict__ Kb,
                                            float* __restrict__ S){
  const int tid = threadIdx.x;
  const int wv = tid>>6, lane = tid&63;
  const int mw = wv>>1, nw = wv&1;
  const int arow = lane&15, ks = lane>>4;
  const int m0 = blockIdx.x*128 + mw*64;      // global q row in chunk
  const int n0 = blockIdx.y*128 + nw*64;      // key index 0..511
  const int g  = blockIdx.x>>2;
  const ushort* Kg = Kb + (size_t)g*131072;
  f32x4 acc[4][4] = {};
  const float* Ar0 = Q + (size_t)(m0 + 0*16 + arow)*256;
  const float* Ar1 = Q + (size_t)(m0 + 1*16 + arow)*256;
  const float* Ar2 = Q + (size_t)(m0 + 2*16 + arow)*256;
  const float* Ar3 = Q + (size_t)(m0 + 3*16 + arow)*256;
  #pragma unroll
  for (int k0 = 0; k0 < 256; k0 += 32){
    bf16x8 af[4];
    {
      const float4* p0 = reinterpret_cast<const float4*>(Ar0 + k0 + ks*8);
      const float4* p1 = reinterpret_cast<const float4*>(Ar1 + k0 + ks*8);
      const float4* p2 = reinterpret_cast<const float4*>(Ar2 + k0 + ks*8);
      const float4* p3 = reinterpret_cast<const float4*>(Ar3 + k0 + ks*8);
      af[0] = cvt8(p0[0], p0[1]);
      af[1] = cvt8(p1[0], p1[1]);
      af[2] = cvt8(p2[0], p2[1]);
      af[3] = cvt8(p3[0], p3[1]);
    }
    #pragma unroll
    for (int nf=0; nf<4; ++nf){
      const int j = n0 + nf*16 + arow;        // key row
      bf16x8 bfr = *reinterpret_cast<const bf16x8*>(Kg + (size_t)j*256 + k0 + ks*8);
      #pragma unroll
      for (int mf=0; mf<4; ++mf)
        acc[mf][nf] = __builtin_amdgcn_mfma_f32_16x16x32_bf16(af[mf], bfr, acc[mf][nf], 0, 0, 0);
    }
  }
  #pragma unroll
  for (int nf=0; nf<4; ++nf){
    const int n = n0 + nf*16 + arow;
    #pragma unroll
    for (int mf=0; mf<4; ++mf){
      #pragma unroll
      for (int r=0; r<4; ++r){
        const int m = m0 + mf*16 + ks*4 + r;
        S[(size_t)m*512 + n] = acc[mf][nf][r];
      }
    }
  }
}

// ---------------- row softmax (scale 1/16), f32 S -> normalized bf16 P ----------------
__global__ __launch_bounds__(256) void k_smrow(const float* __restrict__ S, ushort* __restrict__ P){
  const int row = blockIdx.x, tid = threadIdx.x;
  __shared__ float red[4];
  const float* sr = S + (size_t)row*512;
  float s0 = sr[tid], s1 = sr[tid+256];
  float m = fmaxf(s0, s1);
  #pragma unroll
  for (int o=1;o<64;o<<=1) m = fmaxf(m, __shfl_xor(m,o));
  if ((tid&63)==0) red[tid>>6] = m;
  __syncthreads();
  m = fmaxf(fmaxf(red[0],red[1]), fmaxf(red[2],red[3]));
  __syncthreads();
  float e0 = __expf((s0-m)*0.0625f), e1 = __expf((s1-m)*0.0625f);
  float s = e0+e1;
  #pragma unroll
  for (int o=1;o<64;o<<=1) s += __shfl_xor(s,o);
  if ((tid&63)==0) red[tid>>6] = s;
  __syncthreads();
  s = red[0]+red[1]+red[2]+red[3];
  float inv = 1.f/s;
  P[(size_t)row*512 + tid]       = f2bu(e0*inv);
  P[(size_t)row*512 + 256 + tid] = f2bu(e1*inv);
}

// ---------------- batched AV: O[g*512+q][c] = sum_k P[q][k] V[k][c] ----------------
__global__ __launch_bounds__(256) void k_av(const ushort* __restrict__ Pb, const ushort* __restrict__ VTp,
                                            float* __restrict__ O){
  const int tid = threadIdx.x;
  const int wv = tid>>6, lane = tid&63;
  const int mw = wv>>1, nw = wv&1;
  const int arow = lane&15, ks = lane>>4;
  const int m0 = blockIdx.x*128 + mw*64;
  const int n0 = blockIdx.y*128 + nw*64;      // c 0..255
  const int g  = blockIdx.x>>2;
  const ushort* Vg = VTp + (size_t)g*131072;
  f32x4 acc[4][4] = {};
  const ushort* Pr0 = Pb + (size_t)(m0 + 0*16 + arow)*512;
  const ushort* Pr1 = Pb + (size_t)(m0 + 1*16 + arow)*512;
  const ushort* Pr2 = Pb + (size_t)(m0 + 2*16 + arow)*512;
  const ushort* Pr3 = Pb + (size_t)(m0 + 3*16 + arow)*512;
  #pragma unroll 2
  for (int k0 = 0; k0 < 512; k0 += 32){
    const int kb = (k0>>3) + ks;
    bf16x8 af[4];
    af[0] = *reinterpret_cast<const bf16x8*>(Pr0 + k0 + ks*8);
    af[1] = *reinterpret_cast<const bf16x8*>(Pr1 + k0 + ks*8);
    af[2] = *reinterpret_cast<const bf16x8*>(Pr2 + k0 + ks*8);
    af[3] = *reinterpret_cast<const bf16x8*>(Pr3 + k0 + ks*8);
    #pragma unroll
    for (int nf=0; nf<4; ++nf){
      const int col = n0 + nf*16 + arow;
      bf16x8 bfr = *reinterpret_cast<const bf16x8*>(Vg + ((size_t)kb*256 + col)*8);
      #pragma unroll
      for (int mf=0; mf<4; ++mf)
        acc[mf][nf] = __builtin_amdgcn_mfma_f32_16x16x32_bf16(af[mf], bfr, acc[mf][nf], 0, 0, 0);
    }
  }
  #pragma unroll
  for (int nf=0; nf<4; ++nf){
    const int n = n0 + nf*16 + arow;
    #pragma unroll
    for (int mf=0; mf<4; ++mf){
      #pragma unroll
      for (int r=0; r<4; ++r){
        const int m = m0 + mf*16 + ks*4 + r;
        O[(size_t)m*256 + n] = acc[mf][nf][r];
      }
    }
  }
}

// ---------------- small utilities ----------------
__global__ void k_rowbias(const float* __restrict__ bias, float* __restrict__ C, int Nn, int total){
  int i = blockIdx.x*256 + threadIdx.x;
  if (i < total) C[i] = bias[i % Nn];
}
__global__ void k_qvec(const float* __restrict__ seed, const float* __restrict__ Wq,
                       const float* __restrict__ bq, float* __restrict__ qv){
  __shared__ float s[256];
  int t = threadIdx.x;
  s[t] = seed[t]; __syncthreads();
  float acc = bq[t];
  for (int c = 0; c < 256; ++c) acc += s[c] * Wq[c*256 + t];
  qv[t] = acc;
}
// wk2q[c] = sum_t Wk2[c][t]*qv[t]; wk2q[256] = bk2 . qv
__global__ __launch_bounds__(256) void k_wk2q(const float* __restrict__ Wk2, const float* __restrict__ bk2,
                      const float* __restrict__ qv, float* __restrict__ outv){
  __shared__ float qs[256];
  __shared__ float red[4];
  int t = threadIdx.x;
  qs[t] = qv[t]; __syncthreads();
  float a = 0.f;
  for (int c=0;c<256;c+=4){
    float4 w = *reinterpret_cast<const float4*>(Wk2 + t*256 + c);
    a += w.x*qs[c] + w.y*qs[c+1] + w.z*qs[c+2] + w.w*qs[c+3];
  }
  outv[t] = a;
  float bb = bk2[t]*qs[t];
  #pragma unroll
  for (int o=1;o<64;o<<=1) bb += __shfl_xor(bb,o);
  if ((t&63)==0) red[t>>6] = bb;
  __syncthreads();
  if (t==0) outv[256] = red[0]+red[1]+red[2]+red[3];
}
// fused PMA: logits = (kk @ wk2q + b2q)/16; alpha = softmax; wsum = sum_j alpha_j kk[j]
__global__ __launch_bounds__(256) void k_pmafuse(const float* __restrict__ kk, const float* __restrict__ wkq,
                        float* __restrict__ wsum){
  int g = blockIdx.x, tid = threadIdx.x;
  __shared__ float qs[256];
  __shared__ float sc[512];
  __shared__ float red[4];
  qs[tid] = wkq[tid];
  __syncthreads();
  const float b2q = wkq[256];
  const float* kg = kk + (size_t)g*512*256;
  float l0=0.f, l1=0.f;
  for (int j0=0;j0<2;++j0){
    int j = tid + j0*256;
    const float* kr = kg + (size_t)j*256;
    float a = 0.f;
    for (int c=0;c<256;c+=4){
      float4 k4 = *reinterpret_cast<const float4*>(kr + c);
      a += k4.x*qs[c] + k4.y*qs[c+1] + k4.z*qs[c+2] + k4.w*qs[c+3];
    }
    a = (a + b2q)*0.0625f;
    if (j0) l1=a; else l0=a;
  }
  float m = fmaxf(l0,l1);
  #pragma unroll
  for (int o=1;o<64;o<<=1) m = fmaxf(m, __shfl_xor(m,o));
  if ((tid&63)==0) red[tid>>6] = m;
  __syncthreads();
  m = fmaxf(fmaxf(red[0],red[1]), fmaxf(red[2],red[3]));
  __syncthreads();
  float e0 = __expf(l0-m), e1 = __expf(l1-m);
  sc[tid]=e0; sc[tid+256]=e1;
  float s = e0+e1;
  #pragma unroll
  for (int o=1;o<64;o<<=1) s += __shfl_xor(s,o);
  if ((tid&63)==0) red[tid>>6] = s;
  __syncthreads();
  s = red[0]+red[1]+red[2]+red[3];
  float invs = 1.f/s;
  float acc = 0.f;
  for (int j=0;j<512;++j) acc += sc[j] * kg[(size_t)j*256 + tid];
  wsum[(size_t)g*256+tid] = acc*invs;
}
__global__ void k_concat(const float* __restrict__ p1, const float* __restrict__ p2,
                         const float* __restrict__ p3, float* __restrict__ pooled){
  int idx = blockIdx.x*256 + threadIdx.x;
  int b = idx / 768, j = idx % 768;
  float v = (j < 256) ? p1[b*256+j] : (j < 512) ? p2[b*256+j-256] : p3[b*256+j-512];
  pooled[idx] = v;
}

// ---------------- GRU v11: i8 Whh REGISTER-RESIDENT (96 VGPR/lane, asm-pinned) ----------
// 1 graph/block, 256 blocks, 512 thr (8 waves), launch_bounds(512,1) -> 256-VGPR budget.
// wave wv owns cols [wv*96,+96): 48 longs of i8 weights loaded ONCE.
// gi windowed in LDS via bf16 MFMA (unchanged from v10).
__global__ __launch_bounds__(512,1) void k_gru11(const float* __restrict__ X,
                      const ushort* __restrict__ pIh, const char* __restrict__ pHh8,
                      const float* __restrict__ csg, const float* __restrict__ bc,
                      float* __restrict__ p2){
  extern __shared__ char gsm[];
  float*  GIw  = (float*)gsm;                   // [32][768]  98304 B
  float*  gh   = (float*)(gsm + 98304);         // [768]      3072 B
  float*  bcl  = (float*)(gsm + 101376);        // [1024]     4096 B
  float*  csl  = (float*)(gsm + 105472);        // [768]      3072 B
  char*   hbf8 = (char*) (gsm + 108544);        // [256]      256 B
  const int g = blockIdx.x;
  const int tid = threadIdx.x;
  const int wv = tid>>6, lane = tid&63;
  const int arow = lane&15, ks = lane>>4;
  // ---- load Whh i8 fragments ONCE: 48 longs = 96 VGPRs, pinned ----
  long whh8[48];
  #pragma unroll
  for (int kt=0;kt<8;++kt)
    #pragma unroll
    for (int nt=0;nt<6;++nt)
      whh8[kt*6+nt] = *reinterpret_cast<const long*>(pHh8 + ((size_t)(kt*4+ks)*768 + wv*96+nt*16+arow)*8);
  #pragma unroll
  for (int i=0;i<48;++i)
    asm volatile("" : "+v"(whh8[i]));           // opaque: forbid remat/re-load
  for (int i=tid;i<1024;i+=512) bcl[i] = bc[i];
  for (int i=tid;i<768;i+=512)  csl[i] = csg[i];
  if (tid < 256) hbf8[tid] = 0;
  float h_reg = 0.f;
  const float* Xg = X + (size_t)g*512*256;
  __syncthreads();
  for (int w=0; w<16; ++w){
    const int t0 = w*32;
    // ---- window GEMM: GIw[32][768] = X[t0..+32][256] @ Wih (bf16, per-wave 96-col stripe) ----
    #pragma unroll
    for (int mt=0; mt<2; ++mt){
      const float* xr = Xg + (size_t)(t0 + mt*16 + arow)*256;
      f32x4 acc[6] = {};
      #pragma unroll
      for (int kt=0; kt<8; ++kt){
        const float4* xp = reinterpret_cast<const float4*>(xr + kt*32 + ks*8);
        bf16x8 af = cvt8(xp[0], xp[1]);
        #pragma unroll
        for (int nt=0; nt<6; ++nt){
          bf16x8 bfr = *reinterpret_cast<const bf16x8*>(pIh + ((size_t)(kt*4+ks)*768 + wv*96+nt*16+arow)*8);
          acc[nt] = __builtin_amdgcn_mfma_f32_16x16x32_bf16(af, bfr, acc[nt], 0,0,0);
        }
      }
      #pragma unroll
      for (int nt=0; nt<6; ++nt){
        const int col = wv*96 + nt*16 + arow;
        #pragma unroll
        for (int r=0;r<4;++r)
          GIw[(size_t)(mt*16 + ks*4 + r)*768 + col] = acc[nt][r];
      }
    }
    for (int dt=0; dt<32; ++dt){
      // gh_i32 = h8 @ Whh8 : weights from REGISTERS; A row0 = h8 (rows 1..15 zero)
      i32x4 sacc[6] = {};
      #pragma unroll
      for (int kt=0; kt<8; ++kt){
        long a8 = 0;
        if (arow == 0) a8 = *reinterpret_cast<const long*>(hbf8 + kt*32 + ks*8);
        #pragma unroll
        for (int nt=0; nt<6; ++nt)
          sacc[nt] = __builtin_amdgcn_mfma_i32_16x16x32_i8(a8, whh8[kt*6+nt], sacc[nt], 0,0,0);
      }
      if (ks == 0){     // D row0 lives in reg 0 of lanes 0..15
        #pragma unroll
        for (int nt=0; nt<6; ++nt){
          const int col = wv*96 + nt*16 + arow;
          gh[col] = (float)sacc[nt][0] * csl[col];
        }
      }
      __syncthreads();   // gh + GIw ready; hbf8 reads done
      if (tid < 256){
        const int c = tid;
        const float* gir = GIw + (size_t)dt*768;
        float rr = sigm(gir[c]     + gh[c]     + bcl[c]);
        float zz = sigm(gir[256+c] + gh[256+c] + bcl[256+c]);
        float nx = gir[512+c] + bcl[512+c] + rr*(gh[512+c] + bcl[768+c]);
        nx = fminf(fmaxf(nx, -15.f), 15.f);
        float e2 = __expf(2.f*nx);
        float nn = (e2-1.f)*__builtin_amdgcn_rcpf(e2+1.f);
        h_reg = (1.f-zz)*nn + zz*h_reg;
        int q = (int)lrintf(h_reg*127.f);
        q = max(-127, min(127, q));
        hbf8[c] = (char)q;
      }
      __syncthreads();   // hbf8 ready for next step
    }
  }
  if (tid < 256) p2[(size_t)g*256 + tid] = h_reg;
}

// =====================================================================
extern "C" void kernel_launch(void* const* d_in, const int* in_sizes, int n_in,
                              void* d_out, int out_size, void* d_ws, size_t ws_size,
                              hipStream_t stream){
  const int*   x      = (const int*)  d_in[0];
  const int*   ei     = (const int*)  d_in[1];
  const float* emb_w  = (const float*)d_in[3];
  const float* c1_lW  = (const float*)d_in[4];
  const float* c1_lb  = (const float*)d_in[5];
  const float* c1_rW  = (const float*)d_in[6];
  const float* t1     = (const float*)d_in[7];
  const float* c2_lW  = (const float*)d_in[8];
  const float* c2_lb  = (const float*)d_in[9];
  const float* c2_rW  = (const float*)d_in[10];
  const float* t2     = (const float*)d_in[11];
  const float* mlp_W  = (const float*)d_in[12];
  const float* mlp_b  = (const float*)d_in[13];
  const float* gWih   = (const float*)d_in[14];
  const float* gWhh   = (const float*)d_in[15];
  const float* gbih   = (const float*)d_in[16];
  const float* gbhh   = (const float*)d_in[17];
  const float* stWq   = (const float*)d_in[18];
  const float* stbq   = (const float*)d_in[19];
  const float* stWk   = (const float*)d_in[20];
  const float* stbk   = (const float*)d_in[21];
  const float* stWv   = (const float*)d_in[22];
  const float* stbv   = (const float*)d_in[23];
  const float* stWo   = (const float*)d_in[24];
  const float* stbo   = (const float*)d_in[25];
  const float* stlW   = (const float*)d_in[26];
  const float* stlb   = (const float*)d_in[27];
  const float* pma_lW = (const float*)d_in[28];
  const float* pma_lb = (const float*)d_in[29];
  const float* seed   = (const float*)d_in[30];
  const float* fin_W  = (const float*)d_in[31];
  const float* fin_b  = (const float*)d_in[32];
  float* out = (float*)d_out;

  // ---- choose chunk size by available workspace ----
  auto needFor = [](int CHe)->size_t{
    size_t bufN = (size_t)CHe*512*512;
    size_t floats = (size_t)33554432 + 3*bufN + 2*524288 + 2*196608 + 8*65536 + 196608 + 320 + 512;
    size_t ints   = 131072 + 131200 + 131072 + 262144 + 128 + 128;
    return floats*4 + ints*4 + 4096;
  };
  const int CHe = (ws_size >= needFor(64)) ? 64 : 32;
  if (ws_size < needFor(32)) return;
  const int NCHUNKe = BG / CHe;
  const int NCNe = CHe * 512;
  const size_t bufN = (size_t)CHe*512*512;

  // ---- workspace carve ----
  float* H2   = (float*)d_ws;                    // NN*256 f32 (persists)
  float* bufA = H2   + (size_t)33554432;
  float* bufB = bufA + bufN;
  float* bufC = bufB + bufN;
  float* h0   = bufC + bufN;                     // NN*4
  float* ag1  = h0   + (size_t)524288;           // NN*4
  float* wT1  = ag1  + (size_t)524288;           // GRU packs (pIh / pHh8+cs)
  float* wT2  = wT1  + (size_t)196608;           // pC2 + bcomb
  float* p1   = wT2  + (size_t)196608;
  float* p2   = p1   + (size_t)65536;
  float* p3   = p2   + (size_t)65536;
  float* av2  = p3   + (size_t)65536;            // (= PMA wsum)
  float* s1   = av2  + (size_t)65536;
  float* s2v  = s1   + (size_t)65536;
  float* v3   = s2v  + (size_t)65536;
  float* h3   = v3   + (size_t)65536;
  float* pooled = h3 + (size_t)65536;
  float* qv   = pooled + (size_t)196608;
  int*   deg  = (int*)(qv + 320);
  int*   offs = deg  + 131072;
  int*   cur  = offs + 131200;
  int*   esrc = cur  + 131072;
  int*   bsum = esrc + 262144;
  int*   boff = bsum + 128;
  float* wkq  = (float*)(boff + 128);            // 512 floats (wk2q[256] + b2q)

  ushort* pIh  = (ushort*)wT1;                   // 196608 ush = 98304 f
  char*   pHh8 = (char*)(wT1 + 98304);           // 196608 B = 49152 f
  float*  csHh = wT1 + 98304 + 49152;            // 768 f
  ushort* pC2  = (ushort*)wT2;
  float*  bcomb= wT2 + 65536;
  float*  pa   = h0;                             // dead after conv -> ST packs
  ushort* pQ0  = (ushort*)(pa);
  ushort* pK0  = (ushort*)(pa + 32768);
  ushort* pV0  = (ushort*)(pa + 65536);
  ushort* pO0  = (ushort*)(pa + 98304);
  ushort* pL0  = (ushort*)(pa + 131072);
  ushort* pPma = (ushort*)(pa + 163840);
  ushort* pV1  = (ushort*)(pa + 229376);
  ushort* pO1  = (ushort*)(pa + 262144);
  ushort* pL1  = (ushort*)(pa + 294912);
  ushort* pV2  = (ushort*)(pa + 327680);
  ushort* pO2  = (ushort*)(pa + 360448);
  ushort* pL2  = (ushort*)(pa + 393216);
  ushort* pFin = (ushort*)(pa + 425984);

  // attention sub-buffers (inside bufA/bufB)
  ushort* VTp = (ushort*)(bufA + bufN/2);
  ushort* Kbf = (ushort*)bufB;
  ushort* Pbf = (ushort*)(bufB + bufN/4);

  const int ls0 = 65536, ls1 = 256;

  // ---- 1. node encoder ----
  k_node_enc<<<NN/256, 256, 0, stream>>>(x, emb_w, h0);

  // ---- 2. CSR ----
  k_zero<<<NN/256, 256, 0, stream>>>(deg, NN);
  k_count<<<NE/256, 256, 0, stream>>>(ei, deg);
  k_blocksum<<<128, 256, 0, stream>>>(deg, bsum);
  k_scanbsum<<<1, 128, 0, stream>>>(bsum, boff, offs + NN);
  k_scanchunk<<<128, 256, 0, stream>>>(deg, boff, offs);
  k_zero<<<NN/256, 256, 0, stream>>>(cur, NN);
  k_fill<<<NE/256, 256, 0, stream>>>(ei, offs, cur, esrc);

  // ---- 3. conv1 aggregation + early packs ----
  k_aggr4<<<NN/256, 256, 0, stream>>>(h0, offs, esrc, t1, ag1);
  k_packb <<<256, 256, 0, stream>>>(c2_rW, pC2, 256, 256);
  k_packb <<<256, 256, 0, stream>>>(c2_lW, pC2 + 65536, 256, 256);
  k_packbT<<<768, 256, 0, stream>>>(gWih, pIh, 256, 768);
  k_packhh8<<<768, 256, 0, stream>>>(gWhh, pHh8, csHh);
  k_packbias<<<4, 256, 0, stream>>>(gbih, gbhh, bcomb);

  // ---- 4. conv1 + conv2 (fused K=512), chunked ----
  for (int cg = 0; cg < NCHUNKe; ++cg){
    const int base = cg * NCNe;
    float* Hc = H2 + (size_t)base * 256;
    const dim3 gg(NCNe/128, 2, 1);
    k_conv1_lin<<<NCNe, 256, 0, stream>>>(ag1, h0, c1_lW, c1_lb, c1_rW, bufA, base);
    k_aggr256<<<NCNe, 256, 0, stream>>>(bufA, offs, esrc, t2, base);
    k_bgemm<GF_BIAS|GF_RELU><<<gg, 256, 0, stream>>>(bufA, pC2, c2_lb, nullptr, Hc, NCNe, 256, 512, 512);
  }
  // H2 = h2 (full)

  // ---- 5. p1 = MLP pool via MFMA (pack mlp_W bf16 into free bufB; split-K atomic) ----
  k_packb<<<131072, 256, 0, stream>>>(mlp_W, (ushort*)bufB, 131072, 256);
  k_rowbias<<<256, 256, 0, stream>>>(mlp_b, p1, 256, 65536);
  k_bgemm<GF_ATOMIC><<<dim3(2, 2, 64), 256, 0, stream>>>(H2, (ushort*)bufB, nullptr, nullptr, p1, 256, 256, NN, 131072);

  // ---- 6. GRU v11 (register-resident i8 Whh; 256 blocks, 8 waves) ----
  k_gru11<<<BG, 512, 108800, stream>>>(H2, pIh, pHh8, csHh, bcomb, p2);

  // ---- 7. ST packs + set transformer (MFMA attention + fused PMA), chunked ----
  k_packb<<<256, 256, 0, stream>>>(stWq,        pQ0, 256, 256);
  k_packb<<<256, 256, 0, stream>>>(stWk,        pK0, 256, 256);
  k_packb<<<256, 256, 0, stream>>>(stWv,        pV0, 256, 256);
  k_packb<<<256, 256, 0, stream>>>(stWo,        pO0, 256, 256);
  k_packb<<<256, 256, 0, stream>>>(stlW,        pL0, 256, 256);
  k_packb<<<256, 256, 0, stream>>>(pma_lW,      pPma,256, 256);
  k_packb<<<256, 256, 0, stream>>>(stWv + ls0,  pV1, 256, 256);
  k_packb<<<256, 256, 0, stream>>>(stWo + ls0,  pO1, 256, 256);
  k_packb<<<256, 256, 0, stream>>>(stlW + ls0,  pL1, 256, 256);
  k_packb<<<256, 256, 0, stream>>>(stWv + 2*ls0,pV2, 256, 256);
  k_packb<<<256, 256, 0, stream>>>(stWo + 2*ls0,pO2, 256, 256);
  k_packb<<<256, 256, 0, stream>>>(stlW + 2*ls0,pL2, 256, 256);
  k_packb<<<2304, 256, 0, stream>>>(fin_W,      pFin,768, 768);
  k_qvec<<<1, 256, 0, stream>>>(seed, stWq + ls0, stbq + ls1, qv);
  k_wk2q<<<1, 256, 0, stream>>>(stWk + ls0, stbk + ls1, qv, wkq);

  for (int cg = 0; cg < NCHUNKe; ++cg){
    const int base = cg * NCNe;
    float* Hc = H2 + (size_t)base * 256;
    const dim3 gg(NCNe/128, 2, 1);
    k_bgemm<GF_BIAS><<<gg, 256, 0, stream>>>(Hc, pQ0, stbq, nullptr, bufA, NCNe, 256, 256, 256);           // Q f32
    k_bgemm<GF_BIAS|GF_BF16><<<gg, 256, 0, stream>>>(Hc, pK0, stbk, nullptr, (float*)Kbf, NCNe, 256, 256, 256); // K bf16
    k_bgemm<GF_BIAS|GF_VTP><<<gg, 256, 0, stream>>>(Hc, pV0, stbv, nullptr, (float*)VTp, NCNe, 256, 256, 256);  // V packed
    k_qk<<<dim3(NCNe/128, 4), 256, 0, stream>>>(bufA, Kbf, bufC);                                          // S f32
    k_smrow<<<NCNe, 256, 0, stream>>>(bufC, Pbf);                                                          // P bf16
    k_av<<<dim3(NCNe/128, 2), 256, 0, stream>>>(Pbf, VTp, bufA);                                           // O -> bufA
    k_bgemm<GF_BIAS|GF_RESID><<<gg, 256, 0, stream>>>(bufA, pO0, stbo, Hc, Hc, NCNe, 256, 256, 256);       // h_sab in-place
    k_bgemm<GF_BIAS|GF_RELU|GF_RESID><<<gg, 256, 0, stream>>>(Hc, pL0, stlb, Hc, bufA, NCNe, 256, 256, 256); // h_enc
    k_bgemm<GF_BIAS|GF_RELU><<<gg, 256, 0, stream>>>(bufA, pPma, pma_lb, nullptr, bufB, NCNe, 256, 256, 256); // kk
    k_pmafuse<<<CHe, 256, 0, stream>>>(bufB, wkq, av2 + (size_t)cg*CHe*256);                               // wsum
  }

  // ---- 8. PMA tail + decoder SAB ----
  k_bgemm<GF_BIAS><<<dim3(2, 2, 1), 256, 0, stream>>>(av2, pV1, stbv + ls1, nullptr, v3, 256, 256, 256, 256);   // true av2
  k_bgemm<GF_BIAS|GF_RESID_B><<<dim3(2, 2, 1), 256, 0, stream>>>(v3, pO1, stbo + ls1, seed, s1, 256, 256, 256, 256);
  k_bgemm<GF_BIAS|GF_RELU|GF_RESID><<<dim3(2, 2, 1), 256, 0, stream>>>(s1, pL1, stlb + ls1, s1, s2v, 256, 256, 256, 256);
  k_bgemm<GF_BIAS><<<dim3(2, 2, 1), 256, 0, stream>>>(s2v, pV2, stbv + 2*ls1, nullptr, v3, 256, 256, 256, 256);
  k_bgemm<GF_BIAS|GF_RESID><<<dim3(2, 2, 1), 256, 0, stream>>>(v3, pO2, stbo + 2*ls1, s2v, h3, 256, 256, 256, 256);
  k_bgemm<GF_BIAS|GF_RELU|GF_RESID><<<dim3(2, 2, 1), 256, 0, stream>>>(h3, pL2, stlb + 2*ls1, h3, p3, 256, 256, 256, 256);

  // ---- 9. concat + final linear ----
  k_concat<<<768, 256, 0, stream>>>(p1, p2, p3, pooled);
  k_bgemm<GF_BIAS><<<dim3(2, 6, 1), 256, 0, stream>>>(pooled, pFin, fin_b, nullptr, out, 256, 768, 768, 768);
}

// Round 13
// 2732.147 us; speedup vs baseline: 4.5382x; 1.1512x over previous
//
#include <hip/hip_runtime.h>
#include <hip/hip_bf16.h>
#include <math.h>

// ---- problem constants ----
constexpr int NN   = 131072;   // total nodes (B*NPG)
constexpr int NE   = 262144;   // edges
constexpr int BG   = 256;      // graphs

typedef __bf16 bf16x8 __attribute__((ext_vector_type(8)));
typedef float  f32x4  __attribute__((ext_vector_type(4)));
typedef int    i32x4  __attribute__((ext_vector_type(4)));

__device__ inline float sigm(float x){ return 1.f/(1.f+__expf(-x)); }
__device__ inline float blo(unsigned u){ union{unsigned a;float f;}v; v.a=u<<16; return v.f; }
__device__ inline float bhi(unsigned u){ union{unsigned a;float f;}v; v.a=u&0xffff0000u; return v.f; }
__device__ inline float b2f(ushort u){ union{unsigned a;float f;}v; v.a=((unsigned)u)<<16; return v.f; }
__device__ inline unsigned short f2bu(float f){
  union{float f;unsigned u;}v; v.f=f;
  unsigned u = v.u + 0x7fffu + ((v.u>>16)&1u);
  return (unsigned short)(u>>16);
}
__device__ inline bf16x8 cvt8(float4 a, float4 b){
  union { ushort u[8]; bf16x8 v; } r;
  r.u[0]=f2bu(a.x); r.u[1]=f2bu(a.y); r.u[2]=f2bu(a.z); r.u[3]=f2bu(a.w);
  r.u[4]=f2bu(b.x); r.u[5]=f2bu(b.y); r.u[6]=f2bu(b.z); r.u[7]=f2bu(b.w);
  return r.v;
}

__global__ void k_zero(int* __restrict__ p, int n){
  int i = blockIdx.x*256 + threadIdx.x;
  if (i < n) p[i] = 0;
}

// ---------------- node encoder ----------------
__global__ void k_node_enc(const int* __restrict__ x, const float* __restrict__ emb,
                           float* __restrict__ h0){
  int n = blockIdx.x*256 + threadIdx.x;
  if (n >= NN) return;
  int nt = x[2*n], ninv = x[2*n+1];
  float4 v; v.x = emb[nt*3+0]; v.y = emb[nt*3+1]; v.z = emb[nt*3+2]; v.w = (float)ninv;
  reinterpret_cast<float4*>(h0)[n] = v;
}

// ---------------- CSR build (by dst) ----------------
__global__ void k_count(const int* __restrict__ ei, int* __restrict__ deg){
  int e = blockIdx.x*256 + threadIdx.x;
  if (e >= NE) return;
  atomicAdd(&deg[ei[NE + e]], 1);
}
__global__ void k_blocksum(const int* __restrict__ deg, int* __restrict__ bsum){
  __shared__ int sd[256];
  int t = threadIdx.x;
  const int* p = deg + blockIdx.x*1024;
  int s = p[t*4] + p[t*4+1] + p[t*4+2] + p[t*4+3];
  sd[t]=s; __syncthreads();
  for (int d=128; d>0; d>>=1){ if (t<d) sd[t]+=sd[t+d]; __syncthreads(); }
  if (!t) bsum[blockIdx.x] = sd[0];
}
__global__ void k_scanbsum(const int* __restrict__ bsum, int* __restrict__ boff, int* __restrict__ offN){
  __shared__ int s[128];
  int t = threadIdx.x;
  int mine = bsum[t];
  s[t]=mine; __syncthreads();
  for (int d=1; d<128; d<<=1){ int v = (t>=d)? s[t-d]:0; __syncthreads(); s[t]+=v; __syncthreads(); }
  boff[t] = s[t]-mine;
  if (t==127) offN[0] = s[127];
}
__global__ void k_scanchunk(const int* __restrict__ deg, const int* __restrict__ boff, int* __restrict__ offs){
  __shared__ int ts[256];
  int t = threadIdx.x, b = blockIdx.x;
  const int* p = deg + b*1024;
  int v0=p[t*4],v1=p[t*4+1],v2=p[t*4+2],v3=p[t*4+3];
  int mysum=v0+v1+v2+v3;
  ts[t]=mysum; __syncthreads();
  for (int d=1; d<256; d<<=1){ int v=(t>=d)?ts[t-d]:0; __syncthreads(); ts[t]+=v; __syncthreads(); }
  int ex = ts[t]-mysum + boff[b];
  int* o = offs + b*1024 + t*4;
  o[0]=ex; o[1]=ex+v0; o[2]=ex+v0+v1; o[3]=ex+v0+v1+v2;
}
__global__ void k_fill(const int* __restrict__ ei, const int* __restrict__ offs,
                       int* __restrict__ cur, int* __restrict__ esrc){
  int e = blockIdx.x*256 + threadIdx.x;
  if (e >= NE) return;
  int dst = ei[NE+e];
  int pos = offs[dst] + atomicAdd(&cur[dst],1);
  esrc[pos] = ei[e];
}

// ---------------- softmax aggregation, 4-channel (conv1), no-max (exact) ----------------
__global__ void k_aggr4(const float* __restrict__ h, const int* __restrict__ offs,
                        const int* __restrict__ esrc, const float* __restrict__ tptr,
                        float* __restrict__ ag){
  int n = blockIdx.x*256 + threadIdx.x;
  if (n >= NN) return;
  int s = offs[n], e = offs[n+1];
  float4 z = {0,0,0,0};
  if (s == e){ reinterpret_cast<float4*>(ag)[n] = z; return; }
  float t = *tptr;
  float4 num=z, den=z;
  for (int i=s;i<e;++i){
    float4 v = reinterpret_cast<const float4*>(h)[esrc[i]];
    float ex;
    ex=__expf(v.x*t); num.x+=v.x*ex; den.x+=ex;
    ex=__expf(v.y*t); num.y+=v.y*ex; den.y+=ex;
    ex=__expf(v.z*t); num.z+=v.z*ex; den.z+=ex;
    ex=__expf(v.w*t); num.w+=v.w*ex; den.w+=ex;
  }
  float4 r = {num.x/den.x, num.y/den.y, num.z/den.z, num.w/den.w};
  reinterpret_cast<float4*>(ag)[n] = r;
}

// ---------------- softmax aggregation (no-max, 1 pass), fused [h1|ag] layout ----------------
__global__ __launch_bounds__(256) void k_aggr256(float* __restrict__ buf, const int* __restrict__ offs,
                          const int* __restrict__ esrc, const float* __restrict__ tptr, int base){
  int n = base + blockIdx.x, c = threadIdx.x;
  int s = offs[n], e = offs[n+1];
  float* outp = buf + (size_t)blockIdx.x*512 + 256 + c;
  if (s == e){ *outp = 0.f; return; }
  float t = *tptr;
  float num=0.f, den=0.f;
  for (int i=s;i<e;++i){
    float v = buf[(size_t)(esrc[i]-base)*512 + c];
    float ex = __expf(v*t);
    num += v*ex; den += ex;
  }
  *outp = num/den;
}

// ---------------- conv1 linear (K=4, fused), writes [n][512] col 0..255 ----------------
__global__ __launch_bounds__(256) void k_conv1_lin(const float* __restrict__ ag, const float* __restrict__ h0,
                            const float* __restrict__ lW, const float* __restrict__ lb,
                            const float* __restrict__ rW, float* __restrict__ out, int base){
  int n = base + blockIdx.x, c = threadIdx.x;
  float4 a  = reinterpret_cast<const float4*>(ag)[n];
  float4 xv = reinterpret_cast<const float4*>(h0)[n];
  float acc = lb[c];
  acc += a.x*lW[c]  + a.y*lW[256+c]  + a.z*lW[512+c]  + a.w*lW[768+c];
  acc += xv.x*rW[c] + xv.y*rW[256+c] + xv.z*rW[512+c] + xv.w*rW[768+c];
  out[(size_t)blockIdx.x*512 + c] = fmaxf(acc, 0.f);
}

// ---------------- flags ----------------
#define GF_BIAS    1
#define GF_RELU    2
#define GF_RESID   4
#define GF_RESID_B 8
#define GF_ADDC    32
#define GF_ATOMIC  64
#define GF_BF16    128
#define GF_VTP     256   // write output as per-graph B-pack (for AV's V operand)
#define GF_RESID16 512   // residual read as bf16

// ---------------- weight pack: f32 W[K][N] -> MFMA-B bf16 Bp[((k>>3)*N + j)*8 + (k&7)] ----
__global__ void k_packb(const float* __restrict__ W, ushort* __restrict__ Bp, int K, int N){
  int idx = blockIdx.x*256 + threadIdx.x;
  if (idx >= K*N) return;
  int k = idx / N, j = idx - k*N;
  Bp[((size_t)(k>>3)*N + j)*8 + (k&7)] = f2bu(W[idx]);
}
// transposed source: W is [N][K] row-major; B[k][j] = W[j][k]
__global__ void k_packbT(const float* __restrict__ W, ushort* __restrict__ Bp, int K, int N){
  int idx = blockIdx.x*256 + threadIdx.x;
  if (idx >= K*N) return;
  int j = idx / K, k = idx - j*K;
  Bp[((size_t)(k>>3)*N + j)*8 + (k&7)] = f2bu(W[idx]);
}
// Whh -> i8 B-pack with per-column scales
__global__ __launch_bounds__(256) void k_packhh8(const float* __restrict__ gWhh,
                        char* __restrict__ Bp8, float* __restrict__ cs){
  int j = blockIdx.x, k = threadIdx.x;
  float w = gWhh[(size_t)j*256 + k];
  __shared__ float red[256];
  red[k] = fabsf(w); __syncthreads();
  for (int d=128; d>0; d>>=1){ if (k<d) red[k]=fmaxf(red[k],red[k+d]); __syncthreads(); }
  float mx = fmaxf(red[0], 1e-20f);
  int q = (int)lrintf(w * (127.f/mx));
  q = max(-127, min(127, q));
  Bp8[((size_t)(k>>3)*768 + j)*8 + (k&7)] = (char)q;
  if (k==0) cs[j] = mx/(127.f*127.f);
}
// combined GRU biases
__global__ void k_packbias(const float* __restrict__ gbih, const float* __restrict__ gbhh,
                           float* __restrict__ bc){
  int i = blockIdx.x*256 + threadIdx.x;
  if (i >= 1024) return;
  int c = i & 255;
  float v;
  if (i < 256)      v = gbih[c] + gbhh[c];
  else if (i < 512) v = gbih[256+c] + gbhh[256+c];
  else if (i < 768) v = gbih[512+c];
  else              v = gbhh[512+c];
  bc[i] = v;
}

// ---------------- old f32 MFMA GEMM (tail only) ----------------
template<int FLAGS>
__global__ __launch_bounds__(256) void k_bgemm(const float* __restrict__ A, const ushort* __restrict__ Bp,
                       const float* __restrict__ bias, const float* __restrict__ resid,
                       float* __restrict__ C, int M, int Nn, int K, int lda){
  const int tid = threadIdx.x;
  const int wv = tid>>6, lane = tid&63;
  const int mw = wv>>1, nw = wv&1;
  const int arow = lane&15, ks = lane>>4;
  const int m0 = blockIdx.x*128 + mw*64, n0 = blockIdx.y*128 + nw*64;
  f32x4 acc[4][4] = {};
  #pragma unroll 2
  for (int k0 = 0; k0 < K; k0 += 32){
    const int kb = (k0>>3) + ks;
    bf16x8 af[4];
    #pragma unroll
    for (int mf=0; mf<4; ++mf){
      const float4* p = reinterpret_cast<const float4*>(A + (size_t)(m0+mf*16+arow)*lda + k0 + ks*8);
      af[mf] = cvt8(p[0], p[1]);
    }
    #pragma unroll
    for (int nf=0; nf<4; ++nf){
      const int col = n0 + nf*16 + arow;
      bf16x8 bfr = *reinterpret_cast<const bf16x8*>(Bp + ((size_t)kb*Nn + col)*8);
      #pragma unroll
      for (int mf=0; mf<4; ++mf)
        acc[mf][nf] = __builtin_amdgcn_mfma_f32_16x16x32_bf16(af[mf], bfr, acc[mf][nf], 0, 0, 0);
    }
  }
  #pragma unroll
  for (int nf=0; nf<4; ++nf){
    const int n = n0 + nf*16 + arow;
    float bv  = (FLAGS & GF_BIAS)    ? bias[n]  : 0.f;
    float rbv = (FLAGS & GF_RESID_B) ? resid[n] : 0.f;
    #pragma unroll
    for (int mf=0; mf<4; ++mf){
      #pragma unroll
      for (int r=0; r<4; ++r){
        const int m = m0 + mf*16 + ks*4 + r;
        size_t idx = (size_t)m*Nn + n;
        float v = acc[mf][nf][r];
        v += bv;
        if (FLAGS & GF_RELU)  v = fmaxf(v, 0.f);
        if (FLAGS & GF_RESID) v += resid[idx];
        v += rbv;
        C[idx] = v;
      }
    }
  }
}

// ---------------- bgemm2: 128x256 tile per block (A read once), N fixed = 256 -----------
// ABF: A is bf16 (direct fragment loads). FLAGS epilogues as before + GF_RESID16.
template<int FLAGS, bool ABF>
__global__ __launch_bounds__(256) void k_bgemm2(const void* __restrict__ Av, const ushort* __restrict__ Bp,
                       const float* __restrict__ bias, const void* __restrict__ residv,
                       void* __restrict__ Cv, int K, int lda){
  const int tid = threadIdx.x;
  const int wv = tid>>6, lane = tid&63;
  const int mw = wv&1, nw = wv>>1;
  const int arow = lane&15, ks = lane>>4;
  const int m0 = blockIdx.x*128 + mw*64;
  const int n0 = nw*128;
  const int kChunk = K / gridDim.z, kBeg = blockIdx.z * kChunk;
  f32x4 acc[4][8] = {};
  #pragma unroll 1
  for (int k0 = kBeg; k0 < kBeg+kChunk; k0 += 32){
    const int kb = (k0>>3) + ks;
    bf16x8 af[4];
    if (ABF){
      const ushort* A = (const ushort*)Av;
      #pragma unroll
      for (int mf=0; mf<4; ++mf)
        af[mf] = *reinterpret_cast<const bf16x8*>(A + (size_t)(m0+mf*16+arow)*lda + k0 + ks*8);
    } else {
      const float* A = (const float*)Av;
      #pragma unroll
      for (int mf=0; mf<4; ++mf){
        const float4* p = reinterpret_cast<const float4*>(A + (size_t)(m0+mf*16+arow)*lda + k0 + ks*8);
        af[mf] = cvt8(p[0], p[1]);
      }
    }
    #pragma unroll
    for (int nf=0; nf<8; ++nf){
      const int col = n0 + nf*16 + arow;
      bf16x8 bfr = *reinterpret_cast<const bf16x8*>(Bp + ((size_t)kb*256 + col)*8);
      #pragma unroll
      for (int mf=0; mf<4; ++mf)
        acc[mf][nf] = __builtin_amdgcn_mfma_f32_16x16x32_bf16(af[mf], bfr, acc[mf][nf], 0, 0, 0);
    }
  }
  #pragma unroll
  for (int nf=0; nf<8; ++nf){
    const int n = n0 + nf*16 + arow;
    float bv = (FLAGS & GF_BIAS) ? bias[n] : 0.f;
    #pragma unroll
    for (int mf=0; mf<4; ++mf){
      #pragma unroll
      for (int r=0; r<4; ++r){
        const int m = m0 + mf*16 + ks*4 + r;
        size_t idx = (size_t)m*256 + n;
        float v = acc[mf][nf][r];
        if (FLAGS & GF_ATOMIC){ atomicAdd((float*)Cv + idx, v); }
        else {
          v += bv;
          if (FLAGS & GF_RELU) v = fmaxf(v, 0.f);
          if (FLAGS & GF_RESID16) v += b2f(((const ushort*)residv)[idx]);
          if (FLAGS & GF_VTP){
            const int rr = m & 511, mg = m >> 9;
            ((ushort*)Cv)[(size_t)mg*131072 + (((rr>>3)*256 + n)<<3) + (rr&7)] = f2bu(v);
          } else if (FLAGS & GF_BF16){
            ((ushort*)Cv)[idx] = f2bu(v);
          } else {
            ((float*)Cv)[idx] = v;
          }
        }
      }
    }
  }
}

// ---------------- batched QK^T (bf16 Q, bf16 K): S[g][q][k] ----------------
__global__ __launch_bounds__(256) void k_qk16(const ushort* __restrict__ Qb, const ushort* __restrict__ Kb,
                                              float* __restrict__ S){
  const int tid = threadIdx.x;
  const int wv = tid>>6, lane = tid&63;
  const int mw = wv>>1, nw = wv&1;
  const int arow = lane&15, ks = lane>>4;
  const int m0 = blockIdx.x*128 + mw*64;
  const int n0 = blockIdx.y*128 + nw*64;
  const int g  = blockIdx.x>>2;
  const ushort* Kg = Kb + (size_t)g*131072;
  f32x4 acc[4][4] = {};
  #pragma unroll
  for (int k0 = 0; k0 < 256; k0 += 32){
    bf16x8 af[4];
    #pragma unroll
    for (int mf=0; mf<4; ++mf)
      af[mf] = *reinterpret_cast<const bf16x8*>(Qb + (size_t)(m0+mf*16+arow)*256 + k0 + ks*8);
    #pragma unroll
    for (int nf=0; nf<4; ++nf){
      const int j = n0 + nf*16 + arow;
      bf16x8 bfr = *reinterpret_cast<const bf16x8*>(Kg + (size_t)j*256 + k0 + ks*8);
      #pragma unroll
      for (int mf=0; mf<4; ++mf)
        acc[mf][nf] = __builtin_amdgcn_mfma_f32_16x16x32_bf16(af[mf], bfr, acc[mf][nf], 0, 0, 0);
    }
  }
  #pragma unroll
  for (int nf=0; nf<4; ++nf){
    const int n = n0 + nf*16 + arow;
    #pragma unroll
    for (int mf=0; mf<4; ++mf){
      #pragma unroll
      for (int r=0; r<4; ++r){
        const int m = m0 + mf*16 + ks*4 + r;
        S[(size_t)m*512 + n] = acc[mf][nf][r];
      }
    }
  }
}

// ---------------- row softmax (scale 1/16), f32 S -> normalized bf16 P ----------------
__global__ __launch_bounds__(256) void k_smrow(const float* __restrict__ S, ushort* __restrict__ P){
  const int row = blockIdx.x, tid = threadIdx.x;
  __shared__ float red[4];
  const float* sr = S + (size_t)row*512;
  float s0 = sr[tid], s1 = sr[tid+256];
  float m = fmaxf(s0, s1);
  #pragma unroll
  for (int o=1;o<64;o<<=1) m = fmaxf(m, __shfl_xor(m,o));
  if ((tid&63)==0) red[tid>>6] = m;
  __syncthreads();
  m = fmaxf(fmaxf(red[0],red[1]), fmaxf(red[2],red[3]));
  __syncthreads();
  float e0 = __expf((s0-m)*0.0625f), e1 = __expf((s1-m)*0.0625f);
  float s = e0+e1;
  #pragma unroll
  for (int o=1;o<64;o<<=1) s += __shfl_xor(s,o);
  if ((tid&63)==0) red[tid>>6] = s;
  __syncthreads();
  s = red[0]+red[1]+red[2]+red[3];
  float inv = 1.f/s;
  P[(size_t)row*512 + tid]       = f2bu(e0*inv);
  P[(size_t)row*512 + 256 + tid] = f2bu(e1*inv);
}

// ---------------- batched AV (single pass, P read once): O bf16 ----------------
__global__ __launch_bounds__(256) void k_av2(const ushort* __restrict__ Pb, const ushort* __restrict__ VTp,
                                             ushort* __restrict__ Ob){
  const int tid = threadIdx.x;
  const int wv = tid>>6, lane = tid&63;
  const int mw = wv&1, nw = wv>>1;
  const int arow = lane&15, ks = lane>>4;
  const int m0 = blockIdx.x*128 + mw*64;
  const int n0 = nw*128;
  const int g  = blockIdx.x>>2;
  const ushort* Vg = VTp + (size_t)g*131072;
  f32x4 acc[4][8] = {};
  #pragma unroll 1
  for (int k0 = 0; k0 < 512; k0 += 32){
    const int kb = (k0>>3) + ks;
    bf16x8 af[4];
    #pragma unroll
    for (int mf=0; mf<4; ++mf)
      af[mf] = *reinterpret_cast<const bf16x8*>(Pb + (size_t)(m0+mf*16+arow)*512 + k0 + ks*8);
    #pragma unroll
    for (int nf=0; nf<8; ++nf){
      const int col = n0 + nf*16 + arow;
      bf16x8 bfr = *reinterpret_cast<const bf16x8*>(Vg + ((size_t)kb*256 + col)*8);
      #pragma unroll
      for (int mf=0; mf<4; ++mf)
        acc[mf][nf] = __builtin_amdgcn_mfma_f32_16x16x32_bf16(af[mf], bfr, acc[mf][nf], 0, 0, 0);
    }
  }
  #pragma unroll
  for (int nf=0; nf<8; ++nf){
    const int n = n0 + nf*16 + arow;
    #pragma unroll
    for (int mf=0; mf<4; ++mf){
      #pragma unroll
      for (int r=0; r<4; ++r){
        const int m = m0 + mf*16 + ks*4 + r;
        Ob[(size_t)m*256 + n] = f2bu(acc[mf][nf][r]);
      }
    }
  }
}

// ---------------- small utilities ----------------
__global__ void k_rowbias(const float* __restrict__ bias, float* __restrict__ C, int Nn, int total){
  int i = blockIdx.x*256 + threadIdx.x;
  if (i < total) C[i] = bias[i % Nn];
}
__global__ void k_qvec(const float* __restrict__ seed, const float* __restrict__ Wq,
                       const float* __restrict__ bq, float* __restrict__ qv){
  __shared__ float s[256];
  int t = threadIdx.x;
  s[t] = seed[t]; __syncthreads();
  float acc = bq[t];
  for (int c = 0; c < 256; ++c) acc += s[c] * Wq[c*256 + t];
  qv[t] = acc;
}
__global__ __launch_bounds__(256) void k_wk2q(const float* __restrict__ Wk2, const float* __restrict__ bk2,
                      const float* __restrict__ qv, float* __restrict__ outv){
  __shared__ float qs[256];
  __shared__ float red[4];
  int t = threadIdx.x;
  qs[t] = qv[t]; __syncthreads();
  float a = 0.f;
  for (int c=0;c<256;c+=4){
    float4 w = *reinterpret_cast<const float4*>(Wk2 + t*256 + c);
    a += w.x*qs[c] + w.y*qs[c+1] + w.z*qs[c+2] + w.w*qs[c+3];
  }
  outv[t] = a;
  float bb = bk2[t]*qs[t];
  #pragma unroll
  for (int o=1;o<64;o<<=1) bb += __shfl_xor(bb,o);
  if ((t&63)==0) red[t>>6] = bb;
  __syncthreads();
  if (t==0) outv[256] = red[0]+red[1]+red[2]+red[3];
}
// fused PMA on bf16 kk: logits=(kk@wk2q+b2q)/16; alpha=softmax; wsum=sum alpha_j kk[j]
__global__ __launch_bounds__(256) void k_pmafuse16(const ushort* __restrict__ kkb, const float* __restrict__ wkq,
                        float* __restrict__ wsum){
  int g = blockIdx.x, tid = threadIdx.x;
  __shared__ float qs[256];
  __shared__ float sc[512];
  __shared__ float red[4];
  qs[tid] = wkq[tid];
  __syncthreads();
  const float b2q = wkq[256];
  const ushort* kg = kkb + (size_t)g*512*256;
  float l0=0.f, l1=0.f;
  for (int j0=0;j0<2;++j0){
    int j = tid + j0*256;
    const ushort* kr = kg + (size_t)j*256;
    float a = 0.f;
    for (int c8=0;c8<32;++c8){
      uint4 kv = *reinterpret_cast<const uint4*>(kr + c8*8);
      const float* qq = qs + c8*8;
      a += qq[0]*blo(kv.x)+qq[1]*bhi(kv.x)+qq[2]*blo(kv.y)+qq[3]*bhi(kv.y)
         + qq[4]*blo(kv.z)+qq[5]*bhi(kv.z)+qq[6]*blo(kv.w)+qq[7]*bhi(kv.w);
    }
    a = (a + b2q)*0.0625f;
    if (j0) l1=a; else l0=a;
  }
  float m = fmaxf(l0,l1);
  #pragma unroll
  for (int o=1;o<64;o<<=1) m = fmaxf(m, __shfl_xor(m,o));
  if ((tid&63)==0) red[tid>>6] = m;
  __syncthreads();
  m = fmaxf(fmaxf(red[0],red[1]), fmaxf(red[2],red[3]));
  __syncthreads();
  float e0 = __expf(l0-m), e1 = __expf(l1-m);
  sc[tid]=e0; sc[tid+256]=e1;
  float s = e0+e1;
  #pragma unroll
  for (int o=1;o<64;o<<=1) s += __shfl_xor(s,o);
  if ((tid&63)==0) red[tid>>6] = s;
  __syncthreads();
  s = red[0]+red[1]+red[2]+red[3];
  float invs = 1.f/s;
  float acc = 0.f;
  for (int j=0;j<512;++j) acc += sc[j] * b2f(kg[(size_t)j*256 + tid]);
  wsum[(size_t)g*256+tid] = acc*invs;
}
__global__ void k_concat(const float* __restrict__ p1, const float* __restrict__ p2,
                         const float* __restrict__ p3, float* __restrict__ pooled){
  int idx = blockIdx.x*256 + threadIdx.x;
  int b = idx / 768, j = idx % 768;
  float v = (j < 256) ? p1[b*256+j] : (j < 512) ? p2[b*256+j-256] : p3[b*256+j-512];
  pooled[idx] = v;
}

// ---------------- GRU v12: i8 Whh stream + bf16 X. 1 graph/block, 512 thr ----------
__global__ __launch_bounds__(512) void k_gru12(const ushort* __restrict__ X,
                      const ushort* __restrict__ pIh, const char* __restrict__ pHh8,
                      const float* __restrict__ csg, const float* __restrict__ bc,
                      float* __restrict__ p2){
  extern __shared__ char gsm[];
  float*  GIw  = (float*)gsm;                   // [32][768]  98304 B
  float*  gh   = (float*)(gsm + 98304);         // [768]
  float*  bcl  = (float*)(gsm + 101376);        // [1024]
  float*  csl  = (float*)(gsm + 105472);        // [768]
  char*   hbf8 = (char*) (gsm + 108544);        // [256]
  const int g = blockIdx.x;
  const int tid = threadIdx.x;
  const int wv = tid>>6, lane = tid&63;
  const int arow = lane&15, ks = lane>>4;
  for (int i=tid;i<1024;i+=512) bcl[i] = bc[i];
  for (int i=tid;i<768;i+=512)  csl[i] = csg[i];
  if (tid < 256) hbf8[tid] = 0;
  float h_reg = 0.f;
  const ushort* Xg = X + (size_t)g*512*256;
  __syncthreads();
  for (int w=0; w<16; ++w){
    const int t0 = w*32;
    #pragma unroll
    for (int mt=0; mt<2; ++mt){
      const ushort* xr = Xg + (size_t)(t0 + mt*16 + arow)*256;
      f32x4 acc[6] = {};
      #pragma unroll
      for (int kt=0; kt<8; ++kt){
        bf16x8 af = *reinterpret_cast<const bf16x8*>(xr + kt*32 + ks*8);
        #pragma unroll
        for (int nt=0; nt<6; ++nt){
          bf16x8 bfr = *reinterpret_cast<const bf16x8*>(pIh + ((size_t)(kt*4+ks)*768 + wv*96+nt*16+arow)*8);
          acc[nt] = __builtin_amdgcn_mfma_f32_16x16x32_bf16(af, bfr, acc[nt], 0,0,0);
        }
      }
      #pragma unroll
      for (int nt=0; nt<6; ++nt){
        const int col = wv*96 + nt*16 + arow;
        #pragma unroll
        for (int r=0;r<4;++r)
          GIw[(size_t)(mt*16 + ks*4 + r)*768 + col] = acc[nt][r];
      }
    }
    for (int dt=0; dt<32; ++dt){
      i32x4 sacc[6] = {};
      #pragma unroll
      for (int kt=0; kt<8; ++kt){
        long a8 = 0;
        if (arow == 0) a8 = *reinterpret_cast<const long*>(hbf8 + kt*32 + ks*8);
        #pragma unroll
        for (int nt=0; nt<6; ++nt){
          const int col = wv*96 + nt*16 + arow;
          long b8 = *reinterpret_cast<const long*>(pHh8 + ((size_t)(kt*4+ks)*768 + col)*8);
          sacc[nt] = __builtin_amdgcn_mfma_i32_16x16x32_i8(a8, b8, sacc[nt], 0,0,0);
        }
      }
      if (ks == 0){
        #pragma unroll
        for (int nt=0; nt<6; ++nt){
          const int col = wv*96 + nt*16 + arow;
          gh[col] = (float)sacc[nt][0] * csl[col];
        }
      }
      __syncthreads();
      if (tid < 256){
        const int c = tid;
        const float* gir = GIw + (size_t)dt*768;
        float rr = sigm(gir[c]     + gh[c]     + bcl[c]);
        float zz = sigm(gir[256+c] + gh[256+c] + bcl[256+c]);
        float nx = gir[512+c] + bcl[512+c] + rr*(gh[512+c] + bcl[768+c]);
        nx = fminf(fmaxf(nx, -15.f), 15.f);
        float e2 = __expf(2.f*nx);
        float nn = (e2-1.f)*__builtin_amdgcn_rcpf(e2+1.f);
        h_reg = (1.f-zz)*nn + zz*h_reg;
        int q = (int)lrintf(h_reg*127.f);
        q = max(-127, min(127, q));
        hbf8[c] = (char)q;
      }
      __syncthreads();
    }
  }
  if (tid < 256) p2[(size_t)g*256 + tid] = h_reg;
}

// =====================================================================
extern "C" void kernel_launch(void* const* d_in, const int* in_sizes, int n_in,
                              void* d_out, int out_size, void* d_ws, size_t ws_size,
                              hipStream_t stream){
  const int*   x      = (const int*)  d_in[0];
  const int*   ei     = (const int*)  d_in[1];
  const float* emb_w  = (const float*)d_in[3];
  const float* c1_lW  = (const float*)d_in[4];
  const float* c1_lb  = (const float*)d_in[5];
  const float* c1_rW  = (const float*)d_in[6];
  const float* t1     = (const float*)d_in[7];
  const float* c2_lW  = (const float*)d_in[8];
  const float* c2_lb  = (const float*)d_in[9];
  const float* c2_rW  = (const float*)d_in[10];
  const float* t2     = (const float*)d_in[11];
  const float* mlp_W  = (const float*)d_in[12];
  const float* mlp_b  = (const float*)d_in[13];
  const float* gWih   = (const float*)d_in[14];
  const float* gWhh   = (const float*)d_in[15];
  const float* gbih   = (const float*)d_in[16];
  const float* gbhh   = (const float*)d_in[17];
  const float* stWq   = (const float*)d_in[18];
  const float* stbq   = (const float*)d_in[19];
  const float* stWk   = (const float*)d_in[20];
  const float* stbk   = (const float*)d_in[21];
  const float* stWv   = (const float*)d_in[22];
  const float* stbv   = (const float*)d_in[23];
  const float* stWo   = (const float*)d_in[24];
  const float* stbo   = (const float*)d_in[25];
  const float* stlW   = (const float*)d_in[26];
  const float* stlb   = (const float*)d_in[27];
  const float* pma_lW = (const float*)d_in[28];
  const float* pma_lb = (const float*)d_in[29];
  const float* seed   = (const float*)d_in[30];
  const float* fin_W  = (const float*)d_in[31];
  const float* fin_b  = (const float*)d_in[32];
  float* out = (float*)d_out;

  auto needFor = [](int CHe)->size_t{
    size_t bufN = (size_t)CHe*512*512;
    size_t floats = (size_t)33554432 + 3*bufN + 2*524288 + 2*196608 + 8*65536 + 196608 + 320 + 512;
    size_t ints   = 131072 + 131200 + 131072 + 262144 + 128 + 128;
    return floats*4 + ints*4 + 4096;
  };
  const int CHe = (ws_size >= needFor(64)) ? 64 : 32;
  if (ws_size < needFor(32)) return;
  const int NCHUNKe = BG / CHe;
  const int NCNe = CHe * 512;
  const size_t bufN = (size_t)CHe*512*512;

  // ---- workspace carve ----
  float* H2   = (float*)d_ws;                    // NN*256: bf16 now (half used)
  float* bufA = H2   + (size_t)33554432;
  float* bufB = bufA + bufN;
  float* bufC = bufB + bufN;
  float* h0   = bufC + bufN;
  float* ag1  = h0   + (size_t)524288;
  float* wT1  = ag1  + (size_t)524288;
  float* wT2  = wT1  + (size_t)196608;
  float* p1   = wT2  + (size_t)196608;
  float* p2   = p1   + (size_t)65536;
  float* p3   = p2   + (size_t)65536;
  float* av2  = p3   + (size_t)65536;
  float* s1   = av2  + (size_t)65536;
  float* s2v  = s1   + (size_t)65536;
  float* v3   = s2v  + (size_t)65536;
  float* h3   = v3   + (size_t)65536;
  float* pooled = h3 + (size_t)65536;
  float* qv   = pooled + (size_t)196608;
  int*   deg  = (int*)(qv + 320);
  int*   offs = deg  + 131072;
  int*   cur  = offs + 131200;
  int*   esrc = cur  + 131072;
  int*   bsum = esrc + 262144;
  int*   boff = bsum + 128;
  float* wkq  = (float*)(boff + 128);

  ushort* H2b  = (ushort*)H2;                    // NN x 256 bf16
  ushort* pIh  = (ushort*)wT1;
  char*   pHh8 = (char*)(wT1 + 98304);
  float*  csHh = wT1 + 98304 + 49152;
  ushort* pC2  = (ushort*)wT2;
  float*  bcomb= wT2 + 65536;
  float*  pa   = h0;
  ushort* pQ0  = (ushort*)(pa);
  ushort* pK0  = (ushort*)(pa + 32768);
  ushort* pV0  = (ushort*)(pa + 65536);
  ushort* pO0  = (ushort*)(pa + 98304);
  ushort* pL0  = (ushort*)(pa + 131072);
  ushort* pPma = (ushort*)(pa + 163840);
  ushort* pV1  = (ushort*)(pa + 229376);
  ushort* pO1  = (ushort*)(pa + 262144);
  ushort* pL1  = (ushort*)(pa + 294912);
  ushort* pV2  = (ushort*)(pa + 327680);
  ushort* pO2  = (ushort*)(pa + 360448);
  ushort* pL2  = (ushort*)(pa + 393216);
  ushort* pFin = (ushort*)(pa + 425984);

  // ST sub-buffers
  ushort* Qbf = (ushort*)bufA;                   // NCNe x 256 bf16
  ushort* Obf = (ushort*)(bufA + bufN/4);        // NCNe x 256 bf16
  ushort* VTp = (ushort*)(bufA + bufN/2);        // per-graph packed V
  ushort* Kbf = (ushort*)bufB;                   // NCNe x 256 bf16 (later kk)
  ushort* Pbf = (ushort*)(bufB + bufN/4);        // NCNe x 512 bf16
  ushort* Ebf = Qbf;                             // h_enc reuses Q space
  ushort* kkb = Kbf;                             // kk reuses K space

  const int ls0 = 65536, ls1 = 256;

  // ---- 1. node encoder ----
  k_node_enc<<<NN/256, 256, 0, stream>>>(x, emb_w, h0);

  // ---- 2. CSR ----
  k_zero<<<NN/256, 256, 0, stream>>>(deg, NN);
  k_count<<<NE/256, 256, 0, stream>>>(ei, deg);
  k_blocksum<<<128, 256, 0, stream>>>(deg, bsum);
  k_scanbsum<<<1, 128, 0, stream>>>(bsum, boff, offs + NN);
  k_scanchunk<<<128, 256, 0, stream>>>(deg, boff, offs);
  k_zero<<<NN/256, 256, 0, stream>>>(cur, NN);
  k_fill<<<NE/256, 256, 0, stream>>>(ei, offs, cur, esrc);

  // ---- 3. conv1 aggregation + early packs ----
  k_aggr4<<<NN/256, 256, 0, stream>>>(h0, offs, esrc, t1, ag1);
  k_packb <<<256, 256, 0, stream>>>(c2_rW, pC2, 256, 256);
  k_packb <<<256, 256, 0, stream>>>(c2_lW, pC2 + 65536, 256, 256);
  k_packbT<<<768, 256, 0, stream>>>(gWih, pIh, 256, 768);
  k_packhh8<<<768, 256, 0, stream>>>(gWhh, pHh8, csHh);
  k_packbias<<<4, 256, 0, stream>>>(gbih, gbhh, bcomb);

  // ---- 4. conv1 + conv2 (fused K=512) -> H2b bf16, chunked ----
  for (int cg = 0; cg < NCHUNKe; ++cg){
    const int base = cg * NCNe;
    ushort* Hcb = H2b + (size_t)base * 256;
    k_conv1_lin<<<NCNe, 256, 0, stream>>>(ag1, h0, c1_lW, c1_lb, c1_rW, bufA, base);
    k_aggr256<<<NCNe, 256, 0, stream>>>(bufA, offs, esrc, t2, base);
    k_bgemm2<GF_BIAS|GF_RELU|GF_BF16, false><<<NCNe/128, 256, 0, stream>>>(bufA, pC2, c2_lb, nullptr, Hcb, 512, 512);
  }

  // ---- 5. p1 = MLP pool via MFMA (A = H2b bf16 viewed [256][131072]) ----
  k_packb<<<131072, 256, 0, stream>>>(mlp_W, (ushort*)bufB, 131072, 256);
  k_rowbias<<<256, 256, 0, stream>>>(mlp_b, p1, 256, 65536);
  k_bgemm2<GF_ATOMIC, true><<<dim3(2, 1, 128), 256, 0, stream>>>(H2b, (ushort*)bufB, nullptr, nullptr, p1, NN, 131072);

  // ---- 6. GRU v12 (i8 Whh stream, bf16 X; 256 blocks, 8 waves) ----
  k_gru12<<<BG, 512, 108800, stream>>>(H2b, pIh, pHh8, csHh, bcomb, p2);

  // ---- 7. ST packs + set transformer (all-bf16 intermediates), chunked ----
  k_packb<<<256, 256, 0, stream>>>(stWq,        pQ0, 256, 256);
  k_packb<<<256, 256, 0, stream>>>(stWk,        pK0, 256, 256);
  k_packb<<<256, 256, 0, stream>>>(stWv,        pV0, 256, 256);
  k_packb<<<256, 256, 0, stream>>>(stWo,        pO0, 256, 256);
  k_packb<<<256, 256, 0, stream>>>(stlW,        pL0, 256, 256);
  k_packb<<<256, 256, 0, stream>>>(pma_lW,      pPma,256, 256);
  k_packb<<<256, 256, 0, stream>>>(stWv + ls0,  pV1, 256, 256);
  k_packb<<<256, 256, 0, stream>>>(stWo + ls0,  pO1, 256, 256);
  k_packb<<<256, 256, 0, stream>>>(stlW + ls0,  pL1, 256, 256);
  k_packb<<<256, 256, 0, stream>>>(stWv + 2*ls0,pV2, 256, 256);
  k_packb<<<256, 256, 0, stream>>>(stWo + 2*ls0,pO2, 256, 256);
  k_packb<<<256, 256, 0, stream>>>(stlW + 2*ls0,pL2, 256, 256);
  k_packb<<<2304, 256, 0, stream>>>(fin_W,      pFin,768, 768);
  k_qvec<<<1, 256, 0, stream>>>(seed, stWq + ls0, stbq + ls1, qv);
  k_wk2q<<<1, 256, 0, stream>>>(stWk + ls0, stbk + ls1, qv, wkq);

  for (int cg = 0; cg < NCHUNKe; ++cg){
    const int base = cg * NCNe;
    ushort* Hcb = H2b + (size_t)base * 256;
    const int gb1 = NCNe/128;
    k_bgemm2<GF_BIAS|GF_BF16, true><<<gb1, 256, 0, stream>>>(Hcb, pQ0, stbq, nullptr, Qbf, 256, 256);   // Q bf16
    k_bgemm2<GF_BIAS|GF_BF16, true><<<gb1, 256, 0, stream>>>(Hcb, pK0, stbk, nullptr, Kbf, 256, 256);   // K bf16
    k_bgemm2<GF_BIAS|GF_VTP,  true><<<gb1, 256, 0, stream>>>(Hcb, pV0, stbv, nullptr, VTp, 256, 256);   // V packed
    k_qk16<<<dim3(gb1, 4), 256, 0, stream>>>(Qbf, Kbf, bufC);                                           // S f32
    k_smrow<<<NCNe, 256, 0, stream>>>(bufC, Pbf);                                                       // P bf16
    k_av2<<<gb1, 256, 0, stream>>>(Pbf, VTp, Obf);                                                      // O bf16
    k_bgemm2<GF_BIAS|GF_RESID16|GF_BF16, true><<<gb1, 256, 0, stream>>>(Obf, pO0, stbo, Hcb, Hcb, 256, 256);        // h_sab
    k_bgemm2<GF_BIAS|GF_RELU|GF_RESID16|GF_BF16, true><<<gb1, 256, 0, stream>>>(Hcb, pL0, stlb, Hcb, Ebf, 256, 256); // h_enc
    k_bgemm2<GF_BIAS|GF_RELU|GF_BF16, true><<<gb1, 256, 0, stream>>>(Ebf, pPma, pma_lb, nullptr, kkb, 256, 256);     // kk
    k_pmafuse16<<<CHe, 256, 0, stream>>>(kkb, wkq, av2 + (size_t)cg*CHe*256);                           // wsum
  }

  // ---- 8. PMA tail + decoder SAB (small, f32 path) ----
  k_bgemm<GF_BIAS><<<dim3(2, 2, 1), 256, 0, stream>>>(av2, pV1, stbv + ls1, nullptr, v3, 256, 256, 256, 256);
  k_bgemm<GF_BIAS|GF_RESID_B><<<dim3(2, 2, 1), 256, 0, stream>>>(v3, pO1, stbo + ls1, seed, s1, 256, 256, 256, 256);
  k_bgemm<GF_BIAS|GF_RELU|GF_RESID><<<dim3(2, 2, 1), 256, 0, stream>>>(s1, pL1, stlb + ls1, s1, s2v, 256, 256, 256, 256);
  k_bgemm<GF_BIAS><<<dim3(2, 2, 1), 256, 0, stream>>>(s2v, pV2, stbv + 2*ls1, nullptr, v3, 256, 256, 256, 256);
  k_bgemm<GF_BIAS|GF_RESID><<<dim3(2, 2, 1), 256, 0, stream>>>(v3, pO2, stbo + 2*ls1, s2v, h3, 256, 256, 256, 256);
  k_bgemm<GF_BIAS|GF_RELU|GF_RESID><<<dim3(2, 2, 1), 256, 0, stream>>>(h3, pL2, stlb + 2*ls1, h3, p3, 256, 256, 256, 256);

  // ---- 9. concat + final linear ----
  k_concat<<<768, 256, 0, stream>>>(p1, p2, p3, pooled);
  k_bgemm<GF_BIAS><<<dim3(2, 6, 1), 256, 0, stream>>>(pooled, pFin, fin_b, nullptr, out, 256, 768, 768, 768);
}

// Round 14
// 2562.355 us; speedup vs baseline: 4.8389x; 1.0663x over previous
//
#include <hip/hip_runtime.h>
#include <hip/hip_bf16.h>
#include <math.h>

// ---- problem constants ----
constexpr int NN   = 131072;   // total nodes (B*NPG)
constexpr int NE   = 262144;   // edges
constexpr int BG   = 256;      // graphs

typedef __bf16 bf16x8 __attribute__((ext_vector_type(8)));
typedef float  f32x4  __attribute__((ext_vector_type(4)));
typedef int    i32x4  __attribute__((ext_vector_type(4)));

__device__ inline float sigm(float x){ return 1.f/(1.f+__expf(-x)); }
__device__ inline float blo(unsigned u){ union{unsigned a;float f;}v; v.a=u<<16; return v.f; }
__device__ inline float bhi(unsigned u){ union{unsigned a;float f;}v; v.a=u&0xffff0000u; return v.f; }
__device__ inline float b2f(ushort u){ union{unsigned a;float f;}v; v.a=((unsigned)u)<<16; return v.f; }
__device__ inline unsigned short f2bu(float f){
  union{float f;unsigned u;}v; v.f=f;
  unsigned u = v.u + 0x7fffu + ((v.u>>16)&1u);
  return (unsigned short)(u>>16);
}
__device__ inline bf16x8 cvt8(float4 a, float4 b){
  union { ushort u[8]; bf16x8 v; } r;
  r.u[0]=f2bu(a.x); r.u[1]=f2bu(a.y); r.u[2]=f2bu(a.z); r.u[3]=f2bu(a.w);
  r.u[4]=f2bu(b.x); r.u[5]=f2bu(b.y); r.u[6]=f2bu(b.z); r.u[7]=f2bu(b.w);
  return r.v;
}

__global__ void k_zero(int* __restrict__ p, int n){
  int i = blockIdx.x*256 + threadIdx.x;
  if (i < n) p[i] = 0;
}

// ---------------- node encoder ----------------
__global__ void k_node_enc(const int* __restrict__ x, const float* __restrict__ emb,
                           float* __restrict__ h0){
  int n = blockIdx.x*256 + threadIdx.x;
  if (n >= NN) return;
  int nt = x[2*n], ninv = x[2*n+1];
  float4 v; v.x = emb[nt*3+0]; v.y = emb[nt*3+1]; v.z = emb[nt*3+2]; v.w = (float)ninv;
  reinterpret_cast<float4*>(h0)[n] = v;
}

// ---------------- CSR build (by dst) ----------------
__global__ void k_count(const int* __restrict__ ei, int* __restrict__ deg){
  int e = blockIdx.x*256 + threadIdx.x;
  if (e >= NE) return;
  atomicAdd(&deg[ei[NE + e]], 1);
}
__global__ void k_blocksum(const int* __restrict__ deg, int* __restrict__ bsum){
  __shared__ int sd[256];
  int t = threadIdx.x;
  const int* p = deg + blockIdx.x*1024;
  int s = p[t*4] + p[t*4+1] + p[t*4+2] + p[t*4+3];
  sd[t]=s; __syncthreads();
  for (int d=128; d>0; d>>=1){ if (t<d) sd[t]+=sd[t+d]; __syncthreads(); }
  if (!t) bsum[blockIdx.x] = sd[0];
}
__global__ void k_scanbsum(const int* __restrict__ bsum, int* __restrict__ boff, int* __restrict__ offN){
  __shared__ int s[128];
  int t = threadIdx.x;
  int mine = bsum[t];
  s[t]=mine; __syncthreads();
  for (int d=1; d<128; d<<=1){ int v = (t>=d)? s[t-d]:0; __syncthreads(); s[t]+=v; __syncthreads(); }
  boff[t] = s[t]-mine;
  if (t==127) offN[0] = s[127];
}
__global__ void k_scanchunk(const int* __restrict__ deg, const int* __restrict__ boff, int* __restrict__ offs){
  __shared__ int ts[256];
  int t = threadIdx.x, b = blockIdx.x;
  const int* p = deg + b*1024;
  int v0=p[t*4],v1=p[t*4+1],v2=p[t*4+2],v3=p[t*4+3];
  int mysum=v0+v1+v2+v3;
  ts[t]=mysum; __syncthreads();
  for (int d=1; d<256; d<<=1){ int v=(t>=d)?ts[t-d]:0; __syncthreads(); ts[t]+=v; __syncthreads(); }
  int ex = ts[t]-mysum + boff[b];
  int* o = offs + b*1024 + t*4;
  o[0]=ex; o[1]=ex+v0; o[2]=ex+v0+v1; o[3]=ex+v0+v1+v2;
}
__global__ void k_fill(const int* __restrict__ ei, const int* __restrict__ offs,
                       int* __restrict__ cur, int* __restrict__ esrc){
  int e = blockIdx.x*256 + threadIdx.x;
  if (e >= NE) return;
  int dst = ei[NE+e];
  int pos = offs[dst] + atomicAdd(&cur[dst],1);
  esrc[pos] = ei[e];
}

// ---------------- softmax aggregation, 4-channel (conv1), no-max (exact) ----------------
__global__ void k_aggr4(const float* __restrict__ h, const int* __restrict__ offs,
                        const int* __restrict__ esrc, const float* __restrict__ tptr,
                        float* __restrict__ ag){
  int n = blockIdx.x*256 + threadIdx.x;
  if (n >= NN) return;
  int s = offs[n], e = offs[n+1];
  float4 z = {0,0,0,0};
  if (s == e){ reinterpret_cast<float4*>(ag)[n] = z; return; }
  float t = *tptr;
  float4 num=z, den=z;
  for (int i=s;i<e;++i){
    float4 v = reinterpret_cast<const float4*>(h)[esrc[i]];
    float ex;
    ex=__expf(v.x*t); num.x+=v.x*ex; den.x+=ex;
    ex=__expf(v.y*t); num.y+=v.y*ex; den.y+=ex;
    ex=__expf(v.z*t); num.z+=v.z*ex; den.z+=ex;
    ex=__expf(v.w*t); num.w+=v.w*ex; den.w+=ex;
  }
  float4 r = {num.x/den.x, num.y/den.y, num.z/den.z, num.w/den.w};
  reinterpret_cast<float4*>(ag)[n] = r;
}

// ---------------- softmax aggregation (no-max), bf16 fused [h1|ag] layout ----------------
__global__ __launch_bounds__(256) void k_aggr256(ushort* __restrict__ buf, const int* __restrict__ offs,
                          const int* __restrict__ esrc, const float* __restrict__ tptr, int base){
  int n = base + blockIdx.x, c = threadIdx.x;
  int s = offs[n], e = offs[n+1];
  ushort* outp = buf + (size_t)blockIdx.x*512 + 256 + c;
  if (s == e){ *outp = 0; return; }
  float t = *tptr;
  float num=0.f, den=0.f;
  for (int i=s;i<e;++i){
    float v = b2f(buf[(size_t)(esrc[i]-base)*512 + c]);
    float ex = __expf(v*t);
    num += v*ex; den += ex;
  }
  *outp = f2bu(num/den);
}

// ---------------- conv1 linear (K=4, fused), writes bf16 [n][512] col 0..255 ----------------
__global__ __launch_bounds__(256) void k_conv1_lin(const float* __restrict__ ag, const float* __restrict__ h0,
                            const float* __restrict__ lW, const float* __restrict__ lb,
                            const float* __restrict__ rW, ushort* __restrict__ out, int base){
  int n = base + blockIdx.x, c = threadIdx.x;
  float4 a  = reinterpret_cast<const float4*>(ag)[n];
  float4 xv = reinterpret_cast<const float4*>(h0)[n];
  float acc = lb[c];
  acc += a.x*lW[c]  + a.y*lW[256+c]  + a.z*lW[512+c]  + a.w*lW[768+c];
  acc += xv.x*rW[c] + xv.y*rW[256+c] + xv.z*rW[512+c] + xv.w*rW[768+c];
  out[(size_t)blockIdx.x*512 + c] = f2bu(fmaxf(acc, 0.f));
}

// ---------------- flags ----------------
#define GF_BIAS    1
#define GF_RELU    2
#define GF_RESID   4
#define GF_RESID_B 8
#define GF_ADDC    32
#define GF_ATOMIC  64
#define GF_BF16    128
#define GF_VTP     256
#define GF_RESID16 512

// ---------------- weight packs ----------------
__global__ void k_packb(const float* __restrict__ W, ushort* __restrict__ Bp, int K, int N){
  int idx = blockIdx.x*256 + threadIdx.x;
  if (idx >= K*N) return;
  int k = idx / N, j = idx - k*N;
  Bp[((size_t)(k>>3)*N + j)*8 + (k&7)] = f2bu(W[idx]);
}
__global__ void k_packbT(const float* __restrict__ W, ushort* __restrict__ Bp, int K, int N){
  int idx = blockIdx.x*256 + threadIdx.x;
  if (idx >= K*N) return;
  int j = idx / K, k = idx - j*K;
  Bp[((size_t)(k>>3)*N + j)*8 + (k&7)] = f2bu(W[idx]);
}
__global__ __launch_bounds__(256) void k_packhh8(const float* __restrict__ gWhh,
                        char* __restrict__ Bp8, float* __restrict__ cs){
  int j = blockIdx.x, k = threadIdx.x;
  float w = gWhh[(size_t)j*256 + k];
  __shared__ float red[256];
  red[k] = fabsf(w); __syncthreads();
  for (int d=128; d>0; d>>=1){ if (k<d) red[k]=fmaxf(red[k],red[k+d]); __syncthreads(); }
  float mx = fmaxf(red[0], 1e-20f);
  int q = (int)lrintf(w * (127.f/mx));
  q = max(-127, min(127, q));
  Bp8[((size_t)(k>>3)*768 + j)*8 + (k&7)] = (char)q;
  if (k==0) cs[j] = mx/(127.f*127.f);
}
__global__ void k_packbias(const float* __restrict__ gbih, const float* __restrict__ gbhh,
                           float* __restrict__ bc){
  int i = blockIdx.x*256 + threadIdx.x;
  if (i >= 1024) return;
  int c = i & 255;
  float v;
  if (i < 256)      v = gbih[c] + gbhh[c];
  else if (i < 512) v = gbih[256+c] + gbhh[256+c];
  else if (i < 768) v = gbih[512+c];
  else              v = gbhh[512+c];
  bc[i] = v;
}

// ---------------- old f32 MFMA GEMM (tail only) ----------------
template<int FLAGS>
__global__ __launch_bounds__(256) void k_bgemm(const float* __restrict__ A, const ushort* __restrict__ Bp,
                       const float* __restrict__ bias, const float* __restrict__ resid,
                       float* __restrict__ C, int M, int Nn, int K, int lda){
  const int tid = threadIdx.x;
  const int wv = tid>>6, lane = tid&63;
  const int mw = wv>>1, nw = wv&1;
  const int arow = lane&15, ks = lane>>4;
  const int m0 = blockIdx.x*128 + mw*64, n0 = blockIdx.y*128 + nw*64;
  f32x4 acc[4][4] = {};
  #pragma unroll 2
  for (int k0 = 0; k0 < K; k0 += 32){
    const int kb = (k0>>3) + ks;
    bf16x8 af[4];
    #pragma unroll
    for (int mf=0; mf<4; ++mf){
      const float4* p = reinterpret_cast<const float4*>(A + (size_t)(m0+mf*16+arow)*lda + k0 + ks*8);
      af[mf] = cvt8(p[0], p[1]);
    }
    #pragma unroll
    for (int nf=0; nf<4; ++nf){
      const int col = n0 + nf*16 + arow;
      bf16x8 bfr = *reinterpret_cast<const bf16x8*>(Bp + ((size_t)kb*Nn + col)*8);
      #pragma unroll
      for (int mf=0; mf<4; ++mf)
        acc[mf][nf] = __builtin_amdgcn_mfma_f32_16x16x32_bf16(af[mf], bfr, acc[mf][nf], 0, 0, 0);
    }
  }
  #pragma unroll
  for (int nf=0; nf<4; ++nf){
    const int n = n0 + nf*16 + arow;
    float bv  = (FLAGS & GF_BIAS)    ? bias[n]  : 0.f;
    float rbv = (FLAGS & GF_RESID_B) ? resid[n] : 0.f;
    #pragma unroll
    for (int mf=0; mf<4; ++mf){
      #pragma unroll
      for (int r=0; r<4; ++r){
        const int m = m0 + mf*16 + ks*4 + r;
        size_t idx = (size_t)m*Nn + n;
        float v = acc[mf][nf][r];
        v += bv;
        if (FLAGS & GF_RELU)  v = fmaxf(v, 0.f);
        if (FLAGS & GF_RESID) v += resid[idx];
        v += rbv;
        C[idx] = v;
      }
    }
  }
}

// ---------------- bgemm2: 128x256 tile per block, N fixed = 256 -----------
template<int FLAGS, bool ABF>
__global__ __launch_bounds__(256) void k_bgemm2(const void* __restrict__ Av, const ushort* __restrict__ Bp,
                       const float* __restrict__ bias, const void* __restrict__ residv,
                       void* __restrict__ Cv, int K, int lda){
  const int tid = threadIdx.x;
  const int wv = tid>>6, lane = tid&63;
  const int mw = wv&1, nw = wv>>1;
  const int arow = lane&15, ks = lane>>4;
  const int m0 = blockIdx.x*128 + mw*64;
  const int n0 = nw*128;
  const int kChunk = K / gridDim.z, kBeg = blockIdx.z * kChunk;
  f32x4 acc[4][8] = {};
  #pragma unroll 1
  for (int k0 = kBeg; k0 < kBeg+kChunk; k0 += 32){
    const int kb = (k0>>3) + ks;
    bf16x8 af[4];
    if (ABF){
      const ushort* A = (const ushort*)Av;
      #pragma unroll
      for (int mf=0; mf<4; ++mf)
        af[mf] = *reinterpret_cast<const bf16x8*>(A + (size_t)(m0+mf*16+arow)*lda + k0 + ks*8);
    } else {
      const float* A = (const float*)Av;
      #pragma unroll
      for (int mf=0; mf<4; ++mf){
        const float4* p = reinterpret_cast<const float4*>(A + (size_t)(m0+mf*16+arow)*lda + k0 + ks*8);
        af[mf] = cvt8(p[0], p[1]);
      }
    }
    #pragma unroll
    for (int nf=0; nf<8; ++nf){
      const int col = n0 + nf*16 + arow;
      bf16x8 bfr = *reinterpret_cast<const bf16x8*>(Bp + ((size_t)kb*256 + col)*8);
      #pragma unroll
      for (int mf=0; mf<4; ++mf)
        acc[mf][nf] = __builtin_amdgcn_mfma_f32_16x16x32_bf16(af[mf], bfr, acc[mf][nf], 0, 0, 0);
    }
  }
  #pragma unroll
  for (int nf=0; nf<8; ++nf){
    const int n = n0 + nf*16 + arow;
    float bv = (FLAGS & GF_BIAS) ? bias[n] : 0.f;
    #pragma unroll
    for (int mf=0; mf<4; ++mf){
      #pragma unroll
      for (int r=0; r<4; ++r){
        const int m = m0 + mf*16 + ks*4 + r;
        size_t idx = (size_t)m*256 + n;
        float v = acc[mf][nf][r];
        if (FLAGS & GF_ATOMIC){ atomicAdd((float*)Cv + idx, v); }
        else {
          v += bv;
          if (FLAGS & GF_RELU) v = fmaxf(v, 0.f);
          if (FLAGS & GF_RESID16) v += b2f(((const ushort*)residv)[idx]);
          if (FLAGS & GF_VTP){
            const int rr = m & 511, mg = m >> 9;
            ((ushort*)Cv)[(size_t)mg*131072 + (((rr>>3)*256 + n)<<3) + (rr&7)] = f2bu(v);
          } else if (FLAGS & GF_BF16){
            ((ushort*)Cv)[idx] = f2bu(v);
          } else {
            ((float*)Cv)[idx] = v;
          }
        }
      }
    }
  }
}

// ---------------- fused attention: QK^T -> LDS softmax -> AV, per 64 q-rows ----------------
// LDS: S [64][516] f32 (pad 516 breaks phase-3 bank conflicts) + red1/red2[256] + invr[64]
__global__ __launch_bounds__(256) void k_afuse(const ushort* __restrict__ Qb, const ushort* __restrict__ Kb,
                        const ushort* __restrict__ VTp, ushort* __restrict__ Ob){
  extern __shared__ char afm[];
  float* Sld  = (float*)afm;                 // 64*516 = 132096 B
  float* red1 = (float*)(afm + 132096);      // 256
  float* red2 = red1 + 256;                  // 256
  float* invr = red2 + 256;                  // 64
  const int tid = threadIdx.x;
  const int wv = tid>>6, lane = tid&63;
  const int arow = lane&15, ks = lane>>4;
  const int m0 = blockIdx.x*64;
  const int g  = blockIdx.x>>3;
  const ushort* Kg = Kb  + (size_t)g*131072;
  const ushort* Vg = VTp + (size_t)g*131072;
  // ---- phase 1: S tile = Q[64] @ K^T ; wave wv owns keys [wv*128, +128) ----
  {
    const int n0 = wv*128;
    f32x4 acc[4][8] = {};
    #pragma unroll
    for (int k0 = 0; k0 < 256; k0 += 32){
      bf16x8 af[4];
      #pragma unroll
      for (int mf=0; mf<4; ++mf)
        af[mf] = *reinterpret_cast<const bf16x8*>(Qb + (size_t)(m0+mf*16+arow)*256 + k0 + ks*8);
      #pragma unroll
      for (int nf=0; nf<8; ++nf){
        const int j = n0 + nf*16 + arow;
        bf16x8 bfr = *reinterpret_cast<const bf16x8*>(Kg + (size_t)j*256 + k0 + ks*8);
        #pragma unroll
        for (int mf=0; mf<4; ++mf)
          acc[mf][nf] = __builtin_amdgcn_mfma_f32_16x16x32_bf16(af[mf], bfr, acc[mf][nf], 0, 0, 0);
      }
    }
    #pragma unroll
    for (int nf=0; nf<8; ++nf){
      const int col = n0 + nf*16 + arow;
      #pragma unroll
      for (int mf=0; mf<4; ++mf){
        #pragma unroll
        for (int r=0; r<4; ++r)
          Sld[(size_t)(mf*16 + ks*4 + r)*516 + col] = acc[mf][nf][r];
      }
    }
  }
  __syncthreads();
  // ---- phase 2: row softmax (unnormalized e in place, invr per row) ----
  {
    const int row = tid>>2, q = tid&3;
    float* sr = Sld + (size_t)row*516 + q*128;
    float mx = -3e38f;
    for (int c=0;c<128;++c) mx = fmaxf(mx, sr[c]);
    red1[row*4+q] = mx;
    __syncthreads();
    mx = fmaxf(fmaxf(red1[row*4], red1[row*4+1]), fmaxf(red1[row*4+2], red1[row*4+3]));
    float sum = 0.f;
    for (int c=0;c<128;++c){ float e = __expf((sr[c]-mx)*0.0625f); sr[c]=e; sum+=e; }
    red2[row*4+q] = sum;
    __syncthreads();
    if (q==0) invr[row] = 1.f/(red2[row*4]+red2[row*4+1]+red2[row*4+2]+red2[row*4+3]);
    __syncthreads();
  }
  // ---- phase 3: O = P @ V (A from LDS, B = per-graph packed V), scale by invr ----
  {
    const int n0 = wv*64;
    f32x4 acc[4][4] = {};
    #pragma unroll 1
    for (int k0 = 0; k0 < 512; k0 += 32){
      const int kb = (k0>>3) + ks;
      bf16x8 af[4];
      #pragma unroll
      for (int mf=0; mf<4; ++mf){
        const float4* p = reinterpret_cast<const float4*>(Sld + (size_t)(mf*16+arow)*516 + k0 + ks*8);
        af[mf] = cvt8(p[0], p[1]);
      }
      #pragma unroll
      for (int nf=0; nf<4; ++nf){
        const int col = n0 + nf*16 + arow;
        bf16x8 bfr = *reinterpret_cast<const bf16x8*>(Vg + ((size_t)kb*256 + col)*8);
        #pragma unroll
        for (int mf=0; mf<4; ++mf)
          acc[mf][nf] = __builtin_amdgcn_mfma_f32_16x16x32_bf16(af[mf], bfr, acc[mf][nf], 0, 0, 0);
      }
    }
    #pragma unroll
    for (int nf=0; nf<4; ++nf){
      const int n = n0 + nf*16 + arow;
      #pragma unroll
      for (int mf=0; mf<4; ++mf){
        #pragma unroll
        for (int r=0; r<4; ++r){
          const int lr = mf*16 + ks*4 + r;
          Ob[(size_t)(m0+lr)*256 + n] = f2bu(acc[mf][nf][r] * invr[lr]);
        }
      }
    }
  }
}

// ---------------- small utilities ----------------
__global__ void k_rowbias(const float* __restrict__ bias, float* __restrict__ C, int Nn, int total){
  int i = blockIdx.x*256 + threadIdx.x;
  if (i < total) C[i] = bias[i % Nn];
}
__global__ void k_qvec(const float* __restrict__ seed, const float* __restrict__ Wq,
                       const float* __restrict__ bq, float* __restrict__ qv){
  __shared__ float s[256];
  int t = threadIdx.x;
  s[t] = seed[t]; __syncthreads();
  float acc = bq[t];
  for (int c = 0; c < 256; ++c) acc += s[c] * Wq[c*256 + t];
  qv[t] = acc;
}
__global__ __launch_bounds__(256) void k_wk2q(const float* __restrict__ Wk2, const float* __restrict__ bk2,
                      const float* __restrict__ qv, float* __restrict__ outv){
  __shared__ float qs[256];
  __shared__ float red[4];
  int t = threadIdx.x;
  qs[t] = qv[t]; __syncthreads();
  float a = 0.f;
  for (int c=0;c<256;c+=4){
    float4 w = *reinterpret_cast<const float4*>(Wk2 + t*256 + c);
    a += w.x*qs[c] + w.y*qs[c+1] + w.z*qs[c+2] + w.w*qs[c+3];
  }
  outv[t] = a;
  float bb = bk2[t]*qs[t];
  #pragma unroll
  for (int o=1;o<64;o<<=1) bb += __shfl_xor(bb,o);
  if ((t&63)==0) red[t>>6] = bb;
  __syncthreads();
  if (t==0) outv[256] = red[0]+red[1]+red[2]+red[3];
}
__global__ __launch_bounds__(256) void k_pmafuse16(const ushort* __restrict__ kkb, const float* __restrict__ wkq,
                        float* __restrict__ wsum){
  int g = blockIdx.x, tid = threadIdx.x;
  __shared__ float qs[256];
  __shared__ float sc[512];
  __shared__ float red[4];
  qs[tid] = wkq[tid];
  __syncthreads();
  const float b2q = wkq[256];
  const ushort* kg = kkb + (size_t)g*512*256;
  float l0=0.f, l1=0.f;
  for (int j0=0;j0<2;++j0){
    int j = tid + j0*256;
    const ushort* kr = kg + (size_t)j*256;
    float a = 0.f;
    for (int c8=0;c8<32;++c8){
      uint4 kv = *reinterpret_cast<const uint4*>(kr + c8*8);
      const float* qq = qs + c8*8;
      a += qq[0]*blo(kv.x)+qq[1]*bhi(kv.x)+qq[2]*blo(kv.y)+qq[3]*bhi(kv.y)
         + qq[4]*blo(kv.z)+qq[5]*bhi(kv.z)+qq[6]*blo(kv.w)+qq[7]*bhi(kv.w);
    }
    a = (a + b2q)*0.0625f;
    if (j0) l1=a; else l0=a;
  }
  float m = fmaxf(l0,l1);
  #pragma unroll
  for (int o=1;o<64;o<<=1) m = fmaxf(m, __shfl_xor(m,o));
  if ((tid&63)==0) red[tid>>6] = m;
  __syncthreads();
  m = fmaxf(fmaxf(red[0],red[1]), fmaxf(red[2],red[3]));
  __syncthreads();
  float e0 = __expf(l0-m), e1 = __expf(l1-m);
  sc[tid]=e0; sc[tid+256]=e1;
  float s = e0+e1;
  #pragma unroll
  for (int o=1;o<64;o<<=1) s += __shfl_xor(s,o);
  if ((tid&63)==0) red[tid>>6] = s;
  __syncthreads();
  s = red[0]+red[1]+red[2]+red[3];
  float invs = 1.f/s;
  float acc = 0.f;
  for (int j=0;j<512;++j) acc += sc[j] * b2f(kg[(size_t)j*256 + tid]);
  wsum[(size_t)g*256+tid] = acc*invs;
}
__global__ void k_concat(const float* __restrict__ p1, const float* __restrict__ p2,
                         const float* __restrict__ p3, float* __restrict__ pooled){
  int idx = blockIdx.x*256 + threadIdx.x;
  int b = idx / 768, j = idx % 768;
  float v = (j < 256) ? p1[b*256+j] : (j < 512) ? p2[b*256+j-256] : p3[b*256+j-512];
  pooled[idx] = v;
}

// ---------------- GRU v12: i8 Whh stream + bf16 X. 1 graph/block, 512 thr ----------
__global__ __launch_bounds__(512) void k_gru12(const ushort* __restrict__ X,
                      const ushort* __restrict__ pIh, const char* __restrict__ pHh8,
                      const float* __restrict__ csg, const float* __restrict__ bc,
                      float* __restrict__ p2){
  extern __shared__ char gsm[];
  float*  GIw  = (float*)gsm;                   // [32][768]  98304 B
  float*  gh   = (float*)(gsm + 98304);         // [768]
  float*  bcl  = (float*)(gsm + 101376);        // [1024]
  float*  csl  = (float*)(gsm + 105472);        // [768]
  char*   hbf8 = (char*) (gsm + 108544);        // [256]
  const int g = blockIdx.x;
  const int tid = threadIdx.x;
  const int wv = tid>>6, lane = tid&63;
  const int arow = lane&15, ks = lane>>4;
  for (int i=tid;i<1024;i+=512) bcl[i] = bc[i];
  for (int i=tid;i<768;i+=512)  csl[i] = csg[i];
  if (tid < 256) hbf8[tid] = 0;
  float h_reg = 0.f;
  const ushort* Xg = X + (size_t)g*512*256;
  __syncthreads();
  for (int w=0; w<16; ++w){
    const int t0 = w*32;
    #pragma unroll
    for (int mt=0; mt<2; ++mt){
      const ushort* xr = Xg + (size_t)(t0 + mt*16 + arow)*256;
      f32x4 acc[6] = {};
      #pragma unroll
      for (int kt=0; kt<8; ++kt){
        bf16x8 af = *reinterpret_cast<const bf16x8*>(xr + kt*32 + ks*8);
        #pragma unroll
        for (int nt=0; nt<6; ++nt){
          bf16x8 bfr = *reinterpret_cast<const bf16x8*>(pIh + ((size_t)(kt*4+ks)*768 + wv*96+nt*16+arow)*8);
          acc[nt] = __builtin_amdgcn_mfma_f32_16x16x32_bf16(af, bfr, acc[nt], 0,0,0);
        }
      }
      #pragma unroll
      for (int nt=0; nt<6; ++nt){
        const int col = wv*96 + nt*16 + arow;
        #pragma unroll
        for (int r=0;r<4;++r)
          GIw[(size_t)(mt*16 + ks*4 + r)*768 + col] = acc[nt][r];
      }
    }
    for (int dt=0; dt<32; ++dt){
      i32x4 sacc[6] = {};
      #pragma unroll
      for (int kt=0; kt<8; ++kt){
        long a8 = 0;
        if (arow == 0) a8 = *reinterpret_cast<const long*>(hbf8 + kt*32 + ks*8);
        #pragma unroll
        for (int nt=0; nt<6; ++nt){
          const int col = wv*96 + nt*16 + arow;
          long b8 = *reinterpret_cast<const long*>(pHh8 + ((size_t)(kt*4+ks)*768 + col)*8);
          sacc[nt] = __builtin_amdgcn_mfma_i32_16x16x32_i8(a8, b8, sacc[nt], 0,0,0);
        }
      }
      if (ks == 0){
        #pragma unroll
        for (int nt=0; nt<6; ++nt){
          const int col = wv*96 + nt*16 + arow;
          gh[col] = (float)sacc[nt][0] * csl[col];
        }
      }
      __syncthreads();
      if (tid < 256){
        const int c = tid;
        const float* gir = GIw + (size_t)dt*768;
        float rr = sigm(gir[c]     + gh[c]     + bcl[c]);
        float zz = sigm(gir[256+c] + gh[256+c] + bcl[256+c]);
        float nx = gir[512+c] + bcl[512+c] + rr*(gh[512+c] + bcl[768+c]);
        nx = fminf(fmaxf(nx, -15.f), 15.f);
        float e2 = __expf(2.f*nx);
        float nn = (e2-1.f)*__builtin_amdgcn_rcpf(e2+1.f);
        h_reg = (1.f-zz)*nn + zz*h_reg;
        int q = (int)lrintf(h_reg*127.f);
        q = max(-127, min(127, q));
        hbf8[c] = (char)q;
      }
      __syncthreads();
    }
  }
  if (tid < 256) p2[(size_t)g*256 + tid] = h_reg;
}

// =====================================================================
extern "C" void kernel_launch(void* const* d_in, const int* in_sizes, int n_in,
                              void* d_out, int out_size, void* d_ws, size_t ws_size,
                              hipStream_t stream){
  const int*   x      = (const int*)  d_in[0];
  const int*   ei     = (const int*)  d_in[1];
  const float* emb_w  = (const float*)d_in[3];
  const float* c1_lW  = (const float*)d_in[4];
  const float* c1_lb  = (const float*)d_in[5];
  const float* c1_rW  = (const float*)d_in[6];
  const float* t1     = (const float*)d_in[7];
  const float* c2_lW  = (const float*)d_in[8];
  const float* c2_lb  = (const float*)d_in[9];
  const float* c2_rW  = (const float*)d_in[10];
  const float* t2     = (const float*)d_in[11];
  const float* mlp_W  = (const float*)d_in[12];
  const float* mlp_b  = (const float*)d_in[13];
  const float* gWih   = (const float*)d_in[14];
  const float* gWhh   = (const float*)d_in[15];
  const float* gbih   = (const float*)d_in[16];
  const float* gbhh   = (const float*)d_in[17];
  const float* stWq   = (const float*)d_in[18];
  const float* stbq   = (const float*)d_in[19];
  const float* stWk   = (const float*)d_in[20];
  const float* stbk   = (const float*)d_in[21];
  const float* stWv   = (const float*)d_in[22];
  const float* stbv   = (const float*)d_in[23];
  const float* stWo   = (const float*)d_in[24];
  const float* stbo   = (const float*)d_in[25];
  const float* stlW   = (const float*)d_in[26];
  const float* stlb   = (const float*)d_in[27];
  const float* pma_lW = (const float*)d_in[28];
  const float* pma_lb = (const float*)d_in[29];
  const float* seed   = (const float*)d_in[30];
  const float* fin_W  = (const float*)d_in[31];
  const float* fin_b  = (const float*)d_in[32];
  float* out = (float*)d_out;

  auto needFor = [](int CHe)->size_t{
    size_t bufN = (size_t)CHe*512*512;
    size_t floats = (size_t)33554432 + 3*bufN + 2*524288 + 2*196608 + 8*65536 + 196608 + 320 + 512;
    size_t ints   = 131072 + 131200 + 131072 + 262144 + 128 + 128;
    return floats*4 + ints*4 + 4096;
  };
  const int CHe = (ws_size >= needFor(64)) ? 64 : 32;
  if (ws_size < needFor(32)) return;
  const int NCHUNKe = BG / CHe;
  const int NCNe = CHe * 512;
  const size_t bufN = (size_t)CHe*512*512;

  // ---- workspace carve ----
  float* H2   = (float*)d_ws;
  float* bufA = H2   + (size_t)33554432;
  float* bufB = bufA + bufN;
  float* bufC = bufB + bufN;
  float* h0   = bufC + bufN;
  float* ag1  = h0   + (size_t)524288;
  float* wT1  = ag1  + (size_t)524288;
  float* wT2  = wT1  + (size_t)196608;
  float* p1   = wT2  + (size_t)196608;
  float* p2   = p1   + (size_t)65536;
  float* p3   = p2   + (size_t)65536;
  float* av2  = p3   + (size_t)65536;
  float* s1   = av2  + (size_t)65536;
  float* s2v  = s1   + (size_t)65536;
  float* v3   = s2v  + (size_t)65536;
  float* h3   = v3   + (size_t)65536;
  float* pooled = h3 + (size_t)65536;
  float* qv   = pooled + (size_t)196608;
  int*   deg  = (int*)(qv + 320);
  int*   offs = deg  + 131072;
  int*   cur  = offs + 131200;
  int*   esrc = cur  + 131072;
  int*   bsum = esrc + 262144;
  int*   boff = bsum + 128;
  float* wkq  = (float*)(boff + 128);

  ushort* H2b  = (ushort*)H2;
  ushort* pIh  = (ushort*)wT1;
  char*   pHh8 = (char*)(wT1 + 98304);
  float*  csHh = wT1 + 98304 + 49152;
  ushort* pC2  = (ushort*)wT2;
  float*  bcomb= wT2 + 65536;
  float*  pa   = h0;
  ushort* pQ0  = (ushort*)(pa);
  ushort* pK0  = (ushort*)(pa + 32768);
  ushort* pV0  = (ushort*)(pa + 65536);
  ushort* pO0  = (ushort*)(pa + 98304);
  ushort* pL0  = (ushort*)(pa + 131072);
  ushort* pPma = (ushort*)(pa + 163840);
  ushort* pV1  = (ushort*)(pa + 229376);
  ushort* pO1  = (ushort*)(pa + 262144);
  ushort* pL1  = (ushort*)(pa + 294912);
  ushort* pV2  = (ushort*)(pa + 327680);
  ushort* pO2  = (ushort*)(pa + 360448);
  ushort* pL2  = (ushort*)(pa + 393216);
  ushort* pFin = (ushort*)(pa + 425984);

  // ST sub-buffers
  ushort* Qbf = (ushort*)bufA;                   // NCNe x 256 bf16
  ushort* Obf = (ushort*)(bufA + bufN/4);        // NCNe x 256 bf16
  ushort* VTp = (ushort*)(bufA + bufN/2);        // per-graph packed V
  ushort* Kbf = (ushort*)bufB;                   // NCNe x 256 bf16 (later kk)
  ushort* Ebf = Qbf;
  ushort* kkb = Kbf;
  ushort* cvb = (ushort*)bufC;                   // conv staging bf16 [n][512]

  const int ls0 = 65536, ls1 = 256;

  // ---- 1. node encoder ----
  k_node_enc<<<NN/256, 256, 0, stream>>>(x, emb_w, h0);

  // ---- 2. CSR ----
  k_zero<<<NN/256, 256, 0, stream>>>(deg, NN);
  k_count<<<NE/256, 256, 0, stream>>>(ei, deg);
  k_blocksum<<<128, 256, 0, stream>>>(deg, bsum);
  k_scanbsum<<<1, 128, 0, stream>>>(bsum, boff, offs + NN);
  k_scanchunk<<<128, 256, 0, stream>>>(deg, boff, offs);
  k_zero<<<NN/256, 256, 0, stream>>>(cur, NN);
  k_fill<<<NE/256, 256, 0, stream>>>(ei, offs, cur, esrc);

  // ---- 3. conv1 aggregation + early packs ----
  k_aggr4<<<NN/256, 256, 0, stream>>>(h0, offs, esrc, t1, ag1);
  k_packb <<<256, 256, 0, stream>>>(c2_rW, pC2, 256, 256);
  k_packb <<<256, 256, 0, stream>>>(c2_lW, pC2 + 65536, 256, 256);
  k_packbT<<<768, 256, 0, stream>>>(gWih, pIh, 256, 768);
  k_packhh8<<<768, 256, 0, stream>>>(gWhh, pHh8, csHh);
  k_packbias<<<4, 256, 0, stream>>>(gbih, gbhh, bcomb);

  // ---- 4. conv1 + conv2 (bf16 staging, fused K=512) -> H2b bf16, chunked ----
  for (int cg = 0; cg < NCHUNKe; ++cg){
    const int base = cg * NCNe;
    ushort* Hcb = H2b + (size_t)base * 256;
    k_conv1_lin<<<NCNe, 256, 0, stream>>>(ag1, h0, c1_lW, c1_lb, c1_rW, cvb, base);
    k_aggr256<<<NCNe, 256, 0, stream>>>(cvb, offs, esrc, t2, base);
    k_bgemm2<GF_BIAS|GF_RELU|GF_BF16, true><<<NCNe/128, 256, 0, stream>>>(cvb, pC2, c2_lb, nullptr, Hcb, 512, 512);
  }

  // ---- 5. p1 = MLP pool via MFMA ----
  k_packb<<<131072, 256, 0, stream>>>(mlp_W, (ushort*)bufB, 131072, 256);
  k_rowbias<<<256, 256, 0, stream>>>(mlp_b, p1, 256, 65536);
  k_bgemm2<GF_ATOMIC, true><<<dim3(2, 1, 128), 256, 0, stream>>>(H2b, (ushort*)bufB, nullptr, nullptr, p1, NN, 131072);

  // ---- 6. GRU v12 ----
  k_gru12<<<BG, 512, 108800, stream>>>(H2b, pIh, pHh8, csHh, bcomb, p2);

  // ---- 7. ST packs + set transformer (fused attention), chunked ----
  k_packb<<<256, 256, 0, stream>>>(stWq,        pQ0, 256, 256);
  k_packb<<<256, 256, 0, stream>>>(stWk,        pK0, 256, 256);
  k_packb<<<256, 256, 0, stream>>>(stWv,        pV0, 256, 256);
  k_packb<<<256, 256, 0, stream>>>(stWo,        pO0, 256, 256);
  k_packb<<<256, 256, 0, stream>>>(stlW,        pL0, 256, 256);
  k_packb<<<256, 256, 0, stream>>>(pma_lW,      pPma,256, 256);
  k_packb<<<256, 256, 0, stream>>>(stWv + ls0,  pV1, 256, 256);
  k_packb<<<256, 256, 0, stream>>>(stWo + ls0,  pO1, 256, 256);
  k_packb<<<256, 256, 0, stream>>>(stlW + ls0,  pL1, 256, 256);
  k_packb<<<256, 256, 0, stream>>>(stWv + 2*ls0,pV2, 256, 256);
  k_packb<<<256, 256, 0, stream>>>(stWo + 2*ls0,pO2, 256, 256);
  k_packb<<<256, 256, 0, stream>>>(stlW + 2*ls0,pL2, 256, 256);
  k_packb<<<2304, 256, 0, stream>>>(fin_W,      pFin,768, 768);
  k_qvec<<<1, 256, 0, stream>>>(seed, stWq + ls0, stbq + ls1, qv);
  k_wk2q<<<1, 256, 0, stream>>>(stWk + ls0, stbk + ls1, qv, wkq);

  for (int cg = 0; cg < NCHUNKe; ++cg){
    const int base = cg * NCNe;
    ushort* Hcb = H2b + (size_t)base * 256;
    const int gb1 = NCNe/128;
    k_bgemm2<GF_BIAS|GF_BF16, true><<<gb1, 256, 0, stream>>>(Hcb, pQ0, stbq, nullptr, Qbf, 256, 256);
    k_bgemm2<GF_BIAS|GF_BF16, true><<<gb1, 256, 0, stream>>>(Hcb, pK0, stbk, nullptr, Kbf, 256, 256);
    k_bgemm2<GF_BIAS|GF_VTP,  true><<<gb1, 256, 0, stream>>>(Hcb, pV0, stbv, nullptr, VTp, 256, 256);
    k_afuse<<<NCNe/64, 256, 134400, stream>>>(Qbf, Kbf, VTp, Obf);
    k_bgemm2<GF_BIAS|GF_RESID16|GF_BF16, true><<<gb1, 256, 0, stream>>>(Obf, pO0, stbo, Hcb, Hcb, 256, 256);
    k_bgemm2<GF_BIAS|GF_RELU|GF_RESID16|GF_BF16, true><<<gb1, 256, 0, stream>>>(Hcb, pL0, stlb, Hcb, Ebf, 256, 256);
    k_bgemm2<GF_BIAS|GF_RELU|GF_BF16, true><<<gb1, 256, 0, stream>>>(Ebf, pPma, pma_lb, nullptr, kkb, 256, 256);
    k_pmafuse16<<<CHe, 256, 0, stream>>>(kkb, wkq, av2 + (size_t)cg*CHe*256);
  }

  // ---- 8. PMA tail + decoder SAB (small, f32 path) ----
  k_bgemm<GF_BIAS><<<dim3(2, 2, 1), 256, 0, stream>>>(av2, pV1, stbv + ls1, nullptr, v3, 256, 256, 256, 256);
  k_bgemm<GF_BIAS|GF_RESID_B><<<dim3(2, 2, 1), 256, 0, stream>>>(v3, pO1, stbo + ls1, seed, s1, 256, 256, 256, 256);
  k_bgemm<GF_BIAS|GF_RELU|GF_RESID><<<dim3(2, 2, 1), 256, 0, stream>>>(s1, pL1, stlb + ls1, s1, s2v, 256, 256, 256, 256);
  k_bgemm<GF_BIAS><<<dim3(2, 2, 1), 256, 0, stream>>>(s2v, pV2, stbv + 2*ls1, nullptr, v3, 256, 256, 256, 256);
  k_bgemm<GF_BIAS|GF_RESID><<<dim3(2, 2, 1), 256, 0, stream>>>(v3, pO2, stbo + 2*ls1, s2v, h3, 256, 256, 256, 256);
  k_bgemm<GF_BIAS|GF_RELU|GF_RESID><<<dim3(2, 2, 1), 256, 0, stream>>>(h3, pL2, stlb + 2*ls1, h3, p3, 256, 256, 256, 256);

  // ---- 9. concat + final linear ----
  k_concat<<<768, 256, 0, stream>>>(p1, p2, p3, pooled);
  k_bgemm<GF_BIAS><<<dim3(2, 6, 1), 256, 0, stream>>>(pooled, pFin, fin_b, nullptr, out, 256, 768, 768, 768);
}